// Round 1
// baseline (4395.645 us; speedup 1.0000x reference)
//
#include <hip/hip_runtime.h>

#define NN 50000
#define NE 800000
#define EPSB 1e-5f

__device__ __forceinline__ float sigm(float x){ return 1.0f/(1.0f+__expf(-x)); }
__device__ __forceinline__ float silu_(float x){ return x/(1.0f+__expf(-x)); }

// ---------------- elementwise / prep ----------------

__global__ __launch_bounds__(256) void k_silu4(const float* __restrict__ in,
                                               float* __restrict__ out, int n4){
  int i = blockIdx.x*256 + threadIdx.x;
  if (i < n4){
    float4 v = ((const float4*)in)[i];
    v.x = silu_(v.x); v.y = silu_(v.y); v.z = silu_(v.z); v.w = silu_(v.w);
    ((float4*)out)[i] = v;
  }
}

__global__ __launch_bounds__(256) void k_deg(const int* __restrict__ src,
                                             int* __restrict__ deg){
  int e = blockIdx.x*256 + threadIdx.x;
  if (e < NE) atomicAdd(&deg[src[e]], 1);
}

__global__ __launch_bounds__(256) void k_invdeg(const int* __restrict__ deg,
                                                float* __restrict__ invd){
  int n = blockIdx.x*256 + threadIdx.x;
  if (n < NN) invd[n] = 1.0f / fmaxf((float)deg[n], 1.0f);
}

// ---------------- node linears: xl[k][n][f] = h[n,:] . Wv[k][f,:] + bv[k][f] ----------------
// grid (ceil(N/64), 4); block 256 = 4 waves; wave w handles 16 nodes; lane = f.
__global__ __launch_bounds__(256) void k_nodelin(const float* __restrict__ h,
    const float* __restrict__ Wv, const float* __restrict__ bv,
    float* __restrict__ xl){
  const int k = blockIdx.y;
  __shared__ float sW[4096];
  __shared__ float sH[4096];
  const int n0 = blockIdx.x * 64;
  const float* Wk = Wv + k*4096;
  for (int i = threadIdx.x; i < 1024; i += 256){
    int lin = i*4, f = lin>>6, d = lin&63;
    float4 v = ((const float4*)Wk)[i];
    *(float4*)((char*)sW + (((f<<8) + (d<<2)) ^ ((f&7)<<4))) = v;
  }
  const int v4 = (NN - n0) * 16;   // valid float4 count in tile
  const float* hb = h + (size_t)n0*64;
  for (int i = threadIdx.x; i < 1024; i += 256){
    float4 v = (i < v4) ? ((const float4*)hb)[i] : make_float4(0.f,0.f,0.f,0.f);
    ((float4*)sH)[i] = v;
  }
  __syncthreads();
  const int wid = threadIdx.x >> 6, f = threadIdx.x & 63;
  float acc[16];
  #pragma unroll
  for (int j=0;j<16;++j) acc[j]=0.f;
  #pragma unroll
  for (int dc=0; dc<16; ++dc){
    float4 a = *(float4*)((char*)sW + (((f<<8) + (dc<<4)) ^ ((f&7)<<4)));
    #pragma unroll
    for (int j=0;j<16;++j){
      float4 b = *(float4*)(sH + ((wid*16+j)<<6) + (dc<<2));
      acc[j] = fmaf(a.x,b.x, fmaf(a.y,b.y, fmaf(a.z,b.z, fmaf(a.w,b.w, acc[j]))));
    }
  }
  float bias = bv[(k<<6)+f];
  #pragma unroll
  for (int j=0;j<16;++j){
    int n = n0 + wid*16 + j;
    if (n < NN) xl[((size_t)k*NN + n)*64 + f] = acc[j] + bias;
  }
}

// ---------------- edge pass A: u-stats + gated message aggregation ----------------
// grid E/64; block 256; 64 edges per block, 16 per wave; lane = f.
__global__ __launch_bounds__(256) void k_edgeA(const float* __restrict__ w_in, int first,
    const int* __restrict__ src, const int* __restrict__ dst,
    const float* __restrict__ We, const float* __restrict__ be,
    const float* __restrict__ x2, const float* __restrict__ x3, const float* __restrict__ x4,
    float* __restrict__ agg, float* __restrict__ esum, float* __restrict__ esq){
  __shared__ float sWe[4096], sw[4096];
  __shared__ int sidx[128];
  __shared__ float sred[4][64][2];
  const int e0 = blockIdx.x*64;
  for (int i = threadIdx.x; i < 1024; i += 256){
    int lin=i*4, f=lin>>6, d=lin&63;
    float4 v = ((const float4*)We)[i];
    *(float4*)((char*)sWe + (((f<<8)+(d<<2)) ^ ((f&7)<<4))) = v;
  }
  const float* wb = w_in + (size_t)e0*64;
  for (int i = threadIdx.x; i < 1024; i += 256){
    float4 v = ((const float4*)wb)[i];
    if (first){ v.x=silu_(v.x); v.y=silu_(v.y); v.z=silu_(v.z); v.w=silu_(v.w); }
    ((float4*)sw)[i] = v;
  }
  if (threadIdx.x < 64) sidx[threadIdx.x] = src[e0+threadIdx.x];
  else if (threadIdx.x < 128) sidx[threadIdx.x] = dst[e0+threadIdx.x-64];
  __syncthreads();
  const int wid = threadIdx.x>>6, f = threadIdx.x&63;
  float acc[16];
  #pragma unroll
  for (int j=0;j<16;++j) acc[j]=0.f;
  #pragma unroll
  for (int dc=0; dc<16; ++dc){
    float4 a = *(float4*)((char*)sWe + (((f<<8)+(dc<<4)) ^ ((f&7)<<4)));
    #pragma unroll
    for (int j=0;j<16;++j){
      float4 b = *(float4*)(sw + ((wid*16+j)<<6) + (dc<<2));
      acc[j] = fmaf(a.x,b.x, fmaf(a.y,b.y, fmaf(a.z,b.z, fmaf(a.w,b.w, acc[j]))));
    }
  }
  float bef = be[f];
  float s1=0.f, s2=0.f;
  #pragma unroll
  for (int j=0;j<16;++j){
    int el = wid*16+j;
    int s = sidx[el], d2 = sidx[64+el];
    float u = acc[j] + bef + x3[(size_t)s*64+f] + x4[(size_t)d2*64+f];
    s1 += u; s2 += u*u;
    float m = sigm(sw[(el<<6)+f]) * x2[(size_t)d2*64+f];
    atomicAdd(&agg[(size_t)s*64+f], m);
  }
  sred[wid][f][0]=s1; sred[wid][f][1]=s2;
  __syncthreads();
  if (wid==0){
    float a1 = sred[0][f][0]+sred[1][f][0]+sred[2][f][0]+sred[3][f][0];
    float a2 = sred[0][f][1]+sred[1][f][1]+sred[2][f][1]+sred[3][f][1];
    int slot = blockIdx.x & 63;
    atomicAdd(&esum[(slot<<6)+f], a1);
    atomicAdd(&esq[(slot<<6)+f], a2);
  }
}

// ---------------- node BN stats over t = x1 + agg*invdeg ----------------
__global__ __launch_bounds__(256) void k_nodestats(const float* __restrict__ x1,
    const float* __restrict__ agg, const float* __restrict__ invd,
    float* __restrict__ nsum, float* __restrict__ nsq){
  const int f = threadIdx.x & 63, sub = threadIdx.x >> 6;
  float s1=0.f, s2=0.f;
  for (int n = blockIdx.x*4 + sub; n < NN; n += gridDim.x*4){
    float t = x1[(size_t)n*64+f] + agg[(size_t)n*64+f]*invd[n];
    s1 += t; s2 += t*t;
  }
  __shared__ float red[4][64][2];
  red[sub][f][0]=s1; red[sub][f][1]=s2;
  __syncthreads();
  if (sub==0){
    float a1=red[0][f][0]+red[1][f][0]+red[2][f][0]+red[3][f][0];
    float a2=red[0][f][1]+red[1][f][1]+red[2][f][1]+red[3][f][1];
    int slot = blockIdx.x & 63;
    atomicAdd(&nsum[(slot<<6)+f], a1);
    atomicAdd(&nsq[(slot<<6)+f], a2);
  }
}

// ---------------- finalize both BN -> scale/shift ----------------
__global__ void k_finalize(const float* __restrict__ nsum, const float* __restrict__ nsq,
    const float* __restrict__ esum, const float* __restrict__ esq,
    const float* __restrict__ gn, const float* __restrict__ bn,
    const float* __restrict__ ge, const float* __restrict__ beb,
    float* __restrict__ coef){
  int t = threadIdx.x;
  if (t >= 128) return;
  int f = t & 63;
  const float* S1 = (t<64)? nsum : esum;
  const float* S2 = (t<64)? nsq  : esq;
  float cnt = (t<64)? (float)NN : (float)NE;
  float s1=0.f, s2=0.f;
  for (int k=0;k<64;++k){ s1 += S1[(k<<6)+f]; s2 += S2[(k<<6)+f]; }
  float mu = s1/cnt;
  float var = s2/cnt - mu*mu;
  float rstd = rsqrtf(var + EPSB);
  float g = (t<64)? gn[f] : ge[f];
  float b = (t<64)? bn[f] : beb[f];
  float sc = g*rstd, sh = b - mu*sc;
  coef[((t<64)?0:2)*64 + f] = sc;
  coef[((t<64)?1:3)*64 + f] = sh;
}

// ---------------- node update: h += silu(bn(t)) ----------------
__global__ __launch_bounds__(256) void k_nodeupd(const float* __restrict__ x1,
    const float* __restrict__ agg, const float* __restrict__ invd,
    const float* __restrict__ coef, float* __restrict__ h){
  int i = blockIdx.x*256 + threadIdx.x;
  if (i >= NN*64) return;
  int n = i>>6, f = i&63;
  float t = x1[i] + agg[i]*invd[n];
  float v = t*coef[f] + coef[64+f];
  h[i] += silu_(v);
}

// ---------------- edge pass B: recompute u, normalize, w += silu(bn(u)) ----------------
__global__ __launch_bounds__(256) void k_edgeB(const float* __restrict__ w_in, int first,
    const int* __restrict__ src, const int* __restrict__ dst,
    const float* __restrict__ We, const float* __restrict__ be,
    const float* __restrict__ x3, const float* __restrict__ x4,
    const float* __restrict__ coef, float* __restrict__ w_out){
  __shared__ float sWe[4096], sw[4096];
  __shared__ int sidx[128];
  const int e0 = blockIdx.x*64;
  for (int i = threadIdx.x; i < 1024; i += 256){
    int lin=i*4, f=lin>>6, d=lin&63;
    float4 v = ((const float4*)We)[i];
    *(float4*)((char*)sWe + (((f<<8)+(d<<2)) ^ ((f&7)<<4))) = v;
  }
  const float* wb = w_in + (size_t)e0*64;
  for (int i = threadIdx.x; i < 1024; i += 256){
    float4 v = ((const float4*)wb)[i];
    if (first){ v.x=silu_(v.x); v.y=silu_(v.y); v.z=silu_(v.z); v.w=silu_(v.w); }
    ((float4*)sw)[i] = v;
  }
  if (threadIdx.x < 64) sidx[threadIdx.x] = src[e0+threadIdx.x];
  else if (threadIdx.x < 128) sidx[threadIdx.x] = dst[e0+threadIdx.x-64];
  __syncthreads();
  const int wid = threadIdx.x>>6, f = threadIdx.x&63;
  float acc[16];
  #pragma unroll
  for (int j=0;j<16;++j) acc[j]=0.f;
  #pragma unroll
  for (int dc=0; dc<16; ++dc){
    float4 a = *(float4*)((char*)sWe + (((f<<8)+(dc<<4)) ^ ((f&7)<<4)));
    #pragma unroll
    for (int j=0;j<16;++j){
      float4 b = *(float4*)(sw + ((wid*16+j)<<6) + (dc<<2));
      acc[j] = fmaf(a.x,b.x, fmaf(a.y,b.y, fmaf(a.z,b.z, fmaf(a.w,b.w, acc[j]))));
    }
  }
  float bef = be[f];
  float sc = coef[128+f], sh = coef[192+f];
  #pragma unroll
  for (int j=0;j<16;++j){
    int el = wid*16+j;
    int s = sidx[el], d2 = sidx[64+el];
    float u = acc[j] + bef + x3[(size_t)s*64+f] + x4[(size_t)d2*64+f];
    float v = silu_(u*sc + sh);
    w_out[((size_t)(e0+el))*64 + f] = sw[(el<<6)+f] + v;
  }
}

// ---------------- launch ----------------

extern "C" void kernel_launch(void* const* d_in, const int* in_sizes, int n_in,
                              void* d_out, int out_size, void* d_ws, size_t ws_size,
                              hipStream_t stream){
  const float* x      = (const float*)d_in[0];
  const int*   eidx   = (const int*)d_in[1];
  const float* eattr  = (const float*)d_in[2];
  const float* Wv     = (const float*)d_in[3];
  const float* bv     = (const float*)d_in[4];
  const float* We     = (const float*)d_in[5];
  const float* be     = (const float*)d_in[6];
  const float* g_node = (const float*)d_in[7];
  const float* b_node = (const float*)d_in[8];
  const float* g_edge = (const float*)d_in[9];
  const float* b_edge = (const float*)d_in[10];
  const int* src = eidx;
  const int* dst = eidx + NE;

  float* hout = (float*)d_out;                 // [N][64] live node state
  float* wout = hout + (size_t)NN*64;          // [E][64] live edge state

  float* W    = (float*)d_ws;
  float* xl   = W;                  // 4 * N * 64
  float* agg  = W + 12800000;       // N*64
  float* nsum = W + 16000000;       // 64*64
  float* nsq  = W + 16004096;
  float* esum = W + 16008192;
  float* esq  = W + 16012288;
  float* coef = W + 16016384;       // 4*64
  int*   deg  = (int*)(W + 16016640);
  float* invd = W + 16066640;

  hipMemsetAsync(deg, 0, NN*sizeof(int), stream);
  k_silu4<<<3125, 256, 0, stream>>>(x, hout, 800000);
  k_deg<<<(NE+255)/256, 256, 0, stream>>>(src, deg);
  k_invdeg<<<(NN+255)/256, 256, 0, stream>>>(deg, invd);

  for (int l=0; l<3; ++l){
    hipMemsetAsync(agg, 0, (3200000 + 4*4096)*sizeof(float), stream);
    k_nodelin<<<dim3(782,4), 256, 0, stream>>>(hout, Wv + l*4*4096, bv + l*256, xl);
    const float* win = (l==0)? eattr : wout;
    k_edgeA<<<12500, 256, 0, stream>>>(win, l==0, src, dst, We + l*4096, be + l*64,
        xl + (size_t)1*NN*64, xl + (size_t)2*NN*64, xl + (size_t)3*NN*64,
        agg, esum, esq);
    k_nodestats<<<128, 256, 0, stream>>>(xl, agg, invd, nsum, nsq);
    k_finalize<<<1, 128, 0, stream>>>(nsum, nsq, esum, esq,
        g_node + l*64, b_node + l*64, g_edge + l*64, b_edge + l*64, coef);
    k_nodeupd<<<12500, 256, 0, stream>>>(xl, agg, invd, coef, hout);
    k_edgeB<<<12500, 256, 0, stream>>>(win, l==0, src, dst, We + l*4096, be + l*64,
        xl + (size_t)2*NN*64, xl + (size_t)3*NN*64, coef, wout);
  }
}

// Round 2
// 1930.983 us; speedup vs baseline: 2.2764x; 2.2764x over previous
//
#include <hip/hip_runtime.h>

#define NN 50000
#define NE 800000
#define EPSB 1e-5f

__device__ __forceinline__ float sigm(float x){ return 1.0f/(1.0f+__expf(-x)); }
__device__ __forceinline__ float silu_(float x){ return x/(1.0f+__expf(-x)); }

// ---------------- elementwise / prep ----------------

__global__ __launch_bounds__(256) void k_silu4(const float* __restrict__ in,
                                               float* __restrict__ out, int n4){
  int i = blockIdx.x*256 + threadIdx.x;
  if (i < n4){
    float4 v = ((const float4*)in)[i];
    v.x = silu_(v.x); v.y = silu_(v.y); v.z = silu_(v.z); v.w = silu_(v.w);
    ((float4*)out)[i] = v;
  }
}

__global__ __launch_bounds__(256) void k_deg(const int* __restrict__ src,
                                             int* __restrict__ deg){
  int e = blockIdx.x*256 + threadIdx.x;
  if (e < NE) atomicAdd(&deg[src[e]], 1);
}

__global__ __launch_bounds__(256) void k_invdeg(const int* __restrict__ deg,
                                                float* __restrict__ invd){
  int n = blockIdx.x*256 + threadIdx.x;
  if (n < NN) invd[n] = 1.0f / fmaxf((float)deg[n], 1.0f);
}

// ---------------- node linears: xl[k][n][f] = h[n,:] . Wv[k][f,:] + bv[k][f] ----------------
// grid (ceil(N/64), 4); block 256 = 4 waves; wave w handles 16 nodes; lane = f.
// NOTE: dc loop is unroll-1 — full 16x16 unroll previously spilled ~2.3KB/thread
// (VGPR=256, 2.87GB scratch traffic, 885us). Bounded live set keeps it in regs.
__global__ __launch_bounds__(256) void k_nodelin(const float* __restrict__ h,
    const float* __restrict__ Wv, const float* __restrict__ bv,
    float* __restrict__ xl){
  const int k = blockIdx.y;
  __shared__ float sW[4096];
  __shared__ float sH[4096];
  const int n0 = blockIdx.x * 64;
  const float* Wk = Wv + k*4096;
  for (int i = threadIdx.x; i < 1024; i += 256){
    int lin = i*4, f = lin>>6, d = lin&63;
    float4 v = ((const float4*)Wk)[i];
    *(float4*)((char*)sW + (((f<<8) + (d<<2)) ^ ((f&7)<<4))) = v;
  }
  const int v4 = (NN - n0) * 16;   // valid float4 count in tile
  const float* hb = h + (size_t)n0*64;
  for (int i = threadIdx.x; i < 1024; i += 256){
    float4 v = (i < v4) ? ((const float4*)hb)[i] : make_float4(0.f,0.f,0.f,0.f);
    ((float4*)sH)[i] = v;
  }
  __syncthreads();
  const int wid = threadIdx.x >> 6, f = threadIdx.x & 63;
  float acc[16];
  #pragma unroll
  for (int j=0;j<16;++j) acc[j]=0.f;
  #pragma unroll 1
  for (int dc=0; dc<16; ++dc){
    float4 a = *(float4*)((char*)sW + (((f<<8) + (dc<<4)) ^ ((f&7)<<4)));
    #pragma unroll
    for (int j=0;j<16;++j){
      float4 b = *(float4*)(sH + ((wid*16+j)<<6) + (dc<<2));
      acc[j] = fmaf(a.x,b.x, fmaf(a.y,b.y, fmaf(a.z,b.z, fmaf(a.w,b.w, acc[j]))));
    }
  }
  float bias = bv[(k<<6)+f];
  #pragma unroll
  for (int j=0;j<16;++j){
    int n = n0 + wid*16 + j;
    if (n < NN) xl[((size_t)k*NN + n)*64 + f] = acc[j] + bias;
  }
}

// ---------------- edge pass A: u-stats + gated message aggregation ----------------
// grid E/64; block 256; 64 edges per block, 16 per wave; lane = f.
__global__ __launch_bounds__(256) void k_edgeA(const float* __restrict__ w_in, int first,
    const int* __restrict__ src, const int* __restrict__ dst,
    const float* __restrict__ We, const float* __restrict__ be,
    const float* __restrict__ x2, const float* __restrict__ x3, const float* __restrict__ x4,
    float* __restrict__ agg, float* __restrict__ esum, float* __restrict__ esq){
  __shared__ float sWe[4096], sw[4096];
  __shared__ int sidx[128];
  __shared__ float sred[4][64][2];
  const int e0 = blockIdx.x*64;
  for (int i = threadIdx.x; i < 1024; i += 256){
    int lin=i*4, f=lin>>6, d=lin&63;
    float4 v = ((const float4*)We)[i];
    *(float4*)((char*)sWe + (((f<<8)+(d<<2)) ^ ((f&7)<<4))) = v;
  }
  const float* wb = w_in + (size_t)e0*64;
  for (int i = threadIdx.x; i < 1024; i += 256){
    float4 v = ((const float4*)wb)[i];
    if (first){ v.x=silu_(v.x); v.y=silu_(v.y); v.z=silu_(v.z); v.w=silu_(v.w); }
    ((float4*)sw)[i] = v;
  }
  if (threadIdx.x < 64) sidx[threadIdx.x] = src[e0+threadIdx.x];
  else if (threadIdx.x < 128) sidx[threadIdx.x] = dst[e0+threadIdx.x-64];
  __syncthreads();
  const int wid = threadIdx.x>>6, f = threadIdx.x&63;
  float acc[16];
  #pragma unroll
  for (int j=0;j<16;++j) acc[j]=0.f;
  #pragma unroll
  for (int dc=0; dc<16; ++dc){
    float4 a = *(float4*)((char*)sWe + (((f<<8)+(dc<<4)) ^ ((f&7)<<4)));
    #pragma unroll
    for (int j=0;j<16;++j){
      float4 b = *(float4*)(sw + ((wid*16+j)<<6) + (dc<<2));
      acc[j] = fmaf(a.x,b.x, fmaf(a.y,b.y, fmaf(a.z,b.z, fmaf(a.w,b.w, acc[j]))));
    }
  }
  float bef = be[f];
  float s1=0.f, s2=0.f;
  #pragma unroll
  for (int j=0;j<16;++j){
    int el = wid*16+j;
    int s = sidx[el], d2 = sidx[64+el];
    float u = acc[j] + bef + x3[(size_t)s*64+f] + x4[(size_t)d2*64+f];
    s1 += u; s2 += u*u;
    float m = sigm(sw[(el<<6)+f]) * x2[(size_t)d2*64+f];
    atomicAdd(&agg[(size_t)s*64+f], m);
  }
  sred[wid][f][0]=s1; sred[wid][f][1]=s2;
  __syncthreads();
  if (wid==0){
    float a1 = sred[0][f][0]+sred[1][f][0]+sred[2][f][0]+sred[3][f][0];
    float a2 = sred[0][f][1]+sred[1][f][1]+sred[2][f][1]+sred[3][f][1];
    int slot = blockIdx.x & 63;
    atomicAdd(&esum[(slot<<6)+f], a1);
    atomicAdd(&esq[(slot<<6)+f], a2);
  }
}

// ---------------- node BN stats over t = x1 + agg*invdeg ----------------
__global__ __launch_bounds__(256) void k_nodestats(const float* __restrict__ x1,
    const float* __restrict__ agg, const float* __restrict__ invd,
    float* __restrict__ nsum, float* __restrict__ nsq){
  const int f = threadIdx.x & 63, sub = threadIdx.x >> 6;
  float s1=0.f, s2=0.f;
  for (int n = blockIdx.x*4 + sub; n < NN; n += gridDim.x*4){
    float t = x1[(size_t)n*64+f] + agg[(size_t)n*64+f]*invd[n];
    s1 += t; s2 += t*t;
  }
  __shared__ float red[4][64][2];
  red[sub][f][0]=s1; red[sub][f][1]=s2;
  __syncthreads();
  if (sub==0){
    float a1=red[0][f][0]+red[1][f][0]+red[2][f][0]+red[3][f][0];
    float a2=red[0][f][1]+red[1][f][1]+red[2][f][1]+red[3][f][1];
    int slot = blockIdx.x & 63;
    atomicAdd(&nsum[(slot<<6)+f], a1);
    atomicAdd(&nsq[(slot<<6)+f], a2);
  }
}

// ---------------- finalize both BN -> scale/shift ----------------
__global__ void k_finalize(const float* __restrict__ nsum, const float* __restrict__ nsq,
    const float* __restrict__ esum, const float* __restrict__ esq,
    const float* __restrict__ gn, const float* __restrict__ bn,
    const float* __restrict__ ge, const float* __restrict__ beb,
    float* __restrict__ coef){
  int t = threadIdx.x;
  if (t >= 128) return;
  int f = t & 63;
  const float* S1 = (t<64)? nsum : esum;
  const float* S2 = (t<64)? nsq  : esq;
  float cnt = (t<64)? (float)NN : (float)NE;
  float s1=0.f, s2=0.f;
  for (int k=0;k<64;++k){ s1 += S1[(k<<6)+f]; s2 += S2[(k<<6)+f]; }
  float mu = s1/cnt;
  float var = s2/cnt - mu*mu;
  float rstd = rsqrtf(var + EPSB);
  float g = (t<64)? gn[f] : ge[f];
  float b = (t<64)? bn[f] : beb[f];
  float sc = g*rstd, sh = b - mu*sc;
  coef[((t<64)?0:2)*64 + f] = sc;
  coef[((t<64)?1:3)*64 + f] = sh;
}

// ---------------- node update: h += silu(bn(t)) ----------------
__global__ __launch_bounds__(256) void k_nodeupd(const float* __restrict__ x1,
    const float* __restrict__ agg, const float* __restrict__ invd,
    const float* __restrict__ coef, float* __restrict__ h){
  int i = blockIdx.x*256 + threadIdx.x;
  if (i >= NN*64) return;
  int n = i>>6, f = i&63;
  float t = x1[i] + agg[i]*invd[n];
  float v = t*coef[f] + coef[64+f];
  h[i] += silu_(v);
}

// ---------------- edge pass B: recompute u, normalize, w += silu(bn(u)) ----------------
__global__ __launch_bounds__(256) void k_edgeB(const float* __restrict__ w_in, int first,
    const int* __restrict__ src, const int* __restrict__ dst,
    const float* __restrict__ We, const float* __restrict__ be,
    const float* __restrict__ x3, const float* __restrict__ x4,
    const float* __restrict__ coef, float* __restrict__ w_out){
  __shared__ float sWe[4096], sw[4096];
  __shared__ int sidx[128];
  const int e0 = blockIdx.x*64;
  for (int i = threadIdx.x; i < 1024; i += 256){
    int lin=i*4, f=lin>>6, d=lin&63;
    float4 v = ((const float4*)We)[i];
    *(float4*)((char*)sWe + (((f<<8)+(d<<2)) ^ ((f&7)<<4))) = v;
  }
  const float* wb = w_in + (size_t)e0*64;
  for (int i = threadIdx.x; i < 1024; i += 256){
    float4 v = ((const float4*)wb)[i];
    if (first){ v.x=silu_(v.x); v.y=silu_(v.y); v.z=silu_(v.z); v.w=silu_(v.w); }
    ((float4*)sw)[i] = v;
  }
  if (threadIdx.x < 64) sidx[threadIdx.x] = src[e0+threadIdx.x];
  else if (threadIdx.x < 128) sidx[threadIdx.x] = dst[e0+threadIdx.x-64];
  __syncthreads();
  const int wid = threadIdx.x>>6, f = threadIdx.x&63;
  float acc[16];
  #pragma unroll
  for (int j=0;j<16;++j) acc[j]=0.f;
  #pragma unroll
  for (int dc=0; dc<16; ++dc){
    float4 a = *(float4*)((char*)sWe + (((f<<8)+(dc<<4)) ^ ((f&7)<<4)));
    #pragma unroll
    for (int j=0;j<16;++j){
      float4 b = *(float4*)(sw + ((wid*16+j)<<6) + (dc<<2));
      acc[j] = fmaf(a.x,b.x, fmaf(a.y,b.y, fmaf(a.z,b.z, fmaf(a.w,b.w, acc[j]))));
    }
  }
  float bef = be[f];
  float sc = coef[128+f], sh = coef[192+f];
  #pragma unroll
  for (int j=0;j<16;++j){
    int el = wid*16+j;
    int s = sidx[el], d2 = sidx[64+el];
    float u = acc[j] + bef + x3[(size_t)s*64+f] + x4[(size_t)d2*64+f];
    float v = silu_(u*sc + sh);
    w_out[((size_t)(e0+el))*64 + f] = sw[(el<<6)+f] + v;
  }
}

// ---------------- launch ----------------

extern "C" void kernel_launch(void* const* d_in, const int* in_sizes, int n_in,
                              void* d_out, int out_size, void* d_ws, size_t ws_size,
                              hipStream_t stream){
  const float* x      = (const float*)d_in[0];
  const int*   eidx   = (const int*)d_in[1];
  const float* eattr  = (const float*)d_in[2];
  const float* Wv     = (const float*)d_in[3];
  const float* bv     = (const float*)d_in[4];
  const float* We     = (const float*)d_in[5];
  const float* be     = (const float*)d_in[6];
  const float* g_node = (const float*)d_in[7];
  const float* b_node = (const float*)d_in[8];
  const float* g_edge = (const float*)d_in[9];
  const float* b_edge = (const float*)d_in[10];
  const int* src = eidx;
  const int* dst = eidx + NE;

  float* hout = (float*)d_out;                 // [N][64] live node state
  float* wout = hout + (size_t)NN*64;          // [E][64] live edge state

  float* W    = (float*)d_ws;
  float* xl   = W;                  // 4 * N * 64
  float* agg  = W + 12800000;       // N*64
  float* nsum = W + 16000000;       // 64*64
  float* nsq  = W + 16004096;
  float* esum = W + 16008192;
  float* esq  = W + 16012288;
  float* coef = W + 16016384;       // 4*64
  int*   deg  = (int*)(W + 16016640);
  float* invd = W + 16066640;

  hipMemsetAsync(deg, 0, NN*sizeof(int), stream);
  k_silu4<<<3125, 256, 0, stream>>>(x, hout, 800000);
  k_deg<<<(NE+255)/256, 256, 0, stream>>>(src, deg);
  k_invdeg<<<(NN+255)/256, 256, 0, stream>>>(deg, invd);

  for (int l=0; l<3; ++l){
    hipMemsetAsync(agg, 0, (3200000 + 4*4096)*sizeof(float), stream);
    k_nodelin<<<dim3(782,4), 256, 0, stream>>>(hout, Wv + l*4*4096, bv + l*256, xl);
    const float* win = (l==0)? eattr : wout;
    k_edgeA<<<12500, 256, 0, stream>>>(win, l==0, src, dst, We + l*4096, be + l*64,
        xl + (size_t)1*NN*64, xl + (size_t)2*NN*64, xl + (size_t)3*NN*64,
        agg, esum, esq);
    k_nodestats<<<128, 256, 0, stream>>>(xl, agg, invd, nsum, nsq);
    k_finalize<<<1, 128, 0, stream>>>(nsum, nsq, esum, esq,
        g_node + l*64, b_node + l*64, g_edge + l*64, b_edge + l*64, coef);
    k_nodeupd<<<12500, 256, 0, stream>>>(xl, agg, invd, coef, hout);
    k_edgeB<<<12500, 256, 0, stream>>>(win, l==0, src, dst, We + l*4096, be + l*64,
        xl + (size_t)2*NN*64, xl + (size_t)3*NN*64, coef, wout);
  }
}

// Round 3
// 1237.300 us; speedup vs baseline: 3.5526x; 1.5606x over previous
//
#include <hip/hip_runtime.h>

#define NN 50000
#define NE 800000
#define EPSB 1e-5f

typedef __attribute__((ext_vector_type(8))) short bf16x8;
typedef __attribute__((ext_vector_type(4))) float f32x4;

__device__ __forceinline__ float sigm(float x){ return 1.0f/(1.0f+__expf(-x)); }
__device__ __forceinline__ float silu_(float x){ return x/(1.0f+__expf(-x)); }
__device__ __forceinline__ unsigned short f2bf(float x){
  unsigned int u = __float_as_uint(x);
  return (unsigned short)((u + 0x7FFFu + ((u>>16)&1u)) >> 16);   // RNE
}
__device__ __forceinline__ float bf2f(unsigned short b){
  return __uint_as_float(((unsigned int)b)<<16);
}

// ---------------- elementwise / prep ----------------

__global__ __launch_bounds__(256) void k_silu4(const float* __restrict__ in,
                                               float* __restrict__ out, int n4){
  int i = blockIdx.x*256 + threadIdx.x;
  if (i < n4){
    float4 v = ((const float4*)in)[i];
    v.x = silu_(v.x); v.y = silu_(v.y); v.z = silu_(v.z); v.w = silu_(v.w);
    ((float4*)out)[i] = v;
  }
}

__global__ __launch_bounds__(256) void k_deg(const int* __restrict__ src,
                                             int* __restrict__ deg){
  int e = blockIdx.x*256 + threadIdx.x;
  if (e < NE) atomicAdd(&deg[src[e]], 1);
}

__global__ __launch_bounds__(256) void k_invdeg(const int* __restrict__ deg,
                                                float* __restrict__ invd){
  int n = blockIdx.x*256 + threadIdx.x;
  if (n < NN) invd[n] = 1.0f / fmaxf((float)deg[n], 1.0f);
}

// ---------------- node linears (unchanged; unroll-1 keeps regs bounded) ----------------
__global__ __launch_bounds__(256) void k_nodelin(const float* __restrict__ h,
    const float* __restrict__ Wv, const float* __restrict__ bv,
    float* __restrict__ xl){
  const int k = blockIdx.y;
  __shared__ float sW[4096];
  __shared__ float sH[4096];
  const int n0 = blockIdx.x * 64;
  const float* Wk = Wv + k*4096;
  for (int i = threadIdx.x; i < 1024; i += 256){
    int lin = i*4, f = lin>>6, d = lin&63;
    float4 v = ((const float4*)Wk)[i];
    *(float4*)((char*)sW + (((f<<8) + (d<<2)) ^ ((f&7)<<4))) = v;
  }
  const int v4 = (NN - n0) * 16;
  const float* hb = h + (size_t)n0*64;
  for (int i = threadIdx.x; i < 1024; i += 256){
    float4 v = (i < v4) ? ((const float4*)hb)[i] : make_float4(0.f,0.f,0.f,0.f);
    ((float4*)sH)[i] = v;
  }
  __syncthreads();
  const int wid = threadIdx.x >> 6, f = threadIdx.x & 63;
  float acc[16];
  #pragma unroll
  for (int j=0;j<16;++j) acc[j]=0.f;
  #pragma unroll 1
  for (int dc=0; dc<16; ++dc){
    float4 a = *(float4*)((char*)sW + (((f<<8) + (dc<<4)) ^ ((f&7)<<4)));
    #pragma unroll
    for (int j=0;j<16;++j){
      float4 b = *(float4*)(sH + ((wid*16+j)<<6) + (dc<<2));
      acc[j] = fmaf(a.x,b.x, fmaf(a.y,b.y, fmaf(a.z,b.z, fmaf(a.w,b.w, acc[j]))));
    }
  }
  float bias = bv[(k<<6)+f];
  #pragma unroll
  for (int j=0;j<16;++j){
    int n = n0 + wid*16 + j;
    if (n < NN) xl[((size_t)k*NN + n)*64 + f] = acc[j] + bias;
  }
}

// ---------------- edge pass A (MFMA): u = w@We^T + be + x3[src] + x4[dst] ----------------
// 64 edges/block, 4 waves; wave wid owns edges wid*16..wid*16+15.
// Phase 1 (C-layout): u, BN stats, u -> ws (bf16). Phase 2 (f-layout): gated messages.
__global__ __launch_bounds__(256) void k_edgeA(const float* __restrict__ w_in, int first,
    const int* __restrict__ src, const int* __restrict__ dst,
    const float* __restrict__ We, const float* __restrict__ be,
    const float* __restrict__ x2, const float* __restrict__ x3, const float* __restrict__ x4,
    float* __restrict__ agg, float* __restrict__ esum, float* __restrict__ esq,
    unsigned short* __restrict__ u_out){
  __shared__ unsigned short sWb[4096];   // We bf16, row-swizzled
  __shared__ unsigned short swb[4096];   // w tile bf16, row-swizzled
  __shared__ int sidx[128];
  __shared__ float sred[4][64][2];
  const int e0 = blockIdx.x*64;
  const int t = threadIdx.x;

  // stage We (bf16, swizzle byte ^= (row&7)<<4)
  #pragma unroll
  for (int p=0; p<2; ++p){
    int c = t + p*256;                  // 512 chunks of 8 bf16
    int row = c >> 3, cc = c & 7;
    const float4* sp = (const float4*)(We + row*64 + cc*8);
    float4 a = sp[0], b = sp[1];
    bf16x8 v;
    v[0]=(short)f2bf(a.x); v[1]=(short)f2bf(a.y); v[2]=(short)f2bf(a.z); v[3]=(short)f2bf(a.w);
    v[4]=(short)f2bf(b.x); v[5]=(short)f2bf(b.y); v[6]=(short)f2bf(b.z); v[7]=(short)f2bf(b.w);
    *(bf16x8*)((char*)sWb + ((row*128 + cc*16) ^ ((row&7)<<4))) = v;
  }
  // stage w tile (silu on first layer)
  const float* wb = w_in + (size_t)e0*64;
  #pragma unroll
  for (int p=0; p<2; ++p){
    int c = t + p*256;
    int row = c >> 3, cc = c & 7;
    const float4* sp = (const float4*)(wb + row*64 + cc*8);
    float4 a = sp[0], b = sp[1];
    if (first){ a.x=silu_(a.x);a.y=silu_(a.y);a.z=silu_(a.z);a.w=silu_(a.w);
                b.x=silu_(b.x);b.y=silu_(b.y);b.z=silu_(b.z);b.w=silu_(b.w); }
    bf16x8 v;
    v[0]=(short)f2bf(a.x); v[1]=(short)f2bf(a.y); v[2]=(short)f2bf(a.z); v[3]=(short)f2bf(a.w);
    v[4]=(short)f2bf(b.x); v[5]=(short)f2bf(b.y); v[6]=(short)f2bf(b.z); v[7]=(short)f2bf(b.w);
    *(bf16x8*)((char*)swb + ((row*128 + cc*16) ^ ((row&7)<<4))) = v;
  }
  if (t < 64) sidx[t] = src[e0+t];
  else if (t < 128) sidx[t-64+64] = dst[e0+t-64];
  __syncthreads();

  const int wid = t>>6, lane = t&63;
  const int g = lane>>4, ln = lane&15;

  // A fragments: rows wid*16+ln, k = kk*32 + g*8 .. +7
  bf16x8 afr[2];
  #pragma unroll
  for (int kk=0; kk<2; ++kk){
    int row = wid*16 + ln;
    afr[kk] = *(bf16x8*)((char*)swb + ((row*128 + kk*64 + g*16) ^ ((row&7)<<4)));
  }
  // 4 f-tiles: B from We rows ft*16+ln (B col = We row since B = We^T)
  f32x4 cacc[4];
  #pragma unroll
  for (int ft=0; ft<4; ++ft){
    int row = ft*16 + ln;
    bf16x8 b0 = *(bf16x8*)((char*)sWb + ((row*128 +  0 + g*16) ^ ((row&7)<<4)));
    bf16x8 b1 = *(bf16x8*)((char*)sWb + ((row*128 + 64 + g*16) ^ ((row&7)<<4)));
    f32x4 c = {0.f,0.f,0.f,0.f};
    c = __builtin_amdgcn_mfma_f32_16x16x32_bf16(afr[0], b0, c, 0,0,0);
    c = __builtin_amdgcn_mfma_f32_16x16x32_bf16(afr[1], b1, c, 0,0,0);
    cacc[ft] = c;
  }

  // phase 1: u + stats + u_out   (C layout: row = g*4+r, col f = ft*16+ln)
  float bef[4];
  #pragma unroll
  for (int ft=0; ft<4; ++ft) bef[ft] = be[ft*16+ln];
  float s1[4]={0.f,0.f,0.f,0.f}, s2[4]={0.f,0.f,0.f,0.f};
  #pragma unroll
  for (int r=0; r<4; ++r){
    int jl = g*4 + r;
    int s  = sidx[wid*16 + jl];
    int d2 = sidx[64 + wid*16 + jl];
    const float* x3r = x3 + (size_t)s*64;
    const float* x4r = x4 + (size_t)d2*64;
    size_t eoff = (size_t)(e0 + wid*16 + jl)*64;
    #pragma unroll
    for (int ft=0; ft<4; ++ft){
      int f = ft*16 + ln;
      float u = cacc[ft][r] + bef[ft] + x3r[f] + x4r[f];
      s1[ft] += u; s2[ft] += u*u;
      u_out[eoff + f] = f2bf(u);
    }
  }
  #pragma unroll
  for (int ft=0; ft<4; ++ft){
    s1[ft] += __shfl_xor(s1[ft], 16); s1[ft] += __shfl_xor(s1[ft], 32);
    s2[ft] += __shfl_xor(s2[ft], 16); s2[ft] += __shfl_xor(s2[ft], 32);
  }
  if (g == 0){
    #pragma unroll
    for (int ft=0; ft<4; ++ft){
      sred[wid][ft*16+ln][0] = s1[ft];
      sred[wid][ft*16+ln][1] = s2[ft];
    }
  }
  __syncthreads();
  if (wid == 0){
    int f = lane;
    float a1 = sred[0][f][0]+sred[1][f][0]+sred[2][f][0]+sred[3][f][0];
    float a2 = sred[0][f][1]+sred[1][f][1]+sred[2][f][1]+sred[3][f][1];
    int slot = blockIdx.x & 63;
    atomicAdd(&esum[(slot<<6)+f], a1);
    atomicAdd(&esq[(slot<<6)+f], a2);
  }

  // phase 2: messages (f layout: lane = f, 16 edges per wave)
  #pragma unroll
  for (int j=0; j<16; ++j){
    int el = wid*16 + j;
    int s  = sidx[el];
    int d2 = sidx[64+el];
    unsigned short wv = *(unsigned short*)((char*)swb + ((el*128 + lane*2) ^ ((el&7)<<4)));
    float m = sigm(bf2f(wv)) * x2[(size_t)d2*64 + lane];
    atomicAdd(&agg[(size_t)s*64 + lane], m);
  }
}

// ---------------- node BN stats over t = x1 + agg*invdeg ----------------
__global__ __launch_bounds__(256) void k_nodestats(const float* __restrict__ x1,
    const float* __restrict__ agg, const float* __restrict__ invd,
    float* __restrict__ nsum, float* __restrict__ nsq){
  const int f = threadIdx.x & 63, sub = threadIdx.x >> 6;
  float s1=0.f, s2=0.f;
  for (int n = blockIdx.x*4 + sub; n < NN; n += gridDim.x*4){
    float t = x1[(size_t)n*64+f] + agg[(size_t)n*64+f]*invd[n];
    s1 += t; s2 += t*t;
  }
  __shared__ float red[4][64][2];
  red[sub][f][0]=s1; red[sub][f][1]=s2;
  __syncthreads();
  if (sub==0){
    float a1=red[0][f][0]+red[1][f][0]+red[2][f][0]+red[3][f][0];
    float a2=red[0][f][1]+red[1][f][1]+red[2][f][1]+red[3][f][1];
    int slot = blockIdx.x & 63;
    atomicAdd(&nsum[(slot<<6)+f], a1);
    atomicAdd(&nsq[(slot<<6)+f], a2);
  }
}

// ---------------- finalize both BN -> scale/shift ----------------
__global__ void k_finalize(const float* __restrict__ nsum, const float* __restrict__ nsq,
    const float* __restrict__ esum, const float* __restrict__ esq,
    const float* __restrict__ gn, const float* __restrict__ bn,
    const float* __restrict__ ge, const float* __restrict__ beb,
    float* __restrict__ coef){
  int t = threadIdx.x;
  if (t >= 128) return;
  int f = t & 63;
  const float* S1 = (t<64)? nsum : esum;
  const float* S2 = (t<64)? nsq  : esq;
  float cnt = (t<64)? (float)NN : (float)NE;
  float s1=0.f, s2=0.f;
  for (int k=0;k<64;++k){ s1 += S1[(k<<6)+f]; s2 += S2[(k<<6)+f]; }
  float mu = s1/cnt;
  float var = s2/cnt - mu*mu;
  float rstd = rsqrtf(var + EPSB);
  float g = (t<64)? gn[f] : ge[f];
  float b = (t<64)? bn[f] : beb[f];
  float sc = g*rstd, sh = b - mu*sc;
  coef[((t<64)?0:2)*64 + f] = sc;
  coef[((t<64)?1:3)*64 + f] = sh;
}

// ---------------- node update: h += silu(bn(t)) ----------------
__global__ __launch_bounds__(256) void k_nodeupd(const float* __restrict__ x1,
    const float* __restrict__ agg, const float* __restrict__ invd,
    const float* __restrict__ coef, float* __restrict__ h){
  int i = blockIdx.x*256 + threadIdx.x;
  if (i >= NN*64) return;
  int n = i>>6, f = i&63;
  float t = x1[i] + agg[i]*invd[n];
  float v = t*coef[f] + coef[64+f];
  h[i] += silu_(v);
}

// ---------------- edge pass B (elementwise now): w += silu(bn(u)) ----------------
__global__ __launch_bounds__(256) void k_edgeBew(const float* __restrict__ w_in, int first,
    const unsigned short* __restrict__ u_bf,
    const float* __restrict__ coef, float* __restrict__ w_out){
  int i = blockIdx.x*256 + threadIdx.x;      // over E*64/4 float4 groups
  int f0 = (i*4) & 63;
  float4 wv = ((const float4*)w_in)[i];
  if (first){ wv.x=silu_(wv.x); wv.y=silu_(wv.y); wv.z=silu_(wv.z); wv.w=silu_(wv.w); }
  ushort4 ub = ((const ushort4*)u_bf)[i];
  float4 sc = *(const float4*)(coef + 128 + f0);
  float4 sh = *(const float4*)(coef + 192 + f0);
  float4 o;
  o.x = wv.x + silu_(bf2f(ub.x)*sc.x + sh.x);
  o.y = wv.y + silu_(bf2f(ub.y)*sc.y + sh.y);
  o.z = wv.z + silu_(bf2f(ub.z)*sc.z + sh.z);
  o.w = wv.w + silu_(bf2f(ub.w)*sc.w + sh.w);
  ((float4*)w_out)[i] = o;
}

// ---------------- launch ----------------

extern "C" void kernel_launch(void* const* d_in, const int* in_sizes, int n_in,
                              void* d_out, int out_size, void* d_ws, size_t ws_size,
                              hipStream_t stream){
  const float* x      = (const float*)d_in[0];
  const int*   eidx   = (const int*)d_in[1];
  const float* eattr  = (const float*)d_in[2];
  const float* Wv     = (const float*)d_in[3];
  const float* bv     = (const float*)d_in[4];
  const float* We     = (const float*)d_in[5];
  const float* be     = (const float*)d_in[6];
  const float* g_node = (const float*)d_in[7];
  const float* b_node = (const float*)d_in[8];
  const float* g_edge = (const float*)d_in[9];
  const float* b_edge = (const float*)d_in[10];
  const int* src = eidx;
  const int* dst = eidx + NE;

  float* hout = (float*)d_out;                 // [N][64] live node state
  float* wout = hout + (size_t)NN*64;          // [E][64] live edge state

  float* W    = (float*)d_ws;
  float* xl   = W;                  // 4 * N * 64 = 12.8M floats
  float* agg  = W + 12800000;       // N*64
  float* nsum = W + 16000000;       // 64*64
  float* nsq  = W + 16004096;
  float* esum = W + 16008192;
  float* esq  = W + 16012288;
  float* coef = W + 16016384;       // 4*64
  int*   deg  = (int*)(W + 16016640);
  float* invd = W + 16066640;
  unsigned short* u_bf = (unsigned short*)(W + 16116640);  // E*64 bf16 = 102.4 MB

  hipMemsetAsync(deg, 0, NN*sizeof(int), stream);
  k_silu4<<<3125, 256, 0, stream>>>(x, hout, 800000);
  k_deg<<<(NE+255)/256, 256, 0, stream>>>(src, deg);
  k_invdeg<<<(NN+255)/256, 256, 0, stream>>>(deg, invd);

  for (int l=0; l<3; ++l){
    hipMemsetAsync(agg, 0, (3200000 + 4*4096)*sizeof(float), stream);
    k_nodelin<<<dim3(782,4), 256, 0, stream>>>(hout, Wv + l*4*4096, bv + l*256, xl);
    const float* win = (l==0)? eattr : wout;
    k_edgeA<<<12500, 256, 0, stream>>>(win, l==0, src, dst, We + l*4096, be + l*64,
        xl + (size_t)1*NN*64, xl + (size_t)2*NN*64, xl + (size_t)3*NN*64,
        agg, esum, esq, u_bf);
    k_nodestats<<<128, 256, 0, stream>>>(xl, agg, invd, nsum, nsq);
    k_finalize<<<1, 128, 0, stream>>>(nsum, nsq, esum, esq,
        g_node + l*64, b_node + l*64, g_edge + l*64, b_edge + l*64, coef);
    k_nodeupd<<<12500, 256, 0, stream>>>(xl, agg, invd, coef, hout);
    k_edgeBew<<<50000, 256, 0, stream>>>(win, l==0, u_bf, coef, wout);
  }
}

// Round 4
// 1128.675 us; speedup vs baseline: 3.8945x; 1.0962x over previous
//
#include <hip/hip_runtime.h>

#define NN 50000
#define NE 800000
#define EPSB 1e-5f

typedef __attribute__((ext_vector_type(8))) short bf16x8;
typedef __attribute__((ext_vector_type(8))) unsigned short ushort8;
typedef __attribute__((ext_vector_type(4))) float f32x4;

__device__ __forceinline__ float sigm(float x){ return 1.0f/(1.0f+__expf(-x)); }
__device__ __forceinline__ float silu_(float x){ return x/(1.0f+__expf(-x)); }
__device__ __forceinline__ unsigned short f2bf(float x){
  unsigned int u = __float_as_uint(x);
  return (unsigned short)((u + 0x7FFFu + ((u>>16)&1u)) >> 16);   // RNE
}
__device__ __forceinline__ float bf2f(unsigned short b){
  return __uint_as_float(((unsigned int)b)<<16);
}

// ---------------- elementwise / prep ----------------

__global__ __launch_bounds__(256) void k_silu4(const float* __restrict__ in,
                                               float* __restrict__ out, int n4){
  int i = blockIdx.x*256 + threadIdx.x;
  if (i < n4){
    float4 v = ((const float4*)in)[i];
    v.x = silu_(v.x); v.y = silu_(v.y); v.z = silu_(v.z); v.w = silu_(v.w);
    ((float4*)out)[i] = v;
  }
}

__global__ __launch_bounds__(256) void k_deg(const int* __restrict__ src,
                                             int* __restrict__ deg){
  int e = blockIdx.x*256 + threadIdx.x;
  if (e < NE) atomicAdd(&deg[src[e]], 1);
}

__global__ __launch_bounds__(256) void k_invdeg(const int* __restrict__ deg,
                                                float* __restrict__ invd){
  int n = blockIdx.x*256 + threadIdx.x;
  if (n < NN) invd[n] = 1.0f / fmaxf((float)deg[n], 1.0f);
}

// pre-convert We (3 layers) to bf16, XOR-swizzled (byte ^= (row&7)<<4)
__global__ __launch_bounds__(256) void k_prepWe(const float* __restrict__ We,
                                                unsigned short* __restrict__ wes){
  const int l = blockIdx.x;
  const float* Wl = We + l*4096;
  unsigned short* ol = wes + l*4096;
  int t = threadIdx.x;
  #pragma unroll
  for (int p=0; p<2; ++p){
    int c = t + p*256;          // 512 chunks of 8
    int row = c>>3, cc = c&7;
    const float4* sp = (const float4*)(Wl + row*64 + cc*8);
    float4 a = sp[0], b = sp[1];
    ushort8 v;
    v[0]=f2bf(a.x); v[1]=f2bf(a.y); v[2]=f2bf(a.z); v[3]=f2bf(a.w);
    v[4]=f2bf(b.x); v[5]=f2bf(b.y); v[6]=f2bf(b.z); v[7]=f2bf(b.w);
    *(ushort8*)((char*)ol + ((row*128 + cc*16) ^ ((row&7)<<4))) = v;
  }
}

// ---------------- node linears ----------------
// k==0 -> x1 f32 (node BN path); k>=1 -> bf16 tables x2/x3/x4 for edge gathers.
__global__ __launch_bounds__(256) void k_nodelin(const float* __restrict__ h,
    const float* __restrict__ Wv, const float* __restrict__ bv,
    float* __restrict__ x1, unsigned short* __restrict__ xb){
  const int k = blockIdx.y;
  __shared__ float sW[4096];
  __shared__ float sH[4096];
  const int n0 = blockIdx.x * 64;
  const float* Wk = Wv + k*4096;
  for (int i = threadIdx.x; i < 1024; i += 256){
    int lin = i*4, f = lin>>6, d = lin&63;
    float4 v = ((const float4*)Wk)[i];
    *(float4*)((char*)sW + (((f<<8) + (d<<2)) ^ ((f&7)<<4))) = v;
  }
  const int v4 = (NN - n0) * 16;
  const float* hb = h + (size_t)n0*64;
  for (int i = threadIdx.x; i < 1024; i += 256){
    float4 v = (i < v4) ? ((const float4*)hb)[i] : make_float4(0.f,0.f,0.f,0.f);
    ((float4*)sH)[i] = v;
  }
  __syncthreads();
  const int wid = threadIdx.x >> 6, f = threadIdx.x & 63;
  float acc[16];
  #pragma unroll
  for (int j=0;j<16;++j) acc[j]=0.f;
  #pragma unroll 1
  for (int dc=0; dc<16; ++dc){
    float4 a = *(float4*)((char*)sW + (((f<<8) + (dc<<4)) ^ ((f&7)<<4)));
    #pragma unroll
    for (int j=0;j<16;++j){
      float4 b = *(float4*)(sH + ((wid*16+j)<<6) + (dc<<2));
      acc[j] = fmaf(a.x,b.x, fmaf(a.y,b.y, fmaf(a.z,b.z, fmaf(a.w,b.w, acc[j]))));
    }
  }
  float bias = bv[(k<<6)+f];
  if (k == 0){
    #pragma unroll
    for (int j=0;j<16;++j){
      int n = n0 + wid*16 + j;
      if (n < NN) x1[(size_t)n*64 + f] = acc[j] + bias;
    }
  } else {
    unsigned short* xo = xb + (size_t)(k-1)*NN*64;
    #pragma unroll
    for (int j=0;j<16;++j){
      int n = n0 + wid*16 + j;
      if (n < NN) xo[(size_t)n*64 + f] = f2bf(acc[j] + bias);
    }
  }
}

// ---------------- edge pass A (MFMA): u = w@We^T + be + x3[src] + x4[dst] ----------------
template<int FIRST>
__global__ __launch_bounds__(256) void k_edgeA(const float* __restrict__ ea,
    const unsigned short* __restrict__ wb16,
    const int* __restrict__ src, const int* __restrict__ dst,
    const unsigned short* __restrict__ wes, const float* __restrict__ be,
    const unsigned short* __restrict__ x2, const unsigned short* __restrict__ x3,
    const unsigned short* __restrict__ x4,
    float* __restrict__ agg, float* __restrict__ esum, float* __restrict__ esq,
    unsigned short* __restrict__ u_out){
  __shared__ unsigned short sWb[4096];   // We bf16, pre-swizzled
  __shared__ unsigned short swb[4096];   // w tile bf16, row-swizzled
  __shared__ int sidx[128];
  __shared__ float sred[4][64][2];
  const int e0 = blockIdx.x*64;
  const int t = threadIdx.x;

  // stage We: linear copy (already swizzled in global)
  ((ushort8*)sWb)[t]       = ((const ushort8*)wes)[t];
  ((ushort8*)sWb)[t+256]   = ((const ushort8*)wes)[t+256];

  // stage w tile
  if (FIRST){
    const float* wb = ea + (size_t)e0*64;
    #pragma unroll
    for (int p=0; p<2; ++p){
      int c = t + p*256;
      int row = c >> 3, cc = c & 7;
      const float4* sp = (const float4*)(wb + row*64 + cc*8);
      float4 a = sp[0], b = sp[1];
      a.x=silu_(a.x);a.y=silu_(a.y);a.z=silu_(a.z);a.w=silu_(a.w);
      b.x=silu_(b.x);b.y=silu_(b.y);b.z=silu_(b.z);b.w=silu_(b.w);
      ushort8 v;
      v[0]=f2bf(a.x); v[1]=f2bf(a.y); v[2]=f2bf(a.z); v[3]=f2bf(a.w);
      v[4]=f2bf(b.x); v[5]=f2bf(b.y); v[6]=f2bf(b.z); v[7]=f2bf(b.w);
      *(ushort8*)((char*)swb + ((row*128 + cc*16) ^ ((row&7)<<4))) = v;
    }
  } else {
    const ushort8* wb = (const ushort8*)(wb16 + (size_t)e0*64);
    #pragma unroll
    for (int p=0; p<2; ++p){
      int c = t + p*256;
      int row = c >> 3, cc = c & 7;
      ushort8 v = wb[c];
      *(ushort8*)((char*)swb + ((row*128 + cc*16) ^ ((row&7)<<4))) = v;
    }
  }
  if (t < 64) sidx[t] = src[e0+t];
  else if (t < 128) sidx[t] = dst[e0+t-64];
  __syncthreads();

  const int wid = t>>6, lane = t&63;
  const int g = lane>>4, ln = lane&15;

  // A fragments: rows wid*16+ln, k = kk*32 + g*8 .. +7
  bf16x8 afr[2];
  #pragma unroll
  for (int kk=0; kk<2; ++kk){
    int row = wid*16 + ln;
    afr[kk] = *(bf16x8*)((char*)swb + ((row*128 + kk*64 + g*16) ^ ((row&7)<<4)));
  }
  // 4 f-tiles: B from We rows ft*16+ln (B col = We row since B = We^T)
  f32x4 cacc[4];
  #pragma unroll
  for (int ft=0; ft<4; ++ft){
    int row = ft*16 + ln;
    bf16x8 b0 = *(bf16x8*)((char*)sWb + ((row*128 +  0 + g*16) ^ ((row&7)<<4)));
    bf16x8 b1 = *(bf16x8*)((char*)sWb + ((row*128 + 64 + g*16) ^ ((row&7)<<4)));
    f32x4 c = {0.f,0.f,0.f,0.f};
    c = __builtin_amdgcn_mfma_f32_16x16x32_bf16(afr[0], b0, c, 0,0,0);
    c = __builtin_amdgcn_mfma_f32_16x16x32_bf16(afr[1], b1, c, 0,0,0);
    cacc[ft] = c;
  }

  // phase 1: u + stats + u_out   (C layout: row = g*4+r, col f = ft*16+ln)
  float bef[4];
  #pragma unroll
  for (int ft=0; ft<4; ++ft) bef[ft] = be[ft*16+ln];
  float s1[4]={0.f,0.f,0.f,0.f}, s2[4]={0.f,0.f,0.f,0.f};
  #pragma unroll
  for (int r=0; r<4; ++r){
    int jl = g*4 + r;
    int s  = sidx[wid*16 + jl];
    int d2 = sidx[64 + wid*16 + jl];
    const unsigned short* x3r = x3 + (size_t)s*64;
    const unsigned short* x4r = x4 + (size_t)d2*64;
    size_t eoff = (size_t)(e0 + wid*16 + jl)*64;
    #pragma unroll
    for (int ft=0; ft<4; ++ft){
      int f = ft*16 + ln;
      float u = cacc[ft][r] + bef[ft] + bf2f(x3r[f]) + bf2f(x4r[f]);
      s1[ft] += u; s2[ft] += u*u;
      u_out[eoff + f] = f2bf(u);
    }
  }
  #pragma unroll
  for (int ft=0; ft<4; ++ft){
    s1[ft] += __shfl_xor(s1[ft], 16); s1[ft] += __shfl_xor(s1[ft], 32);
    s2[ft] += __shfl_xor(s2[ft], 16); s2[ft] += __shfl_xor(s2[ft], 32);
  }
  if (g == 0){
    #pragma unroll
    for (int ft=0; ft<4; ++ft){
      sred[wid][ft*16+ln][0] = s1[ft];
      sred[wid][ft*16+ln][1] = s2[ft];
    }
  }
  __syncthreads();
  if (wid == 0){
    int f = lane;
    float a1 = sred[0][f][0]+sred[1][f][0]+sred[2][f][0]+sred[3][f][0];
    float a2 = sred[0][f][1]+sred[1][f][1]+sred[2][f][1]+sred[3][f][1];
    int slot = blockIdx.x & 63;
    atomicAdd(&esum[(slot<<6)+f], a1);
    atomicAdd(&esq[(slot<<6)+f], a2);
  }

  // phase 2: messages (f layout: lane = f, 16 edges per wave)
  #pragma unroll
  for (int j=0; j<16; ++j){
    int el = wid*16 + j;
    int s  = sidx[el];
    int d2 = sidx[64+el];
    unsigned short wv = *(unsigned short*)((char*)swb + ((el*128 + lane*2) ^ ((el&7)<<4)));
    float m = sigm(bf2f(wv)) * bf2f(x2[(size_t)d2*64 + lane]);
    atomicAdd(&agg[(size_t)s*64 + lane], m);
  }
}

// ---------------- node BN stats over t = x1 + agg*invdeg ----------------
__global__ __launch_bounds__(256) void k_nodestats(const float* __restrict__ x1,
    const float* __restrict__ agg, const float* __restrict__ invd,
    float* __restrict__ nsum, float* __restrict__ nsq){
  const int f = threadIdx.x & 63, sub = threadIdx.x >> 6;
  float s1=0.f, s2=0.f;
  for (int n = blockIdx.x*4 + sub; n < NN; n += gridDim.x*4){
    float t = x1[(size_t)n*64+f] + agg[(size_t)n*64+f]*invd[n];
    s1 += t; s2 += t*t;
  }
  __shared__ float red[4][64][2];
  red[sub][f][0]=s1; red[sub][f][1]=s2;
  __syncthreads();
  if (sub==0){
    float a1=red[0][f][0]+red[1][f][0]+red[2][f][0]+red[3][f][0];
    float a2=red[0][f][1]+red[1][f][1]+red[2][f][1]+red[3][f][1];
    int slot = blockIdx.x & 63;
    atomicAdd(&nsum[(slot<<6)+f], a1);
    atomicAdd(&nsq[(slot<<6)+f], a2);
  }
}

// ---------------- finalize both BN -> scale/shift ----------------
__global__ void k_finalize(const float* __restrict__ nsum, const float* __restrict__ nsq,
    const float* __restrict__ esum, const float* __restrict__ esq,
    const float* __restrict__ gn, const float* __restrict__ bn,
    const float* __restrict__ ge, const float* __restrict__ beb,
    float* __restrict__ coef){
  int t = threadIdx.x;
  if (t >= 128) return;
  int f = t & 63;
  const float* S1 = (t<64)? nsum : esum;
  const float* S2 = (t<64)? nsq  : esq;
  float cnt = (t<64)? (float)NN : (float)NE;
  float s1=0.f, s2=0.f;
  for (int k=0;k<64;++k){ s1 += S1[(k<<6)+f]; s2 += S2[(k<<6)+f]; }
  float mu = s1/cnt;
  float var = s2/cnt - mu*mu;
  float rstd = rsqrtf(var + EPSB);
  float g = (t<64)? gn[f] : ge[f];
  float b = (t<64)? bn[f] : beb[f];
  float sc = g*rstd, sh = b - mu*sc;
  coef[((t<64)?0:2)*64 + f] = sc;
  coef[((t<64)?1:3)*64 + f] = sh;
}

// ---------------- node update: h += silu(bn(t)) ----------------
__global__ __launch_bounds__(256) void k_nodeupd(const float* __restrict__ x1,
    const float* __restrict__ agg, const float* __restrict__ invd,
    const float* __restrict__ coef, float* __restrict__ h){
  int i = blockIdx.x*256 + threadIdx.x;
  if (i >= NN*64) return;
  int n = i>>6, f = i&63;
  float t = x1[i] + agg[i]*invd[n];
  float v = t*coef[f] + coef[64+f];
  h[i] += silu_(v);
}

// ---------------- edge pass B (elementwise): w' = w + silu(bn(u)) ----------------
// FIRST: read eattr f32 (+silu) else wb16. LAST: write f32 d_out else wb16.
template<int FIRST, int LAST>
__global__ __launch_bounds__(256) void k_edgeBew(const float* __restrict__ ea,
    const unsigned short* __restrict__ wb_in,
    const unsigned short* __restrict__ u_bf,
    const float* __restrict__ coef,
    unsigned short* __restrict__ wb_out, float* __restrict__ wout){
  int i = blockIdx.x*256 + threadIdx.x;      // over E*64/8 groups
  int f0 = (i*8) & 63;
  float w[8];
  if (FIRST){
    float4 a = ((const float4*)ea)[i*2], b = ((const float4*)ea)[i*2+1];
    w[0]=silu_(a.x); w[1]=silu_(a.y); w[2]=silu_(a.z); w[3]=silu_(a.w);
    w[4]=silu_(b.x); w[5]=silu_(b.y); w[6]=silu_(b.z); w[7]=silu_(b.w);
  } else {
    ushort8 v = ((const ushort8*)wb_in)[i];
    #pragma unroll
    for (int j=0;j<8;++j) w[j] = bf2f(v[j]);
  }
  ushort8 ub = ((const ushort8*)u_bf)[i];
  float4 sc0 = *(const float4*)(coef + 128 + f0);
  float4 sc1 = *(const float4*)(coef + 128 + f0 + 4);
  float4 sh0 = *(const float4*)(coef + 192 + f0);
  float4 sh1 = *(const float4*)(coef + 192 + f0 + 4);
  float o[8];
  o[0] = w[0] + silu_(bf2f(ub[0])*sc0.x + sh0.x);
  o[1] = w[1] + silu_(bf2f(ub[1])*sc0.y + sh0.y);
  o[2] = w[2] + silu_(bf2f(ub[2])*sc0.z + sh0.z);
  o[3] = w[3] + silu_(bf2f(ub[3])*sc0.w + sh0.w);
  o[4] = w[4] + silu_(bf2f(ub[4])*sc1.x + sh1.x);
  o[5] = w[5] + silu_(bf2f(ub[5])*sc1.y + sh1.y);
  o[6] = w[6] + silu_(bf2f(ub[6])*sc1.z + sh1.z);
  o[7] = w[7] + silu_(bf2f(ub[7])*sc1.w + sh1.w);
  if (LAST){
    float4 oa = make_float4(o[0],o[1],o[2],o[3]);
    float4 ob = make_float4(o[4],o[5],o[6],o[7]);
    ((float4*)wout)[i*2]   = oa;
    ((float4*)wout)[i*2+1] = ob;
  } else {
    ushort8 v;
    #pragma unroll
    for (int j=0;j<8;++j) v[j] = f2bf(o[j]);
    ((ushort8*)wb_out)[i] = v;
  }
}

// ---------------- launch ----------------

extern "C" void kernel_launch(void* const* d_in, const int* in_sizes, int n_in,
                              void* d_out, int out_size, void* d_ws, size_t ws_size,
                              hipStream_t stream){
  const float* x      = (const float*)d_in[0];
  const int*   eidx   = (const int*)d_in[1];
  const float* eattr  = (const float*)d_in[2];
  const float* Wv     = (const float*)d_in[3];
  const float* bv     = (const float*)d_in[4];
  const float* We     = (const float*)d_in[5];
  const float* be     = (const float*)d_in[6];
  const float* g_node = (const float*)d_in[7];
  const float* b_node = (const float*)d_in[8];
  const float* g_edge = (const float*)d_in[9];
  const float* b_edge = (const float*)d_in[10];
  const int* src = eidx;
  const int* dst = eidx + NE;

  float* hout = (float*)d_out;                 // [N][64] live node state (f32)
  float* wout = hout + (size_t)NN*64;          // [E][64] final edge output (f32)

  float* W    = (float*)d_ws;
  float* x1   = W;                                          // N*64 f32
  unsigned short* xb = (unsigned short*)(W + 3200000);      // 3*N*64 bf16 (x2,x3,x4)
  float* agg  = W + 8000000;                                // N*64 f32
  float* nsum = W + 11200000;                               // 64*64
  float* nsq  = W + 11204096;
  float* esum = W + 11208192;
  float* esq  = W + 11212288;
  float* coef = W + 11216384;                               // 4*64
  int*   deg  = (int*)(W + 11216640);                       // N ints
  float* invd = W + 11266640;                               // N f32
  unsigned short* wes  = (unsigned short*)(W + 11316640);   // 3*4096 bf16 swizzled
  unsigned short* u_bf = (unsigned short*)(W + 11322784);   // E*64 bf16
  unsigned short* wb16 = (unsigned short*)(W + 36922784);   // E*64 bf16 (live edge state)

  hipMemsetAsync(deg, 0, NN*sizeof(int), stream);
  k_silu4<<<3125, 256, 0, stream>>>(x, hout, 800000);
  k_deg<<<(NE+255)/256, 256, 0, stream>>>(src, deg);
  k_invdeg<<<(NN+255)/256, 256, 0, stream>>>(deg, invd);
  k_prepWe<<<3, 256, 0, stream>>>(We, wes);

  const unsigned short* x2 = xb;
  const unsigned short* x3 = xb + (size_t)NN*64;
  const unsigned short* x4 = xb + (size_t)2*NN*64;

  for (int l=0; l<3; ++l){
    hipMemsetAsync(agg, 0, (3200000 + 4*4096 + 256)*sizeof(float), stream);
    k_nodelin<<<dim3(782,4), 256, 0, stream>>>(hout, Wv + l*4*4096, bv + l*256, x1, xb);
    if (l == 0)
      k_edgeA<1><<<12500, 256, 0, stream>>>(eattr, wb16, src, dst, wes + l*4096,
          be + l*64, x2, x3, x4, agg, esum, esq, u_bf);
    else
      k_edgeA<0><<<12500, 256, 0, stream>>>(eattr, wb16, src, dst, wes + l*4096,
          be + l*64, x2, x3, x4, agg, esum, esq, u_bf);
    k_nodestats<<<128, 256, 0, stream>>>(x1, agg, invd, nsum, nsq);
    k_finalize<<<1, 128, 0, stream>>>(nsum, nsq, esum, esq,
        g_node + l*64, b_node + l*64, g_edge + l*64, b_edge + l*64, coef);
    k_nodeupd<<<12500, 256, 0, stream>>>(x1, agg, invd, coef, hout);
    if (l == 0)
      k_edgeBew<1,0><<<25000, 256, 0, stream>>>(eattr, wb16, u_bf, coef, wb16, wout);
    else if (l == 1)
      k_edgeBew<0,0><<<25000, 256, 0, stream>>>(eattr, wb16, u_bf, coef, wb16, wout);
    else
      k_edgeBew<0,1><<<25000, 256, 0, stream>>>(eattr, wb16, u_bf, coef, wb16, wout);
  }
}

// Round 5
// 1014.172 us; speedup vs baseline: 4.3342x; 1.1129x over previous
//
#include <hip/hip_runtime.h>

#define NN 50000
#define NE 800000
#define EPSB 1e-5f

typedef __attribute__((ext_vector_type(8))) short bf16x8;
typedef __attribute__((ext_vector_type(8))) unsigned short ushort8;
typedef __attribute__((ext_vector_type(4))) float f32x4;

__device__ __forceinline__ float sigm(float x){ return 1.0f/(1.0f+__expf(-x)); }
__device__ __forceinline__ float silu_(float x){ return x/(1.0f+__expf(-x)); }
__device__ __forceinline__ unsigned short f2bf(float x){
  unsigned int u = __float_as_uint(x);
  return (unsigned short)((u + 0x7FFFu + ((u>>16)&1u)) >> 16);   // RNE
}
__device__ __forceinline__ float bf2f(unsigned short b){
  return __uint_as_float(((unsigned int)b)<<16);
}

// ---------------- elementwise / prep ----------------

__global__ __launch_bounds__(256) void k_silu4(const float* __restrict__ in,
                                               float* __restrict__ out, int n4){
  int i = blockIdx.x*256 + threadIdx.x;
  if (i < n4){
    float4 v = ((const float4*)in)[i];
    v.x = silu_(v.x); v.y = silu_(v.y); v.z = silu_(v.z); v.w = silu_(v.w);
    ((float4*)out)[i] = v;
  }
}

__global__ __launch_bounds__(256) void k_deg(const int* __restrict__ src,
                                             int* __restrict__ deg){
  int e = blockIdx.x*256 + threadIdx.x;
  if (e < NE) atomicAdd(&deg[src[e]], 1);
}

__global__ __launch_bounds__(256) void k_invdeg(const int* __restrict__ deg,
                                                float* __restrict__ invd){
  int n = blockIdx.x*256 + threadIdx.x;
  if (n < NN) invd[n] = 1.0f / fmaxf((float)deg[n], 1.0f);
}

// pre-convert all 15 weight mats (Wv 3x4 + We 3x1) to bf16, XOR-swizzled
__global__ __launch_bounds__(256) void k_prepW(const float* __restrict__ Wv,
    const float* __restrict__ We,
    unsigned short* __restrict__ wvs, unsigned short* __restrict__ wes){
  const int m = blockIdx.x;
  const float* S = (m < 12) ? (Wv + m*4096) : (We + (m-12)*4096);
  unsigned short* O = (m < 12) ? (wvs + m*4096) : (wes + (m-12)*4096);
  int t = threadIdx.x;
  #pragma unroll
  for (int p=0; p<2; ++p){
    int c = t + p*256;          // 512 chunks of 8
    int row = c>>3, cc = c&7;
    const float4* sp = (const float4*)(S + row*64 + cc*8);
    float4 a = sp[0], b = sp[1];
    ushort8 v;
    v[0]=f2bf(a.x); v[1]=f2bf(a.y); v[2]=f2bf(a.z); v[3]=f2bf(a.w);
    v[4]=f2bf(b.x); v[5]=f2bf(b.y); v[6]=f2bf(b.z); v[7]=f2bf(b.w);
    *(ushort8*)((char*)O + ((row*128 + cc*16) ^ ((row&7)<<4))) = v;
  }
}

// ---------------- node linears (MFMA) + fused h-update ----------------
// 64 nodes/block, 4 waves; wave wid owns nodes wid*16..+15.
// FUSE: h += silu(bn_prev(x1 + agg*invd)) applied during staging (own rows only).
template<int FUSE>
__global__ __launch_bounds__(256) void k_nodelin(float* __restrict__ h,
    float* __restrict__ x1, const float* __restrict__ agg,
    const float* __restrict__ invd, const float* __restrict__ coefp,
    const unsigned short* __restrict__ wvs, const float* __restrict__ bvl,
    unsigned short* __restrict__ xb){
  __shared__ unsigned short shb[4096];   // h tile bf16 swizzled
  __shared__ unsigned short sW[4096];    // current weight mat
  const int n0 = blockIdx.x*64;
  const int t = threadIdx.x;
  #pragma unroll
  for (int p=0; p<2; ++p){
    int c = t + p*256;
    int row = c>>3, cc = c&7;
    int n = n0 + row;
    ushort8 v = {0,0,0,0,0,0,0,0};
    if (n < NN){
      float4* hp = (float4*)(h + (size_t)n*64 + cc*8);
      float4 a = hp[0], b = hp[1];
      if (FUSE){
        const float4* xp = (const float4*)(x1 + (size_t)n*64 + cc*8);
        const float4* gp = (const float4*)(agg + (size_t)n*64 + cc*8);
        float iv = invd[n];
        float4 xa = xp[0], xb4 = xp[1], ga = gp[0], gb = gp[1];
        float4 s0 = *(const float4*)(coefp + cc*8);
        float4 s1v = *(const float4*)(coefp + cc*8 + 4);
        float4 h0 = *(const float4*)(coefp + 64 + cc*8);
        float4 h1 = *(const float4*)(coefp + 64 + cc*8 + 4);
        a.x += silu_((xa.x + ga.x*iv)*s0.x + h0.x);
        a.y += silu_((xa.y + ga.y*iv)*s0.y + h0.y);
        a.z += silu_((xa.z + ga.z*iv)*s0.z + h0.z);
        a.w += silu_((xa.w + ga.w*iv)*s0.w + h0.w);
        b.x += silu_((xb4.x + gb.x*iv)*s1v.x + h1.x);
        b.y += silu_((xb4.y + gb.y*iv)*s1v.y + h1.y);
        b.z += silu_((xb4.z + gb.z*iv)*s1v.z + h1.z);
        b.w += silu_((xb4.w + gb.w*iv)*s1v.w + h1.w);
        hp[0] = a; hp[1] = b;
      }
      v[0]=f2bf(a.x); v[1]=f2bf(a.y); v[2]=f2bf(a.z); v[3]=f2bf(a.w);
      v[4]=f2bf(b.x); v[5]=f2bf(b.y); v[6]=f2bf(b.z); v[7]=f2bf(b.w);
    }
    *(ushort8*)((char*)shb + ((row*128 + cc*16) ^ ((row&7)<<4))) = v;
  }
  __syncthreads();
  const int wid = t>>6, lane = t&63, g = lane>>4, ln = lane&15;
  const int arow = wid*16 + ln;
  bf16x8 afr0 = *(bf16x8*)((char*)shb + ((arow*128 +  0 + g*16) ^ ((arow&7)<<4)));
  bf16x8 afr1 = *(bf16x8*)((char*)shb + ((arow*128 + 64 + g*16) ^ ((arow&7)<<4)));
  for (int k=0; k<4; ++k){
    __syncthreads();    // prior iter's sW reads complete
    ((ushort8*)sW)[t]     = ((const ushort8*)(wvs + k*4096))[t];
    ((ushort8*)sW)[t+256] = ((const ushort8*)(wvs + k*4096))[t+256];
    __syncthreads();
    #pragma unroll
    for (int ft=0; ft<4; ++ft){
      int brow = ft*16 + ln;            // = output feature f
      bf16x8 b0 = *(bf16x8*)((char*)sW + ((brow*128 +  0 + g*16) ^ ((brow&7)<<4)));
      bf16x8 b1 = *(bf16x8*)((char*)sW + ((brow*128 + 64 + g*16) ^ ((brow&7)<<4)));
      f32x4 c = {0.f,0.f,0.f,0.f};
      c = __builtin_amdgcn_mfma_f32_16x16x32_bf16(afr0, b0, c, 0,0,0);
      c = __builtin_amdgcn_mfma_f32_16x16x32_bf16(afr1, b1, c, 0,0,0);
      float bias = bvl[k*64 + brow];
      #pragma unroll
      for (int r=0; r<4; ++r){
        int n = n0 + wid*16 + g*4 + r;
        if (n < NN){
          float val = c[r] + bias;
          if (k == 0) x1[(size_t)n*64 + brow] = val;
          else xb[(size_t)(k-1)*NN*64 + (size_t)n*64 + brow] = f2bf(val);
        }
      }
    }
  }
}

// ---------------- edge pass A (MFMA) + fused w-state update ----------------
// 64 edges/block, 4 waves. Staging: w_l = w_{l-1} + silu(bn_prev(u_{l-1}))
// (or silu(eattr) for FIRST), written back to wb16 + swizzled LDS.
// Then u_l = w_l@We^T + be + x3[src]+x4[dst]; stats; u->LDS->coalesced store; messages.
template<int FIRST>
__global__ __launch_bounds__(256) void k_edgeA(const float* __restrict__ ea,
    unsigned short* __restrict__ wb16,
    const int* __restrict__ src, const int* __restrict__ dst,
    const unsigned short* __restrict__ wes, const float* __restrict__ be,
    const unsigned short* __restrict__ x2, const unsigned short* __restrict__ x3,
    const unsigned short* __restrict__ x4, const float* __restrict__ coefp,
    float* __restrict__ agg, float* __restrict__ esum, float* __restrict__ esq,
    unsigned short* __restrict__ u_bf){
  __shared__ unsigned short sWb[4096];   // We; reused for u staging after frag reads
  __shared__ unsigned short swb[4096];   // w tile
  __shared__ unsigned short sx3[4096], sx4[4096];
  __shared__ int sidx[128];
  const int e0 = blockIdx.x*64;
  const int t = threadIdx.x;

  if (t < 64) sidx[t] = src[e0+t];
  else if (t < 128) sidx[t] = dst[e0+t-64];
  ((ushort8*)sWb)[t]     = ((const ushort8*)wes)[t];
  ((ushort8*)sWb)[t+256] = ((const ushort8*)wes)[t+256];

  // stage w state (+fused update), write back to global
  #pragma unroll
  for (int p=0; p<2; ++p){
    int c = t + p*256;
    int row = c>>3, cc = c&7;
    ushort8 v;
    if (FIRST){
      const float4* sp = (const float4*)(ea + (size_t)(e0+row)*64 + cc*8);
      float4 a = sp[0], b = sp[1];
      v[0]=f2bf(silu_(a.x)); v[1]=f2bf(silu_(a.y)); v[2]=f2bf(silu_(a.z)); v[3]=f2bf(silu_(a.w));
      v[4]=f2bf(silu_(b.x)); v[5]=f2bf(silu_(b.y)); v[6]=f2bf(silu_(b.z)); v[7]=f2bf(silu_(b.w));
    } else {
      ushort8 wv = ((const ushort8*)(wb16 + (size_t)e0*64))[c];
      ushort8 uv = ((const ushort8*)(u_bf + (size_t)e0*64))[c];
      int f0 = cc*8;
      float4 s0 = *(const float4*)(coefp + 128 + f0);
      float4 s1v = *(const float4*)(coefp + 128 + f0 + 4);
      float4 h0 = *(const float4*)(coefp + 192 + f0);
      float4 h1 = *(const float4*)(coefp + 192 + f0 + 4);
      v[0] = f2bf(bf2f(wv[0]) + silu_(bf2f(uv[0])*s0.x + h0.x));
      v[1] = f2bf(bf2f(wv[1]) + silu_(bf2f(uv[1])*s0.y + h0.y));
      v[2] = f2bf(bf2f(wv[2]) + silu_(bf2f(uv[2])*s0.z + h0.z));
      v[3] = f2bf(bf2f(wv[3]) + silu_(bf2f(uv[3])*s0.w + h0.w));
      v[4] = f2bf(bf2f(wv[4]) + silu_(bf2f(uv[4])*s1v.x + h1.x));
      v[5] = f2bf(bf2f(wv[5]) + silu_(bf2f(uv[5])*s1v.y + h1.y));
      v[6] = f2bf(bf2f(wv[6]) + silu_(bf2f(uv[6])*s1v.z + h1.z));
      v[7] = f2bf(bf2f(wv[7]) + silu_(bf2f(uv[7])*s1v.w + h1.w));
    }
    ((ushort8*)(wb16 + (size_t)e0*64))[c] = v;
    *(ushort8*)((char*)swb + ((row*128 + cc*16) ^ ((row&7)<<4))) = v;
  }
  __syncthreads();   // B1: sidx, sWb, swb visible

  // gather x3/x4 rows into LDS (16B chunks)
  #pragma unroll
  for (int p=0; p<2; ++p){
    int c = t + p*256;
    int row = c>>3, cc = c&7;
    int s  = sidx[row];
    int d2 = sidx[64+row];
    ushort8 a = *(const ushort8*)(x3 + (size_t)s*64  + cc*8);
    ushort8 b = *(const ushort8*)(x4 + (size_t)d2*64 + cc*8);
    *(ushort8*)((char*)sx3 + ((row*128 + cc*16) ^ ((row&7)<<4))) = a;
    *(ushort8*)((char*)sx4 + ((row*128 + cc*16) ^ ((row&7)<<4))) = b;
  }

  const int wid = t>>6, lane = t&63, g = lane>>4, ln = lane&15;
  const int arow = wid*16 + ln;
  bf16x8 afr0 = *(bf16x8*)((char*)swb + ((arow*128 +  0 + g*16) ^ ((arow&7)<<4)));
  bf16x8 afr1 = *(bf16x8*)((char*)swb + ((arow*128 + 64 + g*16) ^ ((arow&7)<<4)));
  bf16x8 bfr[4][2];
  #pragma unroll
  for (int ft=0; ft<4; ++ft){
    int brow = ft*16 + ln;
    bfr[ft][0] = *(bf16x8*)((char*)sWb + ((brow*128 +  0 + g*16) ^ ((brow&7)<<4)));
    bfr[ft][1] = *(bf16x8*)((char*)sWb + ((brow*128 + 64 + g*16) ^ ((brow&7)<<4)));
  }
  __syncthreads();   // B2: sx3/sx4 visible; all sWb frag reads done (sWb reusable)

  f32x4 cacc[4];
  #pragma unroll
  for (int ft=0; ft<4; ++ft){
    f32x4 c = {0.f,0.f,0.f,0.f};
    c = __builtin_amdgcn_mfma_f32_16x16x32_bf16(afr0, bfr[ft][0], c, 0,0,0);
    c = __builtin_amdgcn_mfma_f32_16x16x32_bf16(afr1, bfr[ft][1], c, 0,0,0);
    cacc[ft] = c;
  }

  // phase 1: u, stats, u -> sWb
  float bef[4];
  #pragma unroll
  for (int ft=0; ft<4; ++ft) bef[ft] = be[ft*16+ln];
  float s1[4]={0.f,0.f,0.f,0.f}, s2[4]={0.f,0.f,0.f,0.f};
  #pragma unroll
  for (int r=0; r<4; ++r){
    int row = wid*16 + g*4 + r;
    #pragma unroll
    for (int ft=0; ft<4; ++ft){
      int f = ft*16 + ln;
      unsigned short a3 = *(unsigned short*)((char*)sx3 + ((row*128 + f*2) ^ ((row&7)<<4)));
      unsigned short a4 = *(unsigned short*)((char*)sx4 + ((row*128 + f*2) ^ ((row&7)<<4)));
      float u = cacc[ft][r] + bef[ft] + bf2f(a3) + bf2f(a4);
      s1[ft] += u; s2[ft] += u*u;
      *(unsigned short*)((char*)sWb + ((row*128 + f*2) ^ ((row&7)<<4))) = f2bf(u);
    }
  }
  #pragma unroll
  for (int ft=0; ft<4; ++ft){
    s1[ft] += __shfl_xor(s1[ft], 16); s1[ft] += __shfl_xor(s1[ft], 32);
    s2[ft] += __shfl_xor(s2[ft], 16); s2[ft] += __shfl_xor(s2[ft], 32);
  }
  if (g == 0){
    int slot = ((blockIdx.x<<2) + wid) & 63;
    #pragma unroll
    for (int ft=0; ft<4; ++ft){
      atomicAdd(&esum[(slot<<6) + ft*16 + ln], s1[ft]);
      atomicAdd(&esq [(slot<<6) + ft*16 + ln], s2[ft]);
    }
  }
  __syncthreads();   // B3: u staged in sWb

  // u coalesced store
  #pragma unroll
  for (int p=0; p<2; ++p){
    int c = t + p*256;
    int row = c>>3, cc = c&7;
    ushort8 v = *(ushort8*)((char*)sWb + ((row*128 + cc*16) ^ ((row&7)<<4)));
    ((ushort8*)(u_bf + (size_t)e0*64))[c] = v;
  }

  // phase 2: gated messages
  #pragma unroll
  for (int j=0; j<16; ++j){
    int el = (wid<<4) + j;
    int s  = sidx[el];
    int d2 = sidx[64+el];
    unsigned short wv = *(unsigned short*)((char*)swb + ((el*128 + lane*2) ^ ((el&7)<<4)));
    float m = sigm(bf2f(wv)) * bf2f(x2[(size_t)d2*64 + lane]);
    atomicAdd(&agg[(size_t)s*64 + lane], m);
  }
}

// ---------------- node BN stats over t = x1 + agg*invdeg ----------------
__global__ __launch_bounds__(256) void k_nodestats(const float* __restrict__ x1,
    const float* __restrict__ agg, const float* __restrict__ invd,
    float* __restrict__ nsum, float* __restrict__ nsq){
  const int f = threadIdx.x & 63, sub = threadIdx.x >> 6;
  float s1=0.f, s2=0.f;
  for (int n = blockIdx.x*4 + sub; n < NN; n += gridDim.x*4){
    float t = x1[(size_t)n*64+f] + agg[(size_t)n*64+f]*invd[n];
    s1 += t; s2 += t*t;
  }
  __shared__ float red[4][64][2];
  red[sub][f][0]=s1; red[sub][f][1]=s2;
  __syncthreads();
  if (sub==0){
    float a1=red[0][f][0]+red[1][f][0]+red[2][f][0]+red[3][f][0];
    float a2=red[0][f][1]+red[1][f][1]+red[2][f][1]+red[3][f][1];
    int slot = blockIdx.x & 63;
    atomicAdd(&nsum[(slot<<6)+f], a1);
    atomicAdd(&nsq[(slot<<6)+f], a2);
  }
}

// ---------------- finalize both BN -> per-layer coef slot ----------------
__global__ void k_finalize(const float* __restrict__ nsum, const float* __restrict__ nsq,
    const float* __restrict__ esum, const float* __restrict__ esq,
    const float* __restrict__ gn, const float* __restrict__ bn,
    const float* __restrict__ ge, const float* __restrict__ beb,
    float* __restrict__ coef){
  int t = threadIdx.x;
  if (t >= 128) return;
  int f = t & 63;
  const float* S1 = (t<64)? nsum : esum;
  const float* S2 = (t<64)? nsq  : esq;
  float cnt = (t<64)? (float)NN : (float)NE;
  float s1=0.f, s2=0.f;
  for (int k=0;k<64;++k){ s1 += S1[(k<<6)+f]; s2 += S2[(k<<6)+f]; }
  float mu = s1/cnt;
  float var = s2/cnt - mu*mu;
  float rstd = rsqrtf(var + EPSB);
  float g = (t<64)? gn[f] : ge[f];
  float b = (t<64)? bn[f] : beb[f];
  float sc = g*rstd, sh = b - mu*sc;
  coef[((t<64)?0:2)*64 + f] = sc;
  coef[((t<64)?1:3)*64 + f] = sh;
}

// ---------------- final node update: h += silu(bn(t)) ----------------
__global__ __launch_bounds__(256) void k_nodeupd(const float* __restrict__ x1,
    const float* __restrict__ agg, const float* __restrict__ invd,
    const float* __restrict__ coef, float* __restrict__ h){
  int i = blockIdx.x*256 + threadIdx.x;
  if (i >= NN*64) return;
  int n = i>>6, f = i&63;
  float t = x1[i] + agg[i]*invd[n];
  float v = t*coef[f] + coef[64+f];
  h[i] += silu_(v);
}

// ---------------- final edge output: wout = w2 + silu(bn(u2)) (f32) ----------------
__global__ __launch_bounds__(256) void k_edgeBfin(const unsigned short* __restrict__ wb16,
    const unsigned short* __restrict__ u_bf, const float* __restrict__ coef,
    float* __restrict__ wout){
  int i = blockIdx.x*256 + threadIdx.x;      // E*64/8 groups
  int f0 = (i*8) & 63;
  ushort8 wv = ((const ushort8*)wb16)[i];
  ushort8 ub = ((const ushort8*)u_bf)[i];
  float4 s0 = *(const float4*)(coef + 128 + f0);
  float4 s1v = *(const float4*)(coef + 128 + f0 + 4);
  float4 h0 = *(const float4*)(coef + 192 + f0);
  float4 h1 = *(const float4*)(coef + 192 + f0 + 4);
  float4 oa, ob;
  oa.x = bf2f(wv[0]) + silu_(bf2f(ub[0])*s0.x + h0.x);
  oa.y = bf2f(wv[1]) + silu_(bf2f(ub[1])*s0.y + h0.y);
  oa.z = bf2f(wv[2]) + silu_(bf2f(ub[2])*s0.z + h0.z);
  oa.w = bf2f(wv[3]) + silu_(bf2f(ub[3])*s0.w + h0.w);
  ob.x = bf2f(wv[4]) + silu_(bf2f(ub[4])*s1v.x + h1.x);
  ob.y = bf2f(wv[5]) + silu_(bf2f(ub[5])*s1v.y + h1.y);
  ob.z = bf2f(wv[6]) + silu_(bf2f(ub[6])*s1v.z + h1.z);
  ob.w = bf2f(wv[7]) + silu_(bf2f(ub[7])*s1v.w + h1.w);
  ((float4*)wout)[i*2]   = oa;
  ((float4*)wout)[i*2+1] = ob;
}

// ---------------- launch ----------------

extern "C" void kernel_launch(void* const* d_in, const int* in_sizes, int n_in,
                              void* d_out, int out_size, void* d_ws, size_t ws_size,
                              hipStream_t stream){
  const float* x      = (const float*)d_in[0];
  const int*   eidx   = (const int*)d_in[1];
  const float* eattr  = (const float*)d_in[2];
  const float* Wv     = (const float*)d_in[3];
  const float* bv     = (const float*)d_in[4];
  const float* We     = (const float*)d_in[5];
  const float* be     = (const float*)d_in[6];
  const float* g_node = (const float*)d_in[7];
  const float* b_node = (const float*)d_in[8];
  const float* g_edge = (const float*)d_in[9];
  const float* b_edge = (const float*)d_in[10];
  const int* src = eidx;
  const int* dst = eidx + NE;

  float* hout = (float*)d_out;                 // [N][64] live node state (f32)
  float* wout = hout + (size_t)NN*64;          // [E][64] final edge output (f32)

  float* W    = (float*)d_ws;
  float* x1   = W;                                           // 3.2M f32
  float* agg  = W + 3200000;                                 // 3.2M f32
  float* nsum = W + 6400000;                                 // 4096
  float* nsq  = W + 6404096;
  float* esum = W + 6408192;
  float* esq  = W + 6412288;
  float* coef = W + 6416384;                                 // 3*256
  float* invd = W + 6417152;                                 // 50000
  int*   deg  = (int*)(W + 6467152);                         // 50000
  unsigned short* xb   = (unsigned short*)(W + 6517152);     // 3*3.2M bf16
  unsigned short* wvs  = (unsigned short*)(W + 11317152);    // 12*4096 bf16 swz
  unsigned short* wes  = (unsigned short*)(W + 11341728);    // 3*4096 bf16 swz
  unsigned short* u_bf = (unsigned short*)(W + 11347872);    // E*64 bf16
  unsigned short* wb16 = (unsigned short*)(W + 36947872);    // E*64 bf16

  hipMemsetAsync(deg, 0, NN*sizeof(int), stream);
  k_silu4<<<3125, 256, 0, stream>>>(x, hout, 800000);
  k_deg<<<(NE+255)/256, 256, 0, stream>>>(src, deg);
  k_invdeg<<<(NN+255)/256, 256, 0, stream>>>(deg, invd);
  k_prepW<<<15, 256, 0, stream>>>(Wv, We, wvs, wes);

  const unsigned short* x2 = xb;
  const unsigned short* x3 = xb + (size_t)NN*64;
  const unsigned short* x4 = xb + (size_t)2*NN*64;

  for (int l=0; l<3; ++l){
    const float* cprev = coef + (l-1)*256;    // valid for l>=1
    if (l == 0)
      k_nodelin<0><<<782, 256, 0, stream>>>(hout, x1, agg, invd, coef,
          wvs + l*16384, bv + l*256, xb);
    else
      k_nodelin<1><<<782, 256, 0, stream>>>(hout, x1, agg, invd, cprev,
          wvs + l*16384, bv + l*256, xb);
    hipMemsetAsync(agg, 0, (3200000 + 4*4096)*sizeof(float), stream);
    if (l == 0)
      k_edgeA<1><<<12500, 256, 0, stream>>>(eattr, wb16, src, dst, wes + l*4096,
          be + l*64, x2, x3, x4, coef, agg, esum, esq, u_bf);
    else
      k_edgeA<0><<<12500, 256, 0, stream>>>(eattr, wb16, src, dst, wes + l*4096,
          be + l*64, x2, x3, x4, cprev, agg, esum, esq, u_bf);
    k_nodestats<<<128, 256, 0, stream>>>(x1, agg, invd, nsum, nsq);
    k_finalize<<<1, 128, 0, stream>>>(nsum, nsq, esum, esq,
        g_node + l*64, b_node + l*64, g_edge + l*64, b_edge + l*64, coef + l*256);
  }
  // final state updates (layer 2 coef)
  k_nodeupd<<<12500, 256, 0, stream>>>(x1, agg, invd, coef + 512, hout);
  k_edgeBfin<<<25000, 256, 0, stream>>>(wb16, u_bf, coef + 512, wout);
}

// Round 6
// 1012.004 us; speedup vs baseline: 4.3435x; 1.0021x over previous
//
#include <hip/hip_runtime.h>

#define NN 50000
#define NE 800000
#define EPSB 1e-5f

typedef __attribute__((ext_vector_type(8))) short bf16x8;
typedef __attribute__((ext_vector_type(8))) unsigned short ushort8;
typedef __attribute__((ext_vector_type(4))) float f32x4;

__device__ __forceinline__ float sigm(float x){ return 1.0f/(1.0f+__expf(-x)); }
__device__ __forceinline__ float silu_(float x){ return x/(1.0f+__expf(-x)); }
__device__ __forceinline__ unsigned short f2bf(float x){
  unsigned int u = __float_as_uint(x);
  return (unsigned short)((u + 0x7FFFu + ((u>>16)&1u)) >> 16);   // RNE
}
__device__ __forceinline__ float bf2f(unsigned short b){
  return __uint_as_float(((unsigned int)b)<<16);
}

// ---------------- elementwise / prep ----------------

__global__ __launch_bounds__(256) void k_silu4(const float* __restrict__ in,
                                               float* __restrict__ out, int n4){
  int i = blockIdx.x*256 + threadIdx.x;
  if (i < n4){
    float4 v = ((const float4*)in)[i];
    v.x = silu_(v.x); v.y = silu_(v.y); v.z = silu_(v.z); v.w = silu_(v.w);
    ((float4*)out)[i] = v;
  }
}

__global__ __launch_bounds__(256) void k_deg(const int* __restrict__ src,
                                             int* __restrict__ deg){
  int e = blockIdx.x*256 + threadIdx.x;
  if (e < NE) atomicAdd(&deg[src[e]], 1);
}

__global__ __launch_bounds__(256) void k_invdeg(const int* __restrict__ deg,
                                                float* __restrict__ invd){
  int n = blockIdx.x*256 + threadIdx.x;
  if (n < NN) invd[n] = 1.0f / fmaxf((float)deg[n], 1.0f);
}

// pre-convert all 15 weight mats (Wv 3x4 + We 3x1) to bf16, XOR-swizzled
__global__ __launch_bounds__(256) void k_prepW(const float* __restrict__ Wv,
    const float* __restrict__ We,
    unsigned short* __restrict__ wvs, unsigned short* __restrict__ wes){
  const int m = blockIdx.x;
  const float* S = (m < 12) ? (Wv + m*4096) : (We + (m-12)*4096);
  unsigned short* O = (m < 12) ? (wvs + m*4096) : (wes + (m-12)*4096);
  int t = threadIdx.x;
  #pragma unroll
  for (int p=0; p<2; ++p){
    int c = t + p*256;          // 512 chunks of 8
    int row = c>>3, cc = c&7;
    const float4* sp = (const float4*)(S + row*64 + cc*8);
    float4 a = sp[0], b = sp[1];
    ushort8 v;
    v[0]=f2bf(a.x); v[1]=f2bf(a.y); v[2]=f2bf(a.z); v[3]=f2bf(a.w);
    v[4]=f2bf(b.x); v[5]=f2bf(b.y); v[6]=f2bf(b.z); v[7]=f2bf(b.w);
    *(ushort8*)((char*)O + ((row*128 + cc*16) ^ ((row&7)<<4))) = v;
  }
}

// ---------------- node linears (MFMA) + fused h-update ----------------
// 64 nodes/block, 4 waves; wave wid owns nodes wid*16..+15.
// FUSE: h += silu(bn_prev(x1 + agg*invd)) applied during staging (own rows only).
template<int FUSE>
__global__ __launch_bounds__(256) void k_nodelin(float* __restrict__ h,
    float* __restrict__ x1, const float* __restrict__ agg,
    const float* __restrict__ invd, const float* __restrict__ coefp,
    const unsigned short* __restrict__ wvs, const float* __restrict__ bvl,
    unsigned short* __restrict__ xb){
  __shared__ unsigned short shb[4096];   // h tile bf16 swizzled
  __shared__ unsigned short sW[4096];    // current weight mat
  const int n0 = blockIdx.x*64;
  const int t = threadIdx.x;
  #pragma unroll
  for (int p=0; p<2; ++p){
    int c = t + p*256;
    int row = c>>3, cc = c&7;
    int n = n0 + row;
    ushort8 v = {0,0,0,0,0,0,0,0};
    if (n < NN){
      float4* hp = (float4*)(h + (size_t)n*64 + cc*8);
      float4 a = hp[0], b = hp[1];
      if (FUSE){
        const float4* xp = (const float4*)(x1 + (size_t)n*64 + cc*8);
        const float4* gp = (const float4*)(agg + (size_t)n*64 + cc*8);
        float iv = invd[n];
        float4 xa = xp[0], xb4 = xp[1], ga = gp[0], gb = gp[1];
        float4 s0 = *(const float4*)(coefp + cc*8);
        float4 s1v = *(const float4*)(coefp + cc*8 + 4);
        float4 h0 = *(const float4*)(coefp + 64 + cc*8);
        float4 h1 = *(const float4*)(coefp + 64 + cc*8 + 4);
        a.x += silu_((xa.x + ga.x*iv)*s0.x + h0.x);
        a.y += silu_((xa.y + ga.y*iv)*s0.y + h0.y);
        a.z += silu_((xa.z + ga.z*iv)*s0.z + h0.z);
        a.w += silu_((xa.w + ga.w*iv)*s0.w + h0.w);
        b.x += silu_((xb4.x + gb.x*iv)*s1v.x + h1.x);
        b.y += silu_((xb4.y + gb.y*iv)*s1v.y + h1.y);
        b.z += silu_((xb4.z + gb.z*iv)*s1v.z + h1.z);
        b.w += silu_((xb4.w + gb.w*iv)*s1v.w + h1.w);
        hp[0] = a; hp[1] = b;
      }
      v[0]=f2bf(a.x); v[1]=f2bf(a.y); v[2]=f2bf(a.z); v[3]=f2bf(a.w);
      v[4]=f2bf(b.x); v[5]=f2bf(b.y); v[6]=f2bf(b.z); v[7]=f2bf(b.w);
    }
    *(ushort8*)((char*)shb + ((row*128 + cc*16) ^ ((row&7)<<4))) = v;
  }
  __syncthreads();
  const int wid = t>>6, lane = t&63, g = lane>>4, ln = lane&15;
  const int arow = wid*16 + ln;
  bf16x8 afr0 = *(bf16x8*)((char*)shb + ((arow*128 +  0 + g*16) ^ ((arow&7)<<4)));
  bf16x8 afr1 = *(bf16x8*)((char*)shb + ((arow*128 + 64 + g*16) ^ ((arow&7)<<4)));
  for (int k=0; k<4; ++k){
    __syncthreads();    // prior iter's sW reads complete
    ((ushort8*)sW)[t]     = ((const ushort8*)(wvs + k*4096))[t];
    ((ushort8*)sW)[t+256] = ((const ushort8*)(wvs + k*4096))[t+256];
    __syncthreads();
    #pragma unroll
    for (int ft=0; ft<4; ++ft){
      int brow = ft*16 + ln;            // = output feature f
      bf16x8 b0 = *(bf16x8*)((char*)sW + ((brow*128 +  0 + g*16) ^ ((brow&7)<<4)));
      bf16x8 b1 = *(bf16x8*)((char*)sW + ((brow*128 + 64 + g*16) ^ ((brow&7)<<4)));
      f32x4 c = {0.f,0.f,0.f,0.f};
      c = __builtin_amdgcn_mfma_f32_16x16x32_bf16(afr0, b0, c, 0,0,0);
      c = __builtin_amdgcn_mfma_f32_16x16x32_bf16(afr1, b1, c, 0,0,0);
      float bias = bvl[k*64 + brow];
      #pragma unroll
      for (int r=0; r<4; ++r){
        int n = n0 + wid*16 + g*4 + r;
        if (n < NN){
          float val = c[r] + bias;
          if (k == 0) x1[(size_t)n*64 + brow] = val;
          else xb[(size_t)(k-1)*NN*64 + (size_t)n*64 + brow] = f2bf(val);
        }
      }
    }
  }
}

// ---------------- edge pass A (MFMA) + fused w-state update ----------------
// 64 edges/block, 4 waves. Staging: w_l = w_{l-1} + silu(bn_prev(u_{l-1}))
// (or silu(eattr) for FIRST), written back to wb16 + swizzled LDS.
// Then u_l = w_l@We^T + be + x3[src]+x4[dst]; stats; u->LDS->coalesced store; messages.
template<int FIRST>
__global__ __launch_bounds__(256) void k_edgeA(const float* __restrict__ ea,
    unsigned short* __restrict__ wb16,
    const int* __restrict__ src, const int* __restrict__ dst,
    const unsigned short* __restrict__ wes, const float* __restrict__ be,
    const unsigned short* __restrict__ x2, const unsigned short* __restrict__ x3,
    const unsigned short* __restrict__ x4, const float* __restrict__ coefp,
    float* __restrict__ agg, float* __restrict__ esum, float* __restrict__ esq,
    unsigned short* __restrict__ u_bf){
  __shared__ unsigned short sWb[4096];   // We; reused for u staging after frag reads
  __shared__ unsigned short swb[4096];   // w tile
  __shared__ unsigned short sx3[4096], sx4[4096];
  __shared__ int sidx[128];
  const int e0 = blockIdx.x*64;
  const int t = threadIdx.x;

  if (t < 64) sidx[t] = src[e0+t];
  else if (t < 128) sidx[t] = dst[e0+t-64];
  ((ushort8*)sWb)[t]     = ((const ushort8*)wes)[t];
  ((ushort8*)sWb)[t+256] = ((const ushort8*)wes)[t+256];

  // stage w state (+fused update), write back to global
  #pragma unroll
  for (int p=0; p<2; ++p){
    int c = t + p*256;
    int row = c>>3, cc = c&7;
    ushort8 v;
    if (FIRST){
      const float4* sp = (const float4*)(ea + (size_t)(e0+row)*64 + cc*8);
      float4 a = sp[0], b = sp[1];
      v[0]=f2bf(silu_(a.x)); v[1]=f2bf(silu_(a.y)); v[2]=f2bf(silu_(a.z)); v[3]=f2bf(silu_(a.w));
      v[4]=f2bf(silu_(b.x)); v[5]=f2bf(silu_(b.y)); v[6]=f2bf(silu_(b.z)); v[7]=f2bf(silu_(b.w));
    } else {
      ushort8 wv = ((const ushort8*)(wb16 + (size_t)e0*64))[c];
      ushort8 uv = ((const ushort8*)(u_bf + (size_t)e0*64))[c];
      int f0 = cc*8;
      float4 s0 = *(const float4*)(coefp + 128 + f0);
      float4 s1v = *(const float4*)(coefp + 128 + f0 + 4);
      float4 h0 = *(const float4*)(coefp + 192 + f0);
      float4 h1 = *(const float4*)(coefp + 192 + f0 + 4);
      v[0] = f2bf(bf2f(wv[0]) + silu_(bf2f(uv[0])*s0.x + h0.x));
      v[1] = f2bf(bf2f(wv[1]) + silu_(bf2f(uv[1])*s0.y + h0.y));
      v[2] = f2bf(bf2f(wv[2]) + silu_(bf2f(uv[2])*s0.z + h0.z));
      v[3] = f2bf(bf2f(wv[3]) + silu_(bf2f(uv[3])*s0.w + h0.w));
      v[4] = f2bf(bf2f(wv[4]) + silu_(bf2f(uv[4])*s1v.x + h1.x));
      v[5] = f2bf(bf2f(wv[5]) + silu_(bf2f(uv[5])*s1v.y + h1.y));
      v[6] = f2bf(bf2f(wv[6]) + silu_(bf2f(uv[6])*s1v.z + h1.z));
      v[7] = f2bf(bf2f(wv[7]) + silu_(bf2f(uv[7])*s1v.w + h1.w));
    }
    ((ushort8*)(wb16 + (size_t)e0*64))[c] = v;
    *(ushort8*)((char*)swb + ((row*128 + cc*16) ^ ((row&7)<<4))) = v;
  }
  __syncthreads();   // B1: sidx, sWb, swb visible

  // gather x3/x4 rows into LDS (16B chunks)
  #pragma unroll
  for (int p=0; p<2; ++p){
    int c = t + p*256;
    int row = c>>3, cc = c&7;
    int s  = sidx[row];
    int d2 = sidx[64+row];
    ushort8 a = *(const ushort8*)(x3 + (size_t)s*64  + cc*8);
    ushort8 b = *(const ushort8*)(x4 + (size_t)d2*64 + cc*8);
    *(ushort8*)((char*)sx3 + ((row*128 + cc*16) ^ ((row&7)<<4))) = a;
    *(ushort8*)((char*)sx4 + ((row*128 + cc*16) ^ ((row&7)<<4))) = b;
  }

  const int wid = t>>6, lane = t&63, g = lane>>4, ln = lane&15;
  const int arow = wid*16 + ln;
  bf16x8 afr0 = *(bf16x8*)((char*)swb + ((arow*128 +  0 + g*16) ^ ((arow&7)<<4)));
  bf16x8 afr1 = *(bf16x8*)((char*)swb + ((arow*128 + 64 + g*16) ^ ((arow&7)<<4)));
  bf16x8 bfr[4][2];
  #pragma unroll
  for (int ft=0; ft<4; ++ft){
    int brow = ft*16 + ln;
    bfr[ft][0] = *(bf16x8*)((char*)sWb + ((brow*128 +  0 + g*16) ^ ((brow&7)<<4)));
    bfr[ft][1] = *(bf16x8*)((char*)sWb + ((brow*128 + 64 + g*16) ^ ((brow&7)<<4)));
  }
  __syncthreads();   // B2: sx3/sx4 visible; all sWb frag reads done (sWb reusable)

  f32x4 cacc[4];
  #pragma unroll
  for (int ft=0; ft<4; ++ft){
    f32x4 c = {0.f,0.f,0.f,0.f};
    c = __builtin_amdgcn_mfma_f32_16x16x32_bf16(afr0, bfr[ft][0], c, 0,0,0);
    c = __builtin_amdgcn_mfma_f32_16x16x32_bf16(afr1, bfr[ft][1], c, 0,0,0);
    cacc[ft] = c;
  }

  // phase 1: u, stats, u -> sWb
  float bef[4];
  #pragma unroll
  for (int ft=0; ft<4; ++ft) bef[ft] = be[ft*16+ln];
  float s1[4]={0.f,0.f,0.f,0.f}, s2[4]={0.f,0.f,0.f,0.f};
  #pragma unroll
  for (int r=0; r<4; ++r){
    int row = wid*16 + g*4 + r;
    #pragma unroll
    for (int ft=0; ft<4; ++ft){
      int f = ft*16 + ln;
      unsigned short a3 = *(unsigned short*)((char*)sx3 + ((row*128 + f*2) ^ ((row&7)<<4)));
      unsigned short a4 = *(unsigned short*)((char*)sx4 + ((row*128 + f*2) ^ ((row&7)<<4)));
      float u = cacc[ft][r] + bef[ft] + bf2f(a3) + bf2f(a4);
      s1[ft] += u; s2[ft] += u*u;
      *(unsigned short*)((char*)sWb + ((row*128 + f*2) ^ ((row&7)<<4))) = f2bf(u);
    }
  }
  #pragma unroll
  for (int ft=0; ft<4; ++ft){
    s1[ft] += __shfl_xor(s1[ft], 16); s1[ft] += __shfl_xor(s1[ft], 32);
    s2[ft] += __shfl_xor(s2[ft], 16); s2[ft] += __shfl_xor(s2[ft], 32);
  }
  if (g == 0){
    int slot = ((blockIdx.x<<2) + wid) & 63;
    #pragma unroll
    for (int ft=0; ft<4; ++ft){
      atomicAdd(&esum[(slot<<6) + ft*16 + ln], s1[ft]);
      atomicAdd(&esq [(slot<<6) + ft*16 + ln], s2[ft]);
    }
  }
  __syncthreads();   // B3: u staged in sWb

  // u coalesced store
  #pragma unroll
  for (int p=0; p<2; ++p){
    int c = t + p*256;
    int row = c>>3, cc = c&7;
    ushort8 v = *(ushort8*)((char*)sWb + ((row*128 + cc*16) ^ ((row&7)<<4)));
    ((ushort8*)(u_bf + (size_t)e0*64))[c] = v;
  }

  // phase 2: gated messages
  #pragma unroll
  for (int j=0; j<16; ++j){
    int el = (wid<<4) + j;
    int s  = sidx[el];
    int d2 = sidx[64+el];
    unsigned short wv = *(unsigned short*)((char*)swb + ((el*128 + lane*2) ^ ((el&7)<<4)));
    float m = sigm(bf2f(wv)) * bf2f(x2[(size_t)d2*64 + lane]);
    atomicAdd(&agg[(size_t)s*64 + lane], m);
  }
}

// ---------------- node BN stats over t = x1 + agg*invdeg ----------------
__global__ __launch_bounds__(256) void k_nodestats(const float* __restrict__ x1,
    const float* __restrict__ agg, const float* __restrict__ invd,
    float* __restrict__ nsum, float* __restrict__ nsq){
  const int f = threadIdx.x & 63, sub = threadIdx.x >> 6;
  float s1=0.f, s2=0.f;
  for (int n = blockIdx.x*4 + sub; n < NN; n += gridDim.x*4){
    float t = x1[(size_t)n*64+f] + agg[(size_t)n*64+f]*invd[n];
    s1 += t; s2 += t*t;
  }
  __shared__ float red[4][64][2];
  red[sub][f][0]=s1; red[sub][f][1]=s2;
  __syncthreads();
  if (sub==0){
    float a1=red[0][f][0]+red[1][f][0]+red[2][f][0]+red[3][f][0];
    float a2=red[0][f][1]+red[1][f][1]+red[2][f][1]+red[3][f][1];
    int slot = blockIdx.x & 63;
    atomicAdd(&nsum[(slot<<6)+f], a1);
    atomicAdd(&nsq[(slot<<6)+f], a2);
  }
}

// ---------------- finalize both BN -> per-layer coef slot ----------------
__global__ void k_finalize(const float* __restrict__ nsum, const float* __restrict__ nsq,
    const float* __restrict__ esum, const float* __restrict__ esq,
    const float* __restrict__ gn, const float* __restrict__ bn,
    const float* __restrict__ ge, const float* __restrict__ beb,
    float* __restrict__ coef){
  int t = threadIdx.x;
  if (t >= 128) return;
  int f = t & 63;
  const float* S1 = (t<64)? nsum : esum;
  const float* S2 = (t<64)? nsq  : esq;
  float cnt = (t<64)? (float)NN : (float)NE;
  float s1=0.f, s2=0.f;
  for (int k=0;k<64;++k){ s1 += S1[(k<<6)+f]; s2 += S2[(k<<6)+f]; }
  float mu = s1/cnt;
  float var = s2/cnt - mu*mu;
  float rstd = rsqrtf(var + EPSB);
  float g = (t<64)? gn[f] : ge[f];
  float b = (t<64)? bn[f] : beb[f];
  float sc = g*rstd, sh = b - mu*sc;
  coef[((t<64)?0:2)*64 + f] = sc;
  coef[((t<64)?1:3)*64 + f] = sh;
}

// ---------------- final node update: h += silu(bn(t)) ----------------
__global__ __launch_bounds__(256) void k_nodeupd(const float* __restrict__ x1,
    const float* __restrict__ agg, const float* __restrict__ invd,
    const float* __restrict__ coef, float* __restrict__ h){
  int i = blockIdx.x*256 + threadIdx.x;
  if (i >= NN*64) return;
  int n = i>>6, f = i&63;
  float t = x1[i] + agg[i]*invd[n];
  float v = t*coef[f] + coef[64+f];
  h[i] += silu_(v);
}

// ---------------- final edge output: wout = w2 + silu(bn(u2)) (f32) ----------------
__global__ __launch_bounds__(256) void k_edgeBfin(const unsigned short* __restrict__ wb16,
    const unsigned short* __restrict__ u_bf, const float* __restrict__ coef,
    float* __restrict__ wout){
  int i = blockIdx.x*256 + threadIdx.x;      // E*64/8 groups
  int f0 = (i*8) & 63;
  ushort8 wv = ((const ushort8*)wb16)[i];
  ushort8 ub = ((const ushort8*)u_bf)[i];
  float4 s0 = *(const float4*)(coef + 128 + f0);
  float4 s1v = *(const float4*)(coef + 128 + f0 + 4);
  float4 h0 = *(const float4*)(coef + 192 + f0);
  float4 h1 = *(const float4*)(coef + 192 + f0 + 4);
  float4 oa, ob;
  oa.x = bf2f(wv[0]) + silu_(bf2f(ub[0])*s0.x + h0.x);
  oa.y = bf2f(wv[1]) + silu_(bf2f(ub[1])*s0.y + h0.y);
  oa.z = bf2f(wv[2]) + silu_(bf2f(ub[2])*s0.z + h0.z);
  oa.w = bf2f(wv[3]) + silu_(bf2f(ub[3])*s0.w + h0.w);
  ob.x = bf2f(wv[4]) + silu_(bf2f(ub[4])*s1v.x + h1.x);
  ob.y = bf2f(wv[5]) + silu_(bf2f(ub[5])*s1v.y + h1.y);
  ob.z = bf2f(wv[6]) + silu_(bf2f(ub[6])*s1v.z + h1.z);
  ob.w = bf2f(wv[7]) + silu_(bf2f(ub[7])*s1v.w + h1.w);
  ((float4*)wout)[i*2]   = oa;
  ((float4*)wout)[i*2+1] = ob;
}

// ---------------- launch ----------------

extern "C" void kernel_launch(void* const* d_in, const int* in_sizes, int n_in,
                              void* d_out, int out_size, void* d_ws, size_t ws_size,
                              hipStream_t stream){
  const float* x      = (const float*)d_in[0];
  const int*   eidx   = (const int*)d_in[1];
  const float* eattr  = (const float*)d_in[2];
  const float* Wv     = (const float*)d_in[3];
  const float* bv     = (const float*)d_in[4];
  const float* We     = (const float*)d_in[5];
  const float* be     = (const float*)d_in[6];
  const float* g_node = (const float*)d_in[7];
  const float* b_node = (const float*)d_in[8];
  const float* g_edge = (const float*)d_in[9];
  const float* b_edge = (const float*)d_in[10];
  const int* src = eidx;
  const int* dst = eidx + NE;

  float* hout = (float*)d_out;                 // [N][64] live node state (f32)
  float* wout = hout + (size_t)NN*64;          // [E][64] final edge output (f32)

  float* W    = (float*)d_ws;
  float* x1   = W;                                           // 3.2M f32
  float* agg  = W + 3200000;                                 // 3.2M f32
  float* nsum = W + 6400000;                                 // 4096
  float* nsq  = W + 6404096;
  float* esum = W + 6408192;
  float* esq  = W + 6412288;
  float* coef = W + 6416384;                                 // 3*256
  float* invd = W + 6417152;                                 // 50000
  int*   deg  = (int*)(W + 6467152);                         // 50000
  unsigned short* xb   = (unsigned short*)(W + 6517152);     // 3*3.2M bf16
  unsigned short* wvs  = (unsigned short*)(W + 11317152);    // 12*4096 bf16 swz
  unsigned short* wes  = (unsigned short*)(W + 11341728);    // 3*4096 bf16 swz
  unsigned short* u_bf = (unsigned short*)(W + 11347872);    // E*64 bf16
  unsigned short* wb16 = (unsigned short*)(W + 36947872);    // E*64 bf16

  hipMemsetAsync(deg, 0, NN*sizeof(int), stream);
  k_silu4<<<3125, 256, 0, stream>>>(x, hout, 800000);
  k_deg<<<(NE+255)/256, 256, 0, stream>>>(src, deg);
  k_invdeg<<<(NN+255)/256, 256, 0, stream>>>(deg, invd);
  k_prepW<<<15, 256, 0, stream>>>(Wv, We, wvs, wes);

  const unsigned short* x2 = xb;
  const unsigned short* x3 = xb + (size_t)NN*64;
  const unsigned short* x4 = xb + (size_t)2*NN*64;

  for (int l=0; l<3; ++l){
    const float* cprev = coef + (l-1)*256;    // valid for l>=1
    if (l == 0)
      k_nodelin<0><<<782, 256, 0, stream>>>(hout, x1, agg, invd, coef,
          wvs + l*16384, bv + l*256, xb);
    else
      k_nodelin<1><<<782, 256, 0, stream>>>(hout, x1, agg, invd, cprev,
          wvs + l*16384, bv + l*256, xb);
    hipMemsetAsync(agg, 0, (3200000 + 4*4096)*sizeof(float), stream);
    if (l == 0)
      k_edgeA<1><<<12500, 256, 0, stream>>>(eattr, wb16, src, dst, wes + l*4096,
          be + l*64, x2, x3, x4, coef, agg, esum, esq, u_bf);
    else
      k_edgeA<0><<<12500, 256, 0, stream>>>(eattr, wb16, src, dst, wes + l*4096,
          be + l*64, x2, x3, x4, cprev, agg, esum, esq, u_bf);
    k_nodestats<<<128, 256, 0, stream>>>(x1, agg, invd, nsum, nsq);
    k_finalize<<<1, 128, 0, stream>>>(nsum, nsq, esum, esq,
        g_node + l*64, b_node + l*64, g_edge + l*64, b_edge + l*64, coef + l*256);
  }
  // final state updates (layer 2 coef)
  k_nodeupd<<<12500, 256, 0, stream>>>(x1, agg, invd, coef + 512, hout);
  k_edgeBfin<<<25000, 256, 0, stream>>>(wb16, u_bf, coef + 512, wout);
}

// Round 7
// 846.930 us; speedup vs baseline: 5.1901x; 1.1949x over previous
//
#include <hip/hip_runtime.h>

#define NN 50000
#define NE 800000
#define EPSB 1e-5f

typedef __attribute__((ext_vector_type(8))) short bf16x8;
typedef __attribute__((ext_vector_type(8))) unsigned short ushort8;
typedef __attribute__((ext_vector_type(4))) float f32x4;

__device__ __forceinline__ float sigm(float x){ return 1.0f/(1.0f+__expf(-x)); }
__device__ __forceinline__ float silu_(float x){ return x/(1.0f+__expf(-x)); }
__device__ __forceinline__ unsigned short f2bf(float x){
  unsigned int u = __float_as_uint(x);
  return (unsigned short)((u + 0x7FFFu + ((u>>16)&1u)) >> 16);   // RNE
}
__device__ __forceinline__ float bf2f(unsigned short b){
  return __uint_as_float(((unsigned int)b)<<16);
}

// ---------------- elementwise / prep ----------------

__global__ __launch_bounds__(256) void k_silu4(const float* __restrict__ in,
                                               float* __restrict__ out, int n4){
  int i = blockIdx.x*256 + threadIdx.x;
  if (i < n4){
    float4 v = ((const float4*)in)[i];
    v.x = silu_(v.x); v.y = silu_(v.y); v.z = silu_(v.z); v.w = silu_(v.w);
    ((float4*)out)[i] = v;
  }
}

__global__ __launch_bounds__(256) void k_deg(const int* __restrict__ src,
                                             int* __restrict__ deg){
  int e = blockIdx.x*256 + threadIdx.x;
  if (e < NE) atomicAdd(&deg[src[e]], 1);
}

// single-block exclusive scan of deg -> cursor; also invd
__global__ __launch_bounds__(1024) void k_scan(const int* __restrict__ deg,
    int* __restrict__ cursor, float* __restrict__ invd){
  __shared__ int wsum[16];
  __shared__ int sbase;
  if (threadIdx.x == 0) sbase = 0;
  __syncthreads();
  const int lane = threadIdx.x & 63, wid = threadIdx.x >> 6;
  for (int start = 0; start < NN; start += 1024){
    int n = start + (int)threadIdx.x;
    int v = (n < NN) ? deg[n] : 0;
    int x = v;
    #pragma unroll
    for (int d=1; d<64; d<<=1){
      int y = __shfl_up(x, d);
      if (lane >= d) x += y;
    }
    if (lane == 63) wsum[wid] = x;
    __syncthreads();
    if (threadIdx.x < 16){
      int s = wsum[threadIdx.x];
      #pragma unroll
      for (int d=1; d<16; d<<=1){
        int y = __shfl_up(s, d);
        if ((int)threadIdx.x >= d) s += y;
      }
      wsum[threadIdx.x] = s;
    }
    __syncthreads();
    int excl = sbase + ((wid>0)? wsum[wid-1] : 0) + (x - v);
    if (n < NN){
      cursor[n] = excl;
      invd[n] = 1.0f / fmaxf((float)v, 1.0f);
    }
    __syncthreads();
    if (threadIdx.x == 0) sbase += wsum[15];
    __syncthreads();
  }
}

// scatter edges into src-sorted order
__global__ __launch_bounds__(256) void k_scatter(const int* __restrict__ src,
    const int* __restrict__ dst, int* __restrict__ cursor,
    int* __restrict__ perm, int* __restrict__ ssrc, int* __restrict__ sdst){
  int e = blockIdx.x*256 + threadIdx.x;
  if (e < NE){
    int s = src[e];
    int pos = atomicAdd(&cursor[s], 1);
    perm[pos] = e;
    ssrc[pos] = s;
    sdst[pos] = dst[e];
  }
}

// pre-convert all 15 weight mats (Wv 3x4 + We 3x1) to bf16, XOR-swizzled
__global__ __launch_bounds__(256) void k_prepW(const float* __restrict__ Wv,
    const float* __restrict__ We,
    unsigned short* __restrict__ wvs, unsigned short* __restrict__ wes){
  const int m = blockIdx.x;
  const float* S = (m < 12) ? (Wv + m*4096) : (We + (m-12)*4096);
  unsigned short* O = (m < 12) ? (wvs + m*4096) : (wes + (m-12)*4096);
  int t = threadIdx.x;
  #pragma unroll
  for (int p=0; p<2; ++p){
    int c = t + p*256;
    int row = c>>3, cc = c&7;
    const float4* sp = (const float4*)(S + row*64 + cc*8);
    float4 a = sp[0], b = sp[1];
    ushort8 v;
    v[0]=f2bf(a.x); v[1]=f2bf(a.y); v[2]=f2bf(a.z); v[3]=f2bf(a.w);
    v[4]=f2bf(b.x); v[5]=f2bf(b.y); v[6]=f2bf(b.z); v[7]=f2bf(b.w);
    *(ushort8*)((char*)O + ((row*128 + cc*16) ^ ((row&7)<<4))) = v;
  }
}

// ---------------- node linears (MFMA) + fused h-update ----------------
template<int FUSE>
__global__ __launch_bounds__(256) void k_nodelin(float* __restrict__ h,
    float* __restrict__ x1, const float* __restrict__ agg,
    const float* __restrict__ invd, const float* __restrict__ coefp,
    const unsigned short* __restrict__ wvs, const float* __restrict__ bvl,
    unsigned short* __restrict__ xb){
  __shared__ unsigned short shb[4096];   // h tile bf16 swizzled
  __shared__ unsigned short sW[4096];    // current weight mat
  const int n0 = blockIdx.x*64;
  const int t = threadIdx.x;
  #pragma unroll
  for (int p=0; p<2; ++p){
    int c = t + p*256;
    int row = c>>3, cc = c&7;
    int n = n0 + row;
    ushort8 v = {0,0,0,0,0,0,0,0};
    if (n < NN){
      float4* hp = (float4*)(h + (size_t)n*64 + cc*8);
      float4 a = hp[0], b = hp[1];
      if (FUSE){
        const float4* xp = (const float4*)(x1 + (size_t)n*64 + cc*8);
        const float4* gp = (const float4*)(agg + (size_t)n*64 + cc*8);
        float iv = invd[n];
        float4 xa = xp[0], xb4 = xp[1], ga = gp[0], gb = gp[1];
        float4 s0 = *(const float4*)(coefp + cc*8);
        float4 s1v = *(const float4*)(coefp + cc*8 + 4);
        float4 h0 = *(const float4*)(coefp + 64 + cc*8);
        float4 h1 = *(const float4*)(coefp + 64 + cc*8 + 4);
        a.x += silu_((xa.x + ga.x*iv)*s0.x + h0.x);
        a.y += silu_((xa.y + ga.y*iv)*s0.y + h0.y);
        a.z += silu_((xa.z + ga.z*iv)*s0.z + h0.z);
        a.w += silu_((xa.w + ga.w*iv)*s0.w + h0.w);
        b.x += silu_((xb4.x + gb.x*iv)*s1v.x + h1.x);
        b.y += silu_((xb4.y + gb.y*iv)*s1v.y + h1.y);
        b.z += silu_((xb4.z + gb.z*iv)*s1v.z + h1.z);
        b.w += silu_((xb4.w + gb.w*iv)*s1v.w + h1.w);
        hp[0] = a; hp[1] = b;
      }
      v[0]=f2bf(a.x); v[1]=f2bf(a.y); v[2]=f2bf(a.z); v[3]=f2bf(a.w);
      v[4]=f2bf(b.x); v[5]=f2bf(b.y); v[6]=f2bf(b.z); v[7]=f2bf(b.w);
    }
    *(ushort8*)((char*)shb + ((row*128 + cc*16) ^ ((row&7)<<4))) = v;
  }
  __syncthreads();
  const int wid = t>>6, lane = t&63, g = lane>>4, ln = lane&15;
  const int arow = wid*16 + ln;
  bf16x8 afr0 = *(bf16x8*)((char*)shb + ((arow*128 +  0 + g*16) ^ ((arow&7)<<4)));
  bf16x8 afr1 = *(bf16x8*)((char*)shb + ((arow*128 + 64 + g*16) ^ ((arow&7)<<4)));
  for (int k=0; k<4; ++k){
    __syncthreads();
    ((ushort8*)sW)[t]     = ((const ushort8*)(wvs + k*4096))[t];
    ((ushort8*)sW)[t+256] = ((const ushort8*)(wvs + k*4096))[t+256];
    __syncthreads();
    #pragma unroll
    for (int ft=0; ft<4; ++ft){
      int brow = ft*16 + ln;
      bf16x8 b0 = *(bf16x8*)((char*)sW + ((brow*128 +  0 + g*16) ^ ((brow&7)<<4)));
      bf16x8 b1 = *(bf16x8*)((char*)sW + ((brow*128 + 64 + g*16) ^ ((brow&7)<<4)));
      f32x4 c = {0.f,0.f,0.f,0.f};
      c = __builtin_amdgcn_mfma_f32_16x16x32_bf16(afr0, b0, c, 0,0,0);
      c = __builtin_amdgcn_mfma_f32_16x16x32_bf16(afr1, b1, c, 0,0,0);
      float bias = bvl[k*64 + brow];
      #pragma unroll
      for (int r=0; r<4; ++r){
        int n = n0 + wid*16 + g*4 + r;
        if (n < NN){
          float val = c[r] + bias;
          if (k == 0) x1[(size_t)n*64 + brow] = val;
          else xb[(size_t)(k-1)*NN*64 + (size_t)n*64 + brow] = f2bf(val);
        }
      }
    }
  }
}

// ---------------- edge pass A (MFMA, src-sorted) + fused w-state update ----------------
// Block handles 64 sorted edge slots. State (wb16, u_bf) lives in SORTED order.
template<int FIRST>
__global__ __launch_bounds__(256) void k_edgeA(const float* __restrict__ ea,
    unsigned short* __restrict__ wb16,
    const int* __restrict__ perm, const int* __restrict__ ssrc,
    const int* __restrict__ sdst,
    const unsigned short* __restrict__ wes, const float* __restrict__ be,
    const unsigned short* __restrict__ x2, const unsigned short* __restrict__ x3,
    const unsigned short* __restrict__ x4, const float* __restrict__ coefp,
    float* __restrict__ agg, float* __restrict__ esum, float* __restrict__ esq,
    unsigned short* __restrict__ u_bf){
  __shared__ unsigned short sWb[4096];   // We; reused for u staging
  __shared__ unsigned short swb[4096];   // w tile
  __shared__ unsigned short sx3[4096], sx4[4096];  // sx4 reused for x2 in phase 2
  __shared__ int sidx[128];
  const int e0 = blockIdx.x*64;
  const int t = threadIdx.x;

  if (t < 64) sidx[t] = ssrc[e0+t];
  else if (t < 128) sidx[t] = sdst[e0+t-64];
  ((ushort8*)sWb)[t]     = ((const ushort8*)wes)[t];
  ((ushort8*)sWb)[t+256] = ((const ushort8*)wes)[t+256];

  // stage w state (+fused update), write back to global (sorted space)
  #pragma unroll
  for (int p=0; p<2; ++p){
    int c = t + p*256;
    int row = c>>3, cc = c&7;
    ushort8 v;
    if (FIRST){
      int esrc = perm[e0 + row];
      const float4* sp = (const float4*)(ea + (size_t)esrc*64 + cc*8);
      float4 a = sp[0], b = sp[1];
      v[0]=f2bf(silu_(a.x)); v[1]=f2bf(silu_(a.y)); v[2]=f2bf(silu_(a.z)); v[3]=f2bf(silu_(a.w));
      v[4]=f2bf(silu_(b.x)); v[5]=f2bf(silu_(b.y)); v[6]=f2bf(silu_(b.z)); v[7]=f2bf(silu_(b.w));
    } else {
      ushort8 wv = ((const ushort8*)(wb16 + (size_t)e0*64))[c];
      ushort8 uv = ((const ushort8*)(u_bf + (size_t)e0*64))[c];
      int f0 = cc*8;
      float4 s0 = *(const float4*)(coefp + 128 + f0);
      float4 s1v = *(const float4*)(coefp + 128 + f0 + 4);
      float4 h0 = *(const float4*)(coefp + 192 + f0);
      float4 h1 = *(const float4*)(coefp + 192 + f0 + 4);
      v[0] = f2bf(bf2f(wv[0]) + silu_(bf2f(uv[0])*s0.x + h0.x));
      v[1] = f2bf(bf2f(wv[1]) + silu_(bf2f(uv[1])*s0.y + h0.y));
      v[2] = f2bf(bf2f(wv[2]) + silu_(bf2f(uv[2])*s0.z + h0.z));
      v[3] = f2bf(bf2f(wv[3]) + silu_(bf2f(uv[3])*s0.w + h0.w));
      v[4] = f2bf(bf2f(wv[4]) + silu_(bf2f(uv[4])*s1v.x + h1.x));
      v[5] = f2bf(bf2f(wv[5]) + silu_(bf2f(uv[5])*s1v.y + h1.y));
      v[6] = f2bf(bf2f(wv[6]) + silu_(bf2f(uv[6])*s1v.z + h1.z));
      v[7] = f2bf(bf2f(wv[7]) + silu_(bf2f(uv[7])*s1v.w + h1.w));
    }
    ((ushort8*)(wb16 + (size_t)e0*64))[c] = v;
    *(ushort8*)((char*)swb + ((row*128 + cc*16) ^ ((row&7)<<4))) = v;
  }
  __syncthreads();   // B1

  // gather x3/x4 rows into LDS (x3 rows nearly sequential thanks to sort)
  #pragma unroll
  for (int p=0; p<2; ++p){
    int c = t + p*256;
    int row = c>>3, cc = c&7;
    int s  = sidx[row];
    int d2 = sidx[64+row];
    ushort8 a = *(const ushort8*)(x3 + (size_t)s*64  + cc*8);
    ushort8 b = *(const ushort8*)(x4 + (size_t)d2*64 + cc*8);
    *(ushort8*)((char*)sx3 + ((row*128 + cc*16) ^ ((row&7)<<4))) = a;
    *(ushort8*)((char*)sx4 + ((row*128 + cc*16) ^ ((row&7)<<4))) = b;
  }

  const int wid = t>>6, lane = t&63, g = lane>>4, ln = lane&15;
  const int arow = wid*16 + ln;
  bf16x8 afr0 = *(bf16x8*)((char*)swb + ((arow*128 +  0 + g*16) ^ ((arow&7)<<4)));
  bf16x8 afr1 = *(bf16x8*)((char*)swb + ((arow*128 + 64 + g*16) ^ ((arow&7)<<4)));
  bf16x8 bfr[4][2];
  #pragma unroll
  for (int ft=0; ft<4; ++ft){
    int brow = ft*16 + ln;
    bfr[ft][0] = *(bf16x8*)((char*)sWb + ((brow*128 +  0 + g*16) ^ ((brow&7)<<4)));
    bfr[ft][1] = *(bf16x8*)((char*)sWb + ((brow*128 + 64 + g*16) ^ ((brow&7)<<4)));
  }
  __syncthreads();   // B2: sx3/sx4 ready; sWb frag reads done

  f32x4 cacc[4];
  #pragma unroll
  for (int ft=0; ft<4; ++ft){
    f32x4 c = {0.f,0.f,0.f,0.f};
    c = __builtin_amdgcn_mfma_f32_16x16x32_bf16(afr0, bfr[ft][0], c, 0,0,0);
    c = __builtin_amdgcn_mfma_f32_16x16x32_bf16(afr1, bfr[ft][1], c, 0,0,0);
    cacc[ft] = c;
  }

  // phase 1: u, stats, u -> sWb
  float bef[4];
  #pragma unroll
  for (int ft=0; ft<4; ++ft) bef[ft] = be[ft*16+ln];
  float s1[4]={0.f,0.f,0.f,0.f}, s2[4]={0.f,0.f,0.f,0.f};
  #pragma unroll
  for (int r=0; r<4; ++r){
    int row = wid*16 + g*4 + r;
    #pragma unroll
    for (int ft=0; ft<4; ++ft){
      int f = ft*16 + ln;
      unsigned short a3 = *(unsigned short*)((char*)sx3 + ((row*128 + f*2) ^ ((row&7)<<4)));
      unsigned short a4 = *(unsigned short*)((char*)sx4 + ((row*128 + f*2) ^ ((row&7)<<4)));
      float u = cacc[ft][r] + bef[ft] + bf2f(a3) + bf2f(a4);
      s1[ft] += u; s2[ft] += u*u;
      *(unsigned short*)((char*)sWb + ((row*128 + f*2) ^ ((row&7)<<4))) = f2bf(u);
    }
  }
  #pragma unroll
  for (int ft=0; ft<4; ++ft){
    s1[ft] += __shfl_xor(s1[ft], 16); s1[ft] += __shfl_xor(s1[ft], 32);
    s2[ft] += __shfl_xor(s2[ft], 16); s2[ft] += __shfl_xor(s2[ft], 32);
  }
  if (g == 0){
    int slot = ((blockIdx.x<<2) + wid) & 63;
    #pragma unroll
    for (int ft=0; ft<4; ++ft){
      atomicAdd(&esum[(slot<<6) + ft*16 + ln], s1[ft]);
      atomicAdd(&esq [(slot<<6) + ft*16 + ln], s2[ft]);
    }
  }
  __syncthreads();   // B3: u staged in sWb; sx4 free

  // u coalesced store + stage x2[dst] into sx4
  #pragma unroll
  for (int p=0; p<2; ++p){
    int c = t + p*256;
    int row = c>>3, cc = c&7;
    ushort8 v = *(ushort8*)((char*)sWb + ((row*128 + cc*16) ^ ((row&7)<<4)));
    ((ushort8*)(u_bf + (size_t)e0*64))[c] = v;
    int d2 = sidx[64+row];
    ushort8 xv = *(const ushort8*)(x2 + (size_t)d2*64 + cc*8);
    *(ushort8*)((char*)sx4 + ((row*128 + cc*16) ^ ((row&7)<<4))) = xv;
  }
  __syncthreads();   // B4: x2 staged

  // phase 2: gated messages, run-length aggregated (ssrc sorted)
  {
    const int el0 = wid<<4;
    int curs = sidx[el0];
    float run = 0.f;
    #pragma unroll
    for (int j=0; j<16; ++j){
      int el = el0 + j;
      int s = sidx[el];
      if (s != curs){
        atomicAdd(&agg[(size_t)curs*64 + lane], run);
        run = 0.f; curs = s;
      }
      unsigned short wv = *(unsigned short*)((char*)swb + ((el*128 + lane*2) ^ ((el&7)<<4)));
      unsigned short xv = *(unsigned short*)((char*)sx4 + ((el*128 + lane*2) ^ ((el&7)<<4)));
      run += sigm(bf2f(wv)) * bf2f(xv);
    }
    atomicAdd(&agg[(size_t)curs*64 + lane], run);
  }
}

// ---------------- node BN stats over t = x1 + agg*invdeg ----------------
__global__ __launch_bounds__(256) void k_nodestats(const float* __restrict__ x1,
    const float* __restrict__ agg, const float* __restrict__ invd,
    float* __restrict__ nsum, float* __restrict__ nsq){
  const int f = threadIdx.x & 63, sub = threadIdx.x >> 6;
  float s1=0.f, s2=0.f;
  for (int n = blockIdx.x*4 + sub; n < NN; n += gridDim.x*4){
    float t = x1[(size_t)n*64+f] + agg[(size_t)n*64+f]*invd[n];
    s1 += t; s2 += t*t;
  }
  __shared__ float red[4][64][2];
  red[sub][f][0]=s1; red[sub][f][1]=s2;
  __syncthreads();
  if (sub==0){
    float a1=red[0][f][0]+red[1][f][0]+red[2][f][0]+red[3][f][0];
    float a2=red[0][f][1]+red[1][f][1]+red[2][f][1]+red[3][f][1];
    int slot = blockIdx.x & 63;
    atomicAdd(&nsum[(slot<<6)+f], a1);
    atomicAdd(&nsq[(slot<<6)+f], a2);
  }
}

// ---------------- finalize both BN -> per-layer coef slot ----------------
__global__ void k_finalize(const float* __restrict__ nsum, const float* __restrict__ nsq,
    const float* __restrict__ esum, const float* __restrict__ esq,
    const float* __restrict__ gn, const float* __restrict__ bn,
    const float* __restrict__ ge, const float* __restrict__ beb,
    float* __restrict__ coef){
  int t = threadIdx.x;
  if (t >= 128) return;
  int f = t & 63;
  const float* S1 = (t<64)? nsum : esum;
  const float* S2 = (t<64)? nsq  : esq;
  float cnt = (t<64)? (float)NN : (float)NE;
  float s1=0.f, s2=0.f;
  for (int k=0;k<64;++k){ s1 += S1[(k<<6)+f]; s2 += S2[(k<<6)+f]; }
  float mu = s1/cnt;
  float var = s2/cnt - mu*mu;
  float rstd = rsqrtf(var + EPSB);
  float g = (t<64)? gn[f] : ge[f];
  float b = (t<64)? bn[f] : beb[f];
  float sc = g*rstd, sh = b - mu*sc;
  coef[((t<64)?0:2)*64 + f] = sc;
  coef[((t<64)?1:3)*64 + f] = sh;
}

// ---------------- final node update: h += silu(bn(t)) ----------------
__global__ __launch_bounds__(256) void k_nodeupd(const float* __restrict__ x1,
    const float* __restrict__ agg, const float* __restrict__ invd,
    const float* __restrict__ coef, float* __restrict__ h){
  int i = blockIdx.x*256 + threadIdx.x;
  if (i >= NN*64) return;
  int n = i>>6, f = i&63;
  float t = x1[i] + agg[i]*invd[n];
  float v = t*coef[f] + coef[64+f];
  h[i] += silu_(v);
}

// ---------------- final edge output: wout[perm] = w2 + silu(bn(u2)) ----------------
__global__ __launch_bounds__(256) void k_edgeBfin(const unsigned short* __restrict__ wb16,
    const unsigned short* __restrict__ u_bf, const float* __restrict__ coef,
    const int* __restrict__ perm, float* __restrict__ wout){
  int i = blockIdx.x*256 + threadIdx.x;      // E*64/8 groups (sorted space)
  int cc = i & 7, f0 = cc*8;
  int eid = perm[i>>3];
  ushort8 wv = ((const ushort8*)wb16)[i];
  ushort8 ub = ((const ushort8*)u_bf)[i];
  float4 s0 = *(const float4*)(coef + 128 + f0);
  float4 s1v = *(const float4*)(coef + 128 + f0 + 4);
  float4 h0 = *(const float4*)(coef + 192 + f0);
  float4 h1 = *(const float4*)(coef + 192 + f0 + 4);
  float4 oa, ob;
  oa.x = bf2f(wv[0]) + silu_(bf2f(ub[0])*s0.x + h0.x);
  oa.y = bf2f(wv[1]) + silu_(bf2f(ub[1])*s0.y + h0.y);
  oa.z = bf2f(wv[2]) + silu_(bf2f(ub[2])*s0.z + h0.z);
  oa.w = bf2f(wv[3]) + silu_(bf2f(ub[3])*s0.w + h0.w);
  ob.x = bf2f(wv[4]) + silu_(bf2f(ub[4])*s1v.x + h1.x);
  ob.y = bf2f(wv[5]) + silu_(bf2f(ub[5])*s1v.y + h1.y);
  ob.z = bf2f(wv[6]) + silu_(bf2f(ub[6])*s1v.z + h1.z);
  ob.w = bf2f(wv[7]) + silu_(bf2f(ub[7])*s1v.w + h1.w);
  float4* wp = (float4*)(wout + (size_t)eid*64 + f0);
  wp[0] = oa; wp[1] = ob;
}

// ---------------- launch ----------------

extern "C" void kernel_launch(void* const* d_in, const int* in_sizes, int n_in,
                              void* d_out, int out_size, void* d_ws, size_t ws_size,
                              hipStream_t stream){
  const float* x      = (const float*)d_in[0];
  const int*   eidx   = (const int*)d_in[1];
  const float* eattr  = (const float*)d_in[2];
  const float* Wv     = (const float*)d_in[3];
  const float* bv     = (const float*)d_in[4];
  const float* We     = (const float*)d_in[5];
  const float* be     = (const float*)d_in[6];
  const float* g_node = (const float*)d_in[7];
  const float* b_node = (const float*)d_in[8];
  const float* g_edge = (const float*)d_in[9];
  const float* b_edge = (const float*)d_in[10];
  const int* src = eidx;
  const int* dst = eidx + NE;

  float* hout = (float*)d_out;                 // [N][64] live node state (f32)
  float* wout = hout + (size_t)NN*64;          // [E][64] final edge output (f32)

  float* W    = (float*)d_ws;
  float* x1   = W;                                           // 3.2M f32
  float* agg  = W + 3200000;                                 // 3.2M f32
  float* nsum = W + 6400000;
  float* nsq  = W + 6404096;
  float* esum = W + 6408192;
  float* esq  = W + 6412288;
  float* coef = W + 6416384;                                 // 3*256
  float* invd = W + 6417152;                                 // 50000
  int*   deg  = (int*)(W + 6467152);                         // 50000
  unsigned short* xb   = (unsigned short*)(W + 6517152);     // 3*3.2M bf16
  unsigned short* wvs  = (unsigned short*)(W + 11317152);    // 12*4096 bf16 swz
  unsigned short* wes  = (unsigned short*)(W + 11341728);    // 3*4096 bf16 swz
  unsigned short* u_bf = (unsigned short*)(W + 11347872);    // E*64 bf16 (sorted)
  unsigned short* wb16 = (unsigned short*)(W + 36947872);    // E*64 bf16 (sorted)
  int* perm   = (int*)(W + 62547872);                        // E
  int* ssrc   = (int*)(W + 63347872);                        // E
  int* sdst   = (int*)(W + 64147872);                        // E
  int* cursor = (int*)(W + 64947872);                        // N

  hipMemsetAsync(deg, 0, NN*sizeof(int), stream);
  k_silu4<<<3125, 256, 0, stream>>>(x, hout, 800000);
  k_deg<<<3125, 256, 0, stream>>>(src, deg);
  k_scan<<<1, 1024, 0, stream>>>(deg, cursor, invd);
  k_scatter<<<3125, 256, 0, stream>>>(src, dst, cursor, perm, ssrc, sdst);
  k_prepW<<<15, 256, 0, stream>>>(Wv, We, wvs, wes);

  const unsigned short* x2 = xb;
  const unsigned short* x3 = xb + (size_t)NN*64;
  const unsigned short* x4 = xb + (size_t)2*NN*64;

  for (int l=0; l<3; ++l){
    const float* cprev = coef + (l-1)*256;    // valid for l>=1
    if (l == 0)
      k_nodelin<0><<<782, 256, 0, stream>>>(hout, x1, agg, invd, coef,
          wvs + l*16384, bv + l*256, xb);
    else
      k_nodelin<1><<<782, 256, 0, stream>>>(hout, x1, agg, invd, cprev,
          wvs + l*16384, bv + l*256, xb);
    hipMemsetAsync(agg, 0, (3200000 + 4*4096)*sizeof(float), stream);
    if (l == 0)
      k_edgeA<1><<<12500, 256, 0, stream>>>(eattr, wb16, perm, ssrc, sdst,
          wes + l*4096, be + l*64, x2, x3, x4, coef, agg, esum, esq, u_bf);
    else
      k_edgeA<0><<<12500, 256, 0, stream>>>(eattr, wb16, perm, ssrc, sdst,
          wes + l*4096, be + l*64, x2, x3, x4, cprev, agg, esum, esq, u_bf);
    k_nodestats<<<128, 256, 0, stream>>>(x1, agg, invd, nsum, nsq);
    k_finalize<<<1, 128, 0, stream>>>(nsum, nsq, esum, esq,
        g_node + l*64, b_node + l*64, g_edge + l*64, b_edge + l*64, coef + l*256);
  }
  // final state updates (layer 2 coef)
  k_nodeupd<<<12500, 256, 0, stream>>>(x1, agg, invd, coef + 512, hout);
  k_edgeBfin<<<25000, 256, 0, stream>>>(wb16, u_bf, coef + 512, perm, wout);
}

// Round 8
// 807.050 us; speedup vs baseline: 5.4466x; 1.0494x over previous
//
#include <hip/hip_runtime.h>

#define NN 50000
#define NE 800000
#define EPSB 1e-5f

typedef __attribute__((ext_vector_type(8))) short bf16x8;
typedef __attribute__((ext_vector_type(8))) unsigned short ushort8;
typedef __attribute__((ext_vector_type(4))) float f32x4;

__device__ __forceinline__ float sigm(float x){ return 1.0f/(1.0f+__expf(-x)); }
__device__ __forceinline__ float silu_(float x){ return x/(1.0f+__expf(-x)); }
__device__ __forceinline__ unsigned short f2bf(float x){
  unsigned int u = __float_as_uint(x);
  return (unsigned short)((u + 0x7FFFu + ((u>>16)&1u)) >> 16);   // RNE
}
__device__ __forceinline__ float bf2f(unsigned short b){
  return __uint_as_float(((unsigned int)b)<<16);
}

// ---------------- elementwise / prep ----------------

__global__ __launch_bounds__(256) void k_silu4(const float* __restrict__ in,
                                               float* __restrict__ out, int n4){
  int i = blockIdx.x*256 + threadIdx.x;
  if (i < n4){
    float4 v = ((const float4*)in)[i];
    v.x = silu_(v.x); v.y = silu_(v.y); v.z = silu_(v.z); v.w = silu_(v.w);
    ((float4*)out)[i] = v;
  }
}

__global__ __launch_bounds__(256) void k_deg(const int* __restrict__ src,
                                             int* __restrict__ deg){
  int e = blockIdx.x*256 + threadIdx.x;
  if (e < NE) atomicAdd(&deg[src[e]], 1);
}

// single-block exclusive scan of deg -> cursor; also invd
__global__ __launch_bounds__(1024) void k_scan(const int* __restrict__ deg,
    int* __restrict__ cursor, float* __restrict__ invd){
  __shared__ int wsum[16];
  __shared__ int sbase;
  if (threadIdx.x == 0) sbase = 0;
  __syncthreads();
  const int lane = threadIdx.x & 63, wid = threadIdx.x >> 6;
  for (int start = 0; start < NN; start += 1024){
    int n = start + (int)threadIdx.x;
    int v = (n < NN) ? deg[n] : 0;
    int x = v;
    #pragma unroll
    for (int d=1; d<64; d<<=1){
      int y = __shfl_up(x, d);
      if (lane >= d) x += y;
    }
    if (lane == 63) wsum[wid] = x;
    __syncthreads();
    if (threadIdx.x < 16){
      int s = wsum[threadIdx.x];
      #pragma unroll
      for (int d=1; d<16; d<<=1){
        int y = __shfl_up(s, d);
        if ((int)threadIdx.x >= d) s += y;
      }
      wsum[threadIdx.x] = s;
    }
    __syncthreads();
    int excl = sbase + ((wid>0)? wsum[wid-1] : 0) + (x - v);
    if (n < NN){
      cursor[n] = excl;
      invd[n] = 1.0f / fmaxf((float)v, 1.0f);
    }
    __syncthreads();
    if (threadIdx.x == 0) sbase += wsum[15];
    __syncthreads();
  }
}

// scatter edges into src-sorted order
__global__ __launch_bounds__(256) void k_scatter(const int* __restrict__ src,
    const int* __restrict__ dst, int* __restrict__ cursor,
    int* __restrict__ perm, int* __restrict__ ssrc, int* __restrict__ sdst){
  int e = blockIdx.x*256 + threadIdx.x;
  if (e < NE){
    int s = src[e];
    int pos = atomicAdd(&cursor[s], 1);
    perm[pos] = e;
    ssrc[pos] = s;
    sdst[pos] = dst[e];
  }
}

// pre-convert all 15 weight mats (Wv 3x4 + We 3x1) to bf16, XOR-swizzled
__global__ __launch_bounds__(256) void k_prepW(const float* __restrict__ Wv,
    const float* __restrict__ We,
    unsigned short* __restrict__ wvs, unsigned short* __restrict__ wes){
  const int m = blockIdx.x;
  const float* S = (m < 12) ? (Wv + m*4096) : (We + (m-12)*4096);
  unsigned short* O = (m < 12) ? (wvs + m*4096) : (wes + (m-12)*4096);
  int t = threadIdx.x;
  #pragma unroll
  for (int p=0; p<2; ++p){
    int c = t + p*256;
    int row = c>>3, cc = c&7;
    const float4* sp = (const float4*)(S + row*64 + cc*8);
    float4 a = sp[0], b = sp[1];
    ushort8 v;
    v[0]=f2bf(a.x); v[1]=f2bf(a.y); v[2]=f2bf(a.z); v[3]=f2bf(a.w);
    v[4]=f2bf(b.x); v[5]=f2bf(b.y); v[6]=f2bf(b.z); v[7]=f2bf(b.w);
    *(ushort8*)((char*)O + ((row*128 + cc*16) ^ ((row&7)<<4))) = v;
  }
}

// ---------------- node linears (MFMA) + fused h-update ----------------
template<int FUSE>
__global__ __launch_bounds__(256) void k_nodelin(float* __restrict__ h,
    float* __restrict__ x1, const float* __restrict__ agg,
    const float* __restrict__ invd, const float* __restrict__ coefp,
    const unsigned short* __restrict__ wvs, const float* __restrict__ bvl,
    unsigned short* __restrict__ xb){
  __shared__ unsigned short shb[4096];   // h tile bf16 swizzled
  __shared__ unsigned short sW[4096];    // current weight mat
  const int n0 = blockIdx.x*64;
  const int t = threadIdx.x;
  #pragma unroll
  for (int p=0; p<2; ++p){
    int c = t + p*256;
    int row = c>>3, cc = c&7;
    int n = n0 + row;
    ushort8 v = {0,0,0,0,0,0,0,0};
    if (n < NN){
      float4* hp = (float4*)(h + (size_t)n*64 + cc*8);
      float4 a = hp[0], b = hp[1];
      if (FUSE){
        const float4* xp = (const float4*)(x1 + (size_t)n*64 + cc*8);
        const float4* gp = (const float4*)(agg + (size_t)n*64 + cc*8);
        float iv = invd[n];
        float4 xa = xp[0], xb4 = xp[1], ga = gp[0], gb = gp[1];
        float4 s0 = *(const float4*)(coefp + cc*8);
        float4 s1v = *(const float4*)(coefp + cc*8 + 4);
        float4 h0 = *(const float4*)(coefp + 64 + cc*8);
        float4 h1 = *(const float4*)(coefp + 64 + cc*8 + 4);
        a.x += silu_((xa.x + ga.x*iv)*s0.x + h0.x);
        a.y += silu_((xa.y + ga.y*iv)*s0.y + h0.y);
        a.z += silu_((xa.z + ga.z*iv)*s0.z + h0.z);
        a.w += silu_((xa.w + ga.w*iv)*s0.w + h0.w);
        b.x += silu_((xb4.x + gb.x*iv)*s1v.x + h1.x);
        b.y += silu_((xb4.y + gb.y*iv)*s1v.y + h1.y);
        b.z += silu_((xb4.z + gb.z*iv)*s1v.z + h1.z);
        b.w += silu_((xb4.w + gb.w*iv)*s1v.w + h1.w);
        hp[0] = a; hp[1] = b;
      }
      v[0]=f2bf(a.x); v[1]=f2bf(a.y); v[2]=f2bf(a.z); v[3]=f2bf(a.w);
      v[4]=f2bf(b.x); v[5]=f2bf(b.y); v[6]=f2bf(b.z); v[7]=f2bf(b.w);
    }
    *(ushort8*)((char*)shb + ((row*128 + cc*16) ^ ((row&7)<<4))) = v;
  }
  __syncthreads();
  const int wid = t>>6, lane = t&63, g = lane>>4, ln = lane&15;
  const int arow = wid*16 + ln;
  bf16x8 afr0 = *(bf16x8*)((char*)shb + ((arow*128 +  0 + g*16) ^ ((arow&7)<<4)));
  bf16x8 afr1 = *(bf16x8*)((char*)shb + ((arow*128 + 64 + g*16) ^ ((arow&7)<<4)));
  for (int k=0; k<4; ++k){
    __syncthreads();
    ((ushort8*)sW)[t]     = ((const ushort8*)(wvs + k*4096))[t];
    ((ushort8*)sW)[t+256] = ((const ushort8*)(wvs + k*4096))[t+256];
    __syncthreads();
    #pragma unroll
    for (int ft=0; ft<4; ++ft){
      int brow = ft*16 + ln;
      bf16x8 b0 = *(bf16x8*)((char*)sW + ((brow*128 +  0 + g*16) ^ ((brow&7)<<4)));
      bf16x8 b1 = *(bf16x8*)((char*)sW + ((brow*128 + 64 + g*16) ^ ((brow&7)<<4)));
      f32x4 c = {0.f,0.f,0.f,0.f};
      c = __builtin_amdgcn_mfma_f32_16x16x32_bf16(afr0, b0, c, 0,0,0);
      c = __builtin_amdgcn_mfma_f32_16x16x32_bf16(afr1, b1, c, 0,0,0);
      float bias = bvl[k*64 + brow];
      #pragma unroll
      for (int r=0; r<4; ++r){
        int n = n0 + wid*16 + g*4 + r;
        if (n < NN){
          float val = c[r] + bias;
          if (k == 0) x1[(size_t)n*64 + brow] = val;
          else xb[(size_t)(k-1)*NN*64 + (size_t)n*64 + brow] = f2bf(val);
        }
      }
    }
  }
}

// ---------------- edge pass A (MFMA, src-sorted) + fused w-state update ----------------
// LDS diet: x3[src]+x4[dst] staged as ONE summed bf16 buffer (u-phase only needs the sum).
// 24.7KB LDS -> 6 blocks/CU.
template<int FIRST>
__global__ __launch_bounds__(256) void k_edgeA(const float* __restrict__ ea,
    unsigned short* __restrict__ wb16,
    const int* __restrict__ perm, const int* __restrict__ ssrc,
    const int* __restrict__ sdst,
    const unsigned short* __restrict__ wes, const float* __restrict__ be,
    const unsigned short* __restrict__ x2, const unsigned short* __restrict__ x3,
    const unsigned short* __restrict__ x4, const float* __restrict__ coefp,
    float* __restrict__ agg, float* __restrict__ esum, float* __restrict__ esq,
    unsigned short* __restrict__ u_bf){
  __shared__ unsigned short sWb[4096];   // We; reused for u staging
  __shared__ unsigned short swb[4096];   // w tile
  __shared__ unsigned short sxs[4096];   // x3[s]+x4[d] sum; reused for x2 in phase 2
  __shared__ int sidx[128];
  const int e0 = blockIdx.x*64;
  const int t = threadIdx.x;

  if (t < 64) sidx[t] = ssrc[e0+t];
  else if (t < 128) sidx[t] = sdst[e0+t-64];
  ((ushort8*)sWb)[t]     = ((const ushort8*)wes)[t];
  ((ushort8*)sWb)[t+256] = ((const ushort8*)wes)[t+256];

  // stage w state (+fused update), write back to global (sorted space)
  #pragma unroll
  for (int p=0; p<2; ++p){
    int c = t + p*256;
    int row = c>>3, cc = c&7;
    ushort8 v;
    if (FIRST){
      int esrc = perm[e0 + row];
      const float4* sp = (const float4*)(ea + (size_t)esrc*64 + cc*8);
      float4 a = sp[0], b = sp[1];
      v[0]=f2bf(silu_(a.x)); v[1]=f2bf(silu_(a.y)); v[2]=f2bf(silu_(a.z)); v[3]=f2bf(silu_(a.w));
      v[4]=f2bf(silu_(b.x)); v[5]=f2bf(silu_(b.y)); v[6]=f2bf(silu_(b.z)); v[7]=f2bf(silu_(b.w));
    } else {
      ushort8 wv = ((const ushort8*)(wb16 + (size_t)e0*64))[c];
      ushort8 uv = ((const ushort8*)(u_bf + (size_t)e0*64))[c];
      int f0 = cc*8;
      float4 s0 = *(const float4*)(coefp + 128 + f0);
      float4 s1v = *(const float4*)(coefp + 128 + f0 + 4);
      float4 h0 = *(const float4*)(coefp + 192 + f0);
      float4 h1 = *(const float4*)(coefp + 192 + f0 + 4);
      v[0] = f2bf(bf2f(wv[0]) + silu_(bf2f(uv[0])*s0.x + h0.x));
      v[1] = f2bf(bf2f(wv[1]) + silu_(bf2f(uv[1])*s0.y + h0.y));
      v[2] = f2bf(bf2f(wv[2]) + silu_(bf2f(uv[2])*s0.z + h0.z));
      v[3] = f2bf(bf2f(wv[3]) + silu_(bf2f(uv[3])*s0.w + h0.w));
      v[4] = f2bf(bf2f(wv[4]) + silu_(bf2f(uv[4])*s1v.x + h1.x));
      v[5] = f2bf(bf2f(wv[5]) + silu_(bf2f(uv[5])*s1v.y + h1.y));
      v[6] = f2bf(bf2f(wv[6]) + silu_(bf2f(uv[6])*s1v.z + h1.z));
      v[7] = f2bf(bf2f(wv[7]) + silu_(bf2f(uv[7])*s1v.w + h1.w));
    }
    ((ushort8*)(wb16 + (size_t)e0*64))[c] = v;
    *(ushort8*)((char*)swb + ((row*128 + cc*16) ^ ((row&7)<<4))) = v;
  }
  __syncthreads();   // B1: sidx, sWb, swb visible

  // gather x3[s] + x4[d], summed, into one LDS buffer
  #pragma unroll
  for (int p=0; p<2; ++p){
    int c = t + p*256;
    int row = c>>3, cc = c&7;
    int s  = sidx[row];
    int d2 = sidx[64+row];
    ushort8 a = *(const ushort8*)(x3 + (size_t)s*64  + cc*8);
    ushort8 b = *(const ushort8*)(x4 + (size_t)d2*64 + cc*8);
    ushort8 v;
    #pragma unroll
    for (int j=0;j<8;++j) v[j] = f2bf(bf2f(a[j]) + bf2f(b[j]));
    *(ushort8*)((char*)sxs + ((row*128 + cc*16) ^ ((row&7)<<4))) = v;
  }

  const int wid = t>>6, lane = t&63, g = lane>>4, ln = lane&15;
  const int arow = wid*16 + ln;
  bf16x8 afr0 = *(bf16x8*)((char*)swb + ((arow*128 +  0 + g*16) ^ ((arow&7)<<4)));
  bf16x8 afr1 = *(bf16x8*)((char*)swb + ((arow*128 + 64 + g*16) ^ ((arow&7)<<4)));
  bf16x8 bfr[4][2];
  #pragma unroll
  for (int ft=0; ft<4; ++ft){
    int brow = ft*16 + ln;
    bfr[ft][0] = *(bf16x8*)((char*)sWb + ((brow*128 +  0 + g*16) ^ ((brow&7)<<4)));
    bfr[ft][1] = *(bf16x8*)((char*)sWb + ((brow*128 + 64 + g*16) ^ ((brow&7)<<4)));
  }
  __syncthreads();   // B2: sxs ready; sWb frag reads done (sWb reusable)

  f32x4 cacc[4];
  #pragma unroll
  for (int ft=0; ft<4; ++ft){
    f32x4 c = {0.f,0.f,0.f,0.f};
    c = __builtin_amdgcn_mfma_f32_16x16x32_bf16(afr0, bfr[ft][0], c, 0,0,0);
    c = __builtin_amdgcn_mfma_f32_16x16x32_bf16(afr1, bfr[ft][1], c, 0,0,0);
    cacc[ft] = c;
  }

  // phase 1: u, stats, u -> sWb
  float bef[4];
  #pragma unroll
  for (int ft=0; ft<4; ++ft) bef[ft] = be[ft*16+ln];
  float s1[4]={0.f,0.f,0.f,0.f}, s2[4]={0.f,0.f,0.f,0.f};
  #pragma unroll
  for (int r=0; r<4; ++r){
    int row = wid*16 + g*4 + r;
    #pragma unroll
    for (int ft=0; ft<4; ++ft){
      int f = ft*16 + ln;
      unsigned short a34 = *(unsigned short*)((char*)sxs + ((row*128 + f*2) ^ ((row&7)<<4)));
      float u = cacc[ft][r] + bef[ft] + bf2f(a34);
      s1[ft] += u; s2[ft] += u*u;
      *(unsigned short*)((char*)sWb + ((row*128 + f*2) ^ ((row&7)<<4))) = f2bf(u);
    }
  }
  #pragma unroll
  for (int ft=0; ft<4; ++ft){
    s1[ft] += __shfl_xor(s1[ft], 16); s1[ft] += __shfl_xor(s1[ft], 32);
    s2[ft] += __shfl_xor(s2[ft], 16); s2[ft] += __shfl_xor(s2[ft], 32);
  }
  if (g == 0){
    int slot = ((blockIdx.x<<2) + wid) & 63;
    #pragma unroll
    for (int ft=0; ft<4; ++ft){
      atomicAdd(&esum[(slot<<6) + ft*16 + ln], s1[ft]);
      atomicAdd(&esq [(slot<<6) + ft*16 + ln], s2[ft]);
    }
  }
  __syncthreads();   // B3: u staged in sWb; sxs free

  // u coalesced store + stage x2[dst] into sxs
  #pragma unroll
  for (int p=0; p<2; ++p){
    int c = t + p*256;
    int row = c>>3, cc = c&7;
    ushort8 v = *(ushort8*)((char*)sWb + ((row*128 + cc*16) ^ ((row&7)<<4)));
    ((ushort8*)(u_bf + (size_t)e0*64))[c] = v;
    int d2 = sidx[64+row];
    ushort8 xv = *(const ushort8*)(x2 + (size_t)d2*64 + cc*8);
    *(ushort8*)((char*)sxs + ((row*128 + cc*16) ^ ((row&7)<<4))) = xv;
  }
  __syncthreads();   // B4: x2 staged

  // phase 2: gated messages, run-length aggregated (ssrc sorted)
  {
    const int el0 = wid<<4;
    int curs = sidx[el0];
    float run = 0.f;
    #pragma unroll
    for (int j=0; j<16; ++j){
      int el = el0 + j;
      int s = sidx[el];
      if (s != curs){
        atomicAdd(&agg[(size_t)curs*64 + lane], run);
        run = 0.f; curs = s;
      }
      unsigned short wv = *(unsigned short*)((char*)swb + ((el*128 + lane*2) ^ ((el&7)<<4)));
      unsigned short xv = *(unsigned short*)((char*)sxs + ((el*128 + lane*2) ^ ((el&7)<<4)));
      run += sigm(bf2f(wv)) * bf2f(xv);
    }
    atomicAdd(&agg[(size_t)curs*64 + lane], run);
  }
}

// ---------------- node BN stats over t = x1 + agg*invdeg ----------------
__global__ __launch_bounds__(256) void k_nodestats(const float* __restrict__ x1,
    const float* __restrict__ agg, const float* __restrict__ invd,
    float* __restrict__ nsum, float* __restrict__ nsq){
  const int f = threadIdx.x & 63, sub = threadIdx.x >> 6;
  float s1=0.f, s2=0.f;
  for (int n = blockIdx.x*4 + sub; n < NN; n += gridDim.x*4){
    float t = x1[(size_t)n*64+f] + agg[(size_t)n*64+f]*invd[n];
    s1 += t; s2 += t*t;
  }
  __shared__ float red[4][64][2];
  red[sub][f][0]=s1; red[sub][f][1]=s2;
  __syncthreads();
  if (sub==0){
    float a1=red[0][f][0]+red[1][f][0]+red[2][f][0]+red[3][f][0];
    float a2=red[0][f][1]+red[1][f][1]+red[2][f][1]+red[3][f][1];
    int slot = blockIdx.x & 63;
    atomicAdd(&nsum[(slot<<6)+f], a1);
    atomicAdd(&nsq[(slot<<6)+f], a2);
  }
}

// ---------------- finalize both BN -> per-layer coef slot ----------------
__global__ void k_finalize(const float* __restrict__ nsum, const float* __restrict__ nsq,
    const float* __restrict__ esum, const float* __restrict__ esq,
    const float* __restrict__ gn, const float* __restrict__ bn,
    const float* __restrict__ ge, const float* __restrict__ beb,
    float* __restrict__ coef){
  int t = threadIdx.x;
  if (t >= 128) return;
  int f = t & 63;
  const float* S1 = (t<64)? nsum : esum;
  const float* S2 = (t<64)? nsq  : esq;
  float cnt = (t<64)? (float)NN : (float)NE;
  float s1=0.f, s2=0.f;
  for (int k=0;k<64;++k){ s1 += S1[(k<<6)+f]; s2 += S2[(k<<6)+f]; }
  float mu = s1/cnt;
  float var = s2/cnt - mu*mu;
  float rstd = rsqrtf(var + EPSB);
  float g = (t<64)? gn[f] : ge[f];
  float b = (t<64)? bn[f] : beb[f];
  float sc = g*rstd, sh = b - mu*sc;
  coef[((t<64)?0:2)*64 + f] = sc;
  coef[((t<64)?1:3)*64 + f] = sh;
}

// ---------------- final node update: h += silu(bn(t)) ----------------
__global__ __launch_bounds__(256) void k_nodeupd(const float* __restrict__ x1,
    const float* __restrict__ agg, const float* __restrict__ invd,
    const float* __restrict__ coef, float* __restrict__ h){
  int i = blockIdx.x*256 + threadIdx.x;
  if (i >= NN*64) return;
  int n = i>>6, f = i&63;
  float t = x1[i] + agg[i]*invd[n];
  float v = t*coef[f] + coef[64+f];
  h[i] += silu_(v);
}

// ---------------- final edge output: wout[perm] = w2 + silu(bn(u2)) ----------------
__global__ __launch_bounds__(256) void k_edgeBfin(const unsigned short* __restrict__ wb16,
    const unsigned short* __restrict__ u_bf, const float* __restrict__ coef,
    const int* __restrict__ perm, float* __restrict__ wout){
  int i = blockIdx.x*256 + threadIdx.x;      // E*64/8 groups (sorted space)
  int cc = i & 7, f0 = cc*8;
  int eid = perm[i>>3];
  ushort8 wv = ((const ushort8*)wb16)[i];
  ushort8 ub = ((const ushort8*)u_bf)[i];
  float4 s0 = *(const float4*)(coef + 128 + f0);
  float4 s1v = *(const float4*)(coef + 128 + f0 + 4);
  float4 h0 = *(const float4*)(coef + 192 + f0);
  float4 h1 = *(const float4*)(coef + 192 + f0 + 4);
  float4 oa, ob;
  oa.x = bf2f(wv[0]) + silu_(bf2f(ub[0])*s0.x + h0.x);
  oa.y = bf2f(wv[1]) + silu_(bf2f(ub[1])*s0.y + h0.y);
  oa.z = bf2f(wv[2]) + silu_(bf2f(ub[2])*s0.z + h0.z);
  oa.w = bf2f(wv[3]) + silu_(bf2f(ub[3])*s0.w + h0.w);
  ob.x = bf2f(wv[4]) + silu_(bf2f(ub[4])*s1v.x + h1.x);
  ob.y = bf2f(wv[5]) + silu_(bf2f(ub[5])*s1v.y + h1.y);
  ob.z = bf2f(wv[6]) + silu_(bf2f(ub[6])*s1v.z + h1.z);
  ob.w = bf2f(wv[7]) + silu_(bf2f(ub[7])*s1v.w + h1.w);
  float4* wp = (float4*)(wout + (size_t)eid*64 + f0);
  wp[0] = oa; wp[1] = ob;
}

// ---------------- launch ----------------

extern "C" void kernel_launch(void* const* d_in, const int* in_sizes, int n_in,
                              void* d_out, int out_size, void* d_ws, size_t ws_size,
                              hipStream_t stream){
  const float* x      = (const float*)d_in[0];
  const int*   eidx   = (const int*)d_in[1];
  const float* eattr  = (const float*)d_in[2];
  const float* Wv     = (const float*)d_in[3];
  const float* bv     = (const float*)d_in[4];
  const float* We     = (const float*)d_in[5];
  const float* be     = (const float*)d_in[6];
  const float* g_node = (const float*)d_in[7];
  const float* b_node = (const float*)d_in[8];
  const float* g_edge = (const float*)d_in[9];
  const float* b_edge = (const float*)d_in[10];
  const int* src = eidx;
  const int* dst = eidx + NE;

  float* hout = (float*)d_out;                 // [N][64] live node state (f32)
  float* wout = hout + (size_t)NN*64;          // [E][64] final edge output (f32)

  float* W    = (float*)d_ws;
  float* x1   = W;                                           // 3.2M f32
  float* agg  = W + 3200000;                                 // 3.2M f32
  float* nsum = W + 6400000;
  float* nsq  = W + 6404096;
  float* esum = W + 6408192;
  float* esq  = W + 6412288;
  float* coef = W + 6416384;                                 // 3*256
  float* invd = W + 6417152;                                 // 50000
  int*   deg  = (int*)(W + 6467152);                         // 50000
  unsigned short* xb   = (unsigned short*)(W + 6517152);     // 3*3.2M bf16
  unsigned short* wvs  = (unsigned short*)(W + 11317152);    // 12*4096 bf16 swz
  unsigned short* wes  = (unsigned short*)(W + 11341728);    // 3*4096 bf16 swz
  unsigned short* u_bf = (unsigned short*)(W + 11347872);    // E*64 bf16 (sorted)
  unsigned short* wb16 = (unsigned short*)(W + 36947872);    // E*64 bf16 (sorted)
  int* perm   = (int*)(W + 62547872);                        // E
  int* ssrc   = (int*)(W + 63347872);                        // E
  int* sdst   = (int*)(W + 64147872);                        // E
  int* cursor = (int*)(W + 64947872);                        // N

  hipMemsetAsync(deg, 0, NN*sizeof(int), stream);
  k_silu4<<<3125, 256, 0, stream>>>(x, hout, 800000);
  k_deg<<<3125, 256, 0, stream>>>(src, deg);
  k_scan<<<1, 1024, 0, stream>>>(deg, cursor, invd);
  k_scatter<<<3125, 256, 0, stream>>>(src, dst, cursor, perm, ssrc, sdst);
  k_prepW<<<15, 256, 0, stream>>>(Wv, We, wvs, wes);

  const unsigned short* x2 = xb;
  const unsigned short* x3 = xb + (size_t)NN*64;
  const unsigned short* x4 = xb + (size_t)2*NN*64;

  for (int l=0; l<3; ++l){
    const float* cprev = coef + (l-1)*256;    // valid for l>=1
    if (l == 0)
      k_nodelin<0><<<782, 256, 0, stream>>>(hout, x1, agg, invd, coef,
          wvs + l*16384, bv + l*256, xb);
    else
      k_nodelin<1><<<782, 256, 0, stream>>>(hout, x1, agg, invd, cprev,
          wvs + l*16384, bv + l*256, xb);
    hipMemsetAsync(agg, 0, (3200000 + 4*4096)*sizeof(float), stream);
    if (l == 0)
      k_edgeA<1><<<12500, 256, 0, stream>>>(eattr, wb16, perm, ssrc, sdst,
          wes + l*4096, be + l*64, x2, x3, x4, coef, agg, esum, esq, u_bf);
    else
      k_edgeA<0><<<12500, 256, 0, stream>>>(eattr, wb16, perm, ssrc, sdst,
          wes + l*4096, be + l*64, x2, x3, x4, cprev, agg, esum, esq, u_bf);
    k_nodestats<<<128, 256, 0, stream>>>(x1, agg, invd, nsum, nsq);
    k_finalize<<<1, 128, 0, stream>>>(nsum, nsq, esum, esq,
        g_node + l*64, b_node + l*64, g_edge + l*64, b_edge + l*64, coef + l*256);
  }
  // final state updates (layer 2 coef)
  k_nodeupd<<<12500, 256, 0, stream>>>(x1, agg, invd, coef + 512, hout);
  k_edgeBfin<<<25000, 256, 0, stream>>>(wb16, u_bf, coef + 512, perm, wout);
}

// Round 9
// 796.618 us; speedup vs baseline: 5.5179x; 1.0131x over previous
//
#include <hip/hip_runtime.h>

#define NN 50000
#define NE 800000
#define EPSB 1e-5f

typedef __attribute__((ext_vector_type(8))) short bf16x8;
typedef __attribute__((ext_vector_type(8))) unsigned short ushort8;
typedef __attribute__((ext_vector_type(4))) float f32x4;

__device__ __forceinline__ float sigm(float x){ return 1.0f/(1.0f+__expf(-x)); }
__device__ __forceinline__ float silu_(float x){ return x/(1.0f+__expf(-x)); }
// HW packed f32->bf16 (RNE), 2 values / instr
__device__ __forceinline__ unsigned int cvt2(float lo, float hi){
  unsigned int r;
  asm("v_cvt_pk_bf16_f32 %0, %1, %2" : "=v"(r) : "v"(lo), "v"(hi));
  return r;
}
__device__ __forceinline__ unsigned short f2bf(float x){
  return (unsigned short)cvt2(x, 0.f);
}
__device__ __forceinline__ float bf2f(unsigned short b){
  return __uint_as_float(((unsigned int)b)<<16);
}
__device__ __forceinline__ ushort8 pack8(float a0,float a1,float a2,float a3,
                                         float a4,float a5,float a6,float a7){
  union { unsigned int u[4]; ushort8 s; } z;
  z.u[0]=cvt2(a0,a1); z.u[1]=cvt2(a2,a3); z.u[2]=cvt2(a4,a5); z.u[3]=cvt2(a6,a7);
  return z.s;
}

// ---------------- prep ----------------

__global__ __launch_bounds__(256) void k_deg(const int* __restrict__ src,
                                             int* __restrict__ deg){
  int e = blockIdx.x*256 + threadIdx.x;
  if (e < NE) atomicAdd(&deg[src[e]], 1);
}

// single-block exclusive scan of deg -> cursor; also invd
__global__ __launch_bounds__(1024) void k_scan(const int* __restrict__ deg,
    int* __restrict__ cursor, float* __restrict__ invd){
  __shared__ int wsum[16];
  __shared__ int sbase;
  if (threadIdx.x == 0) sbase = 0;
  __syncthreads();
  const int lane = threadIdx.x & 63, wid = threadIdx.x >> 6;
  for (int start = 0; start < NN; start += 1024){
    int n = start + (int)threadIdx.x;
    int v = (n < NN) ? deg[n] : 0;
    int x = v;
    #pragma unroll
    for (int d=1; d<64; d<<=1){
      int y = __shfl_up(x, d);
      if (lane >= d) x += y;
    }
    if (lane == 63) wsum[wid] = x;
    __syncthreads();
    if (threadIdx.x < 16){
      int s = wsum[threadIdx.x];
      #pragma unroll
      for (int d=1; d<16; d<<=1){
        int y = __shfl_up(s, d);
        if ((int)threadIdx.x >= d) s += y;
      }
      wsum[threadIdx.x] = s;
    }
    __syncthreads();
    int excl = sbase + ((wid>0)? wsum[wid-1] : 0) + (x - v);
    if (n < NN){
      cursor[n] = excl;
      invd[n] = 1.0f / fmaxf((float)v, 1.0f);
    }
    __syncthreads();
    if (threadIdx.x == 0) sbase += wsum[15];
    __syncthreads();
  }
}

// scatter edges into src-sorted order
__global__ __launch_bounds__(256) void k_scatter(const int* __restrict__ src,
    const int* __restrict__ dst, int* __restrict__ cursor,
    int* __restrict__ perm, int* __restrict__ ssrc, int* __restrict__ sdst){
  int e = blockIdx.x*256 + threadIdx.x;
  if (e < NE){
    int s = src[e];
    int pos = atomicAdd(&cursor[s], 1);
    perm[pos] = e;
    ssrc[pos] = s;
    sdst[pos] = dst[e];
  }
}

// pre-convert all 15 weight mats (Wv 3x4 + We 3x1) to bf16, XOR-swizzled
__global__ __launch_bounds__(256) void k_prepW(const float* __restrict__ Wv,
    const float* __restrict__ We,
    unsigned short* __restrict__ wvs, unsigned short* __restrict__ wes){
  const int m = blockIdx.x;
  const float* S = (m < 12) ? (Wv + m*4096) : (We + (m-12)*4096);
  unsigned short* O = (m < 12) ? (wvs + m*4096) : (wes + (m-12)*4096);
  int t = threadIdx.x;
  #pragma unroll
  for (int p=0; p<2; ++p){
    int c = t + p*256;
    int row = c>>3, cc = c&7;
    const float4* sp = (const float4*)(S + row*64 + cc*8);
    float4 a = sp[0], b = sp[1];
    ushort8 v = pack8(a.x,a.y,a.z,a.w,b.x,b.y,b.z,b.w);
    *(ushort8*)((char*)O + ((row*128 + cc*16) ^ ((row&7)<<4))) = v;
  }
}

// ---------------- node linears (MFMA) + fused h-update ----------------
// MODE 0: h = silu(x) staged inline (layer 0). MODE 1: h += silu(bn_prev(x1+agg*invd)).
template<int MODE>
__global__ __launch_bounds__(256) void k_nodelin(const float* __restrict__ xin,
    float* __restrict__ h, float* __restrict__ x1, const float* __restrict__ agg,
    const float* __restrict__ invd, const float* __restrict__ coefp,
    const unsigned short* __restrict__ wvs, const float* __restrict__ bvl,
    unsigned short* __restrict__ xb){
  __shared__ unsigned short shb[4096];   // h tile bf16 swizzled
  __shared__ unsigned short sW[4096];    // current weight mat
  const int n0 = blockIdx.x*64;
  const int t = threadIdx.x;
  #pragma unroll
  for (int p=0; p<2; ++p){
    int c = t + p*256;
    int row = c>>3, cc = c&7;
    int n = n0 + row;
    ushort8 v = {0,0,0,0,0,0,0,0};
    if (n < NN){
      unsigned base = (unsigned)n*64u + (unsigned)cc*8u;
      float4 a, b;
      if (MODE == 0){
        const float4* xp = (const float4*)(xin + base);
        a = xp[0]; b = xp[1];
        a.x=silu_(a.x); a.y=silu_(a.y); a.z=silu_(a.z); a.w=silu_(a.w);
        b.x=silu_(b.x); b.y=silu_(b.y); b.z=silu_(b.z); b.w=silu_(b.w);
        float4* hp = (float4*)(h + base);
        hp[0] = a; hp[1] = b;
      } else {
        float4* hp = (float4*)(h + base);
        a = hp[0]; b = hp[1];
        const float4* xp = (const float4*)(x1 + base);
        const float4* gp = (const float4*)(agg + base);
        float iv = invd[n];
        float4 xa = xp[0], xb4 = xp[1], ga = gp[0], gb = gp[1];
        float4 s0 = *(const float4*)(coefp + cc*8);
        float4 s1v = *(const float4*)(coefp + cc*8 + 4);
        float4 h0 = *(const float4*)(coefp + 64 + cc*8);
        float4 h1 = *(const float4*)(coefp + 64 + cc*8 + 4);
        a.x += silu_((xa.x + ga.x*iv)*s0.x + h0.x);
        a.y += silu_((xa.y + ga.y*iv)*s0.y + h0.y);
        a.z += silu_((xa.z + ga.z*iv)*s0.z + h0.z);
        a.w += silu_((xa.w + ga.w*iv)*s0.w + h0.w);
        b.x += silu_((xb4.x + gb.x*iv)*s1v.x + h1.x);
        b.y += silu_((xb4.y + gb.y*iv)*s1v.y + h1.y);
        b.z += silu_((xb4.z + gb.z*iv)*s1v.z + h1.z);
        b.w += silu_((xb4.w + gb.w*iv)*s1v.w + h1.w);
        hp[0] = a; hp[1] = b;
      }
      v = pack8(a.x,a.y,a.z,a.w,b.x,b.y,b.z,b.w);
    }
    *(ushort8*)((char*)shb + ((row*128 + cc*16) ^ ((row&7)<<4))) = v;
  }
  __syncthreads();
  const int wid = t>>6, lane = t&63, g = lane>>4, ln = lane&15;
  const int arow = wid*16 + ln;
  bf16x8 afr0 = *(bf16x8*)((char*)shb + ((arow*128 +  0 + g*16) ^ ((arow&7)<<4)));
  bf16x8 afr1 = *(bf16x8*)((char*)shb + ((arow*128 + 64 + g*16) ^ ((arow&7)<<4)));
  for (int k=0; k<4; ++k){
    __syncthreads();
    ((ushort8*)sW)[t]     = ((const ushort8*)(wvs + k*4096))[t];
    ((ushort8*)sW)[t+256] = ((const ushort8*)(wvs + k*4096))[t+256];
    __syncthreads();
    #pragma unroll
    for (int ft=0; ft<4; ++ft){
      int brow = ft*16 + ln;
      bf16x8 b0 = *(bf16x8*)((char*)sW + ((brow*128 +  0 + g*16) ^ ((brow&7)<<4)));
      bf16x8 b1 = *(bf16x8*)((char*)sW + ((brow*128 + 64 + g*16) ^ ((brow&7)<<4)));
      f32x4 c = {0.f,0.f,0.f,0.f};
      c = __builtin_amdgcn_mfma_f32_16x16x32_bf16(afr0, b0, c, 0,0,0);
      c = __builtin_amdgcn_mfma_f32_16x16x32_bf16(afr1, b1, c, 0,0,0);
      float bias = bvl[k*64 + brow];
      #pragma unroll
      for (int r=0; r<4; ++r){
        int n = n0 + wid*16 + g*4 + r;
        if (n < NN){
          float val = c[r] + bias;
          unsigned off = (unsigned)n*64u + (unsigned)brow;
          if (k == 0) x1[off] = val;
          else xb[(unsigned)(k-1)*(NN*64u) + off] = f2bf(val);
        }
      }
    }
  }
}

// ---------------- edge pass A (MFMA, src-sorted) + fused w-state update ----------------
template<int FIRST>
__global__ __launch_bounds__(256) void k_edgeA(const float* __restrict__ ea,
    unsigned short* __restrict__ wb16,
    const int* __restrict__ perm, const int* __restrict__ ssrc,
    const int* __restrict__ sdst,
    const unsigned short* __restrict__ wes, const float* __restrict__ be,
    const unsigned short* __restrict__ x2, const unsigned short* __restrict__ x3,
    const unsigned short* __restrict__ x4, const float* __restrict__ coefp,
    float* __restrict__ agg, float* __restrict__ esum, float* __restrict__ esq,
    unsigned short* __restrict__ u_bf){
  __shared__ unsigned short sWb[4096];   // We; reused for u staging
  __shared__ unsigned short swb[4096];   // w tile
  __shared__ unsigned short sxs[4096];   // x3[s]+x4[d] sum; reused for x2 in phase 2
  __shared__ int sidx[128];
  const int e0 = blockIdx.x*64;
  const unsigned ebase = (unsigned)e0*64u;
  const int t = threadIdx.x;

  if (t < 64) sidx[t] = ssrc[e0+t];
  else if (t < 128) sidx[t] = sdst[e0+t-64];
  ((ushort8*)sWb)[t]     = ((const ushort8*)wes)[t];
  ((ushort8*)sWb)[t+256] = ((const ushort8*)wes)[t+256];

  // stage w state (+fused update), write back to global (sorted space)
  #pragma unroll
  for (int p=0; p<2; ++p){
    int c = t + p*256;
    int row = c>>3, cc = c&7;
    ushort8 v;
    if (FIRST){
      unsigned esrc = (unsigned)perm[e0 + row];
      const float4* sp = (const float4*)(ea + esrc*64u + (unsigned)cc*8u);
      float4 a = sp[0], b = sp[1];
      v = pack8(silu_(a.x),silu_(a.y),silu_(a.z),silu_(a.w),
                silu_(b.x),silu_(b.y),silu_(b.z),silu_(b.w));
    } else {
      ushort8 wv = ((const ushort8*)(wb16 + ebase))[c];
      ushort8 uv = ((const ushort8*)(u_bf + ebase))[c];
      int f0 = cc*8;
      float4 s0 = *(const float4*)(coefp + 128 + f0);
      float4 s1v = *(const float4*)(coefp + 128 + f0 + 4);
      float4 h0 = *(const float4*)(coefp + 192 + f0);
      float4 h1 = *(const float4*)(coefp + 192 + f0 + 4);
      v = pack8(
        bf2f(wv[0]) + silu_(bf2f(uv[0])*s0.x + h0.x),
        bf2f(wv[1]) + silu_(bf2f(uv[1])*s0.y + h0.y),
        bf2f(wv[2]) + silu_(bf2f(uv[2])*s0.z + h0.z),
        bf2f(wv[3]) + silu_(bf2f(uv[3])*s0.w + h0.w),
        bf2f(wv[4]) + silu_(bf2f(uv[4])*s1v.x + h1.x),
        bf2f(wv[5]) + silu_(bf2f(uv[5])*s1v.y + h1.y),
        bf2f(wv[6]) + silu_(bf2f(uv[6])*s1v.z + h1.z),
        bf2f(wv[7]) + silu_(bf2f(uv[7])*s1v.w + h1.w));
    }
    ((ushort8*)(wb16 + ebase))[c] = v;
    *(ushort8*)((char*)swb + ((row*128 + cc*16) ^ ((row&7)<<4))) = v;
  }
  __syncthreads();   // B1: sidx, sWb, swb visible

  // gather x3[s] + x4[d], summed, into one LDS buffer
  #pragma unroll
  for (int p=0; p<2; ++p){
    int c = t + p*256;
    int row = c>>3, cc = c&7;
    unsigned s  = (unsigned)sidx[row];
    unsigned d2 = (unsigned)sidx[64+row];
    ushort8 a = *(const ushort8*)(x3 + s*64u  + (unsigned)cc*8u);
    ushort8 b = *(const ushort8*)(x4 + d2*64u + (unsigned)cc*8u);
    ushort8 v = pack8(
      bf2f(a[0])+bf2f(b[0]), bf2f(a[1])+bf2f(b[1]),
      bf2f(a[2])+bf2f(b[2]), bf2f(a[3])+bf2f(b[3]),
      bf2f(a[4])+bf2f(b[4]), bf2f(a[5])+bf2f(b[5]),
      bf2f(a[6])+bf2f(b[6]), bf2f(a[7])+bf2f(b[7]));
    *(ushort8*)((char*)sxs + ((row*128 + cc*16) ^ ((row&7)<<4))) = v;
  }

  const int wid = t>>6, lane = t&63, g = lane>>4, ln = lane&15;
  const int arow = wid*16 + ln;
  bf16x8 afr0 = *(bf16x8*)((char*)swb + ((arow*128 +  0 + g*16) ^ ((arow&7)<<4)));
  bf16x8 afr1 = *(bf16x8*)((char*)swb + ((arow*128 + 64 + g*16) ^ ((arow&7)<<4)));
  bf16x8 bfr[4][2];
  #pragma unroll
  for (int ft=0; ft<4; ++ft){
    int brow = ft*16 + ln;
    bfr[ft][0] = *(bf16x8*)((char*)sWb + ((brow*128 +  0 + g*16) ^ ((brow&7)<<4)));
    bfr[ft][1] = *(bf16x8*)((char*)sWb + ((brow*128 + 64 + g*16) ^ ((brow&7)<<4)));
  }
  __syncthreads();   // B2: sxs ready; sWb frag reads done (sWb reusable)

  f32x4 cacc[4];
  #pragma unroll
  for (int ft=0; ft<4; ++ft){
    f32x4 c = {0.f,0.f,0.f,0.f};
    c = __builtin_amdgcn_mfma_f32_16x16x32_bf16(afr0, bfr[ft][0], c, 0,0,0);
    c = __builtin_amdgcn_mfma_f32_16x16x32_bf16(afr1, bfr[ft][1], c, 0,0,0);
    cacc[ft] = c;
  }

  // phase 1: u, stats, u -> sWb
  float bef[4];
  #pragma unroll
  for (int ft=0; ft<4; ++ft) bef[ft] = be[ft*16+ln];
  float s1[4]={0.f,0.f,0.f,0.f}, s2[4]={0.f,0.f,0.f,0.f};
  #pragma unroll
  for (int r=0; r<4; ++r){
    int row = wid*16 + g*4 + r;
    #pragma unroll
    for (int ft=0; ft<4; ++ft){
      int f = ft*16 + ln;
      unsigned short a34 = *(unsigned short*)((char*)sxs + ((row*128 + f*2) ^ ((row&7)<<4)));
      float u = cacc[ft][r] + bef[ft] + bf2f(a34);
      s1[ft] += u; s2[ft] += u*u;
      *(unsigned short*)((char*)sWb + ((row*128 + f*2) ^ ((row&7)<<4))) = f2bf(u);
    }
  }
  #pragma unroll
  for (int ft=0; ft<4; ++ft){
    s1[ft] += __shfl_xor(s1[ft], 16); s1[ft] += __shfl_xor(s1[ft], 32);
    s2[ft] += __shfl_xor(s2[ft], 16); s2[ft] += __shfl_xor(s2[ft], 32);
  }
  if (g == 0){
    int slot = ((blockIdx.x<<2) + wid) & 63;
    #pragma unroll
    for (int ft=0; ft<4; ++ft){
      atomicAdd(&esum[(slot<<6) + ft*16 + ln], s1[ft]);
      atomicAdd(&esq [(slot<<6) + ft*16 + ln], s2[ft]);
    }
  }
  __syncthreads();   // B3: u staged in sWb; sxs free

  // u coalesced store + stage x2[dst] into sxs
  #pragma unroll
  for (int p=0; p<2; ++p){
    int c = t + p*256;
    int row = c>>3, cc = c&7;
    ushort8 v = *(ushort8*)((char*)sWb + ((row*128 + cc*16) ^ ((row&7)<<4)));
    ((ushort8*)(u_bf + ebase))[c] = v;
    unsigned d2 = (unsigned)sidx[64+row];
    ushort8 xv = *(const ushort8*)(x2 + d2*64u + (unsigned)cc*8u);
    *(ushort8*)((char*)sxs + ((row*128 + cc*16) ^ ((row&7)<<4))) = xv;
  }
  __syncthreads();   // B4: x2 staged

  // phase 2: gated messages, run-length aggregated (ssrc sorted)
  {
    const int el0 = wid<<4;
    unsigned curs = (unsigned)sidx[el0];
    float run = 0.f;
    #pragma unroll
    for (int j=0; j<16; ++j){
      int el = el0 + j;
      unsigned s = (unsigned)sidx[el];
      if (s != curs){
        atomicAdd(&agg[curs*64u + (unsigned)lane], run);
        run = 0.f; curs = s;
      }
      unsigned short wv = *(unsigned short*)((char*)swb + ((el*128 + lane*2) ^ ((el&7)<<4)));
      unsigned short xv = *(unsigned short*)((char*)sxs + ((el*128 + lane*2) ^ ((el&7)<<4)));
      run += sigm(bf2f(wv)) * bf2f(xv);
    }
    atomicAdd(&agg[curs*64u + (unsigned)lane], run);
  }
}

// ---------------- node BN stats over t = x1 + agg*invdeg ----------------
__global__ __launch_bounds__(256) void k_nodestats(const float* __restrict__ x1,
    const float* __restrict__ agg, const float* __restrict__ invd,
    float* __restrict__ nsum, float* __restrict__ nsq){
  const int f = threadIdx.x & 63, sub = threadIdx.x >> 6;
  float s1=0.f, s2=0.f;
  for (int n = blockIdx.x*4 + sub; n < NN; n += gridDim.x*4){
    unsigned off = (unsigned)n*64u + (unsigned)f;
    float t = x1[off] + agg[off]*invd[n];
    s1 += t; s2 += t*t;
  }
  __shared__ float red[4][64][2];
  red[sub][f][0]=s1; red[sub][f][1]=s2;
  __syncthreads();
  if (sub==0){
    float a1=red[0][f][0]+red[1][f][0]+red[2][f][0]+red[3][f][0];
    float a2=red[0][f][1]+red[1][f][1]+red[2][f][1]+red[3][f][1];
    int slot = blockIdx.x & 63;
    atomicAdd(&nsum[(slot<<6)+f], a1);
    atomicAdd(&nsq[(slot<<6)+f], a2);
  }
}

// ---------------- finalize both BN -> per-layer coef slot ----------------
__global__ void k_finalize(const float* __restrict__ nsum, const float* __restrict__ nsq,
    const float* __restrict__ esum, const float* __restrict__ esq,
    const float* __restrict__ gn, const float* __restrict__ bn,
    const float* __restrict__ ge, const float* __restrict__ beb,
    float* __restrict__ coef){
  int t = threadIdx.x;
  if (t >= 128) return;
  int f = t & 63;
  const float* S1 = (t<64)? nsum : esum;
  const float* S2 = (t<64)? nsq  : esq;
  float cnt = (t<64)? (float)NN : (float)NE;
  float s1=0.f, s2=0.f;
  for (int k=0;k<64;++k){ s1 += S1[(k<<6)+f]; s2 += S2[(k<<6)+f]; }
  float mu = s1/cnt;
  float var = s2/cnt - mu*mu;
  float rstd = rsqrtf(var + EPSB);
  float g = (t<64)? gn[f] : ge[f];
  float b = (t<64)? bn[f] : beb[f];
  float sc = g*rstd, sh = b - mu*sc;
  coef[((t<64)?0:2)*64 + f] = sc;
  coef[((t<64)?1:3)*64 + f] = sh;
}

// ---------------- final node update: h += silu(bn(t)) ----------------
__global__ __launch_bounds__(256) void k_nodeupd(const float* __restrict__ x1,
    const float* __restrict__ agg, const float* __restrict__ invd,
    const float* __restrict__ coef, float* __restrict__ h){
  unsigned i = blockIdx.x*256u + threadIdx.x;
  if (i >= NN*64u) return;
  unsigned n = i>>6, f = i&63u;
  float t = x1[i] + agg[i]*invd[n];
  float v = t*coef[f] + coef[64+f];
  h[i] += silu_(v);
}

// ---------------- final edge output: wout[perm] = w2 + silu(bn(u2)) ----------------
__global__ __launch_bounds__(256) void k_edgeBfin(const unsigned short* __restrict__ wb16,
    const unsigned short* __restrict__ u_bf, const float* __restrict__ coef,
    const int* __restrict__ perm, float* __restrict__ wout){
  unsigned i = blockIdx.x*256u + threadIdx.x;   // E*64/8 groups (sorted space)
  unsigned cc = i & 7u, f0 = cc*8u;
  unsigned eid = (unsigned)perm[i>>3];
  ushort8 wv = ((const ushort8*)wb16)[i];
  ushort8 ub = ((const ushort8*)u_bf)[i];
  float4 s0 = *(const float4*)(coef + 128 + f0);
  float4 s1v = *(const float4*)(coef + 128 + f0 + 4);
  float4 h0 = *(const float4*)(coef + 192 + f0);
  float4 h1 = *(const float4*)(coef + 192 + f0 + 4);
  float4 oa, ob;
  oa.x = bf2f(wv[0]) + silu_(bf2f(ub[0])*s0.x + h0.x);
  oa.y = bf2f(wv[1]) + silu_(bf2f(ub[1])*s0.y + h0.y);
  oa.z = bf2f(wv[2]) + silu_(bf2f(ub[2])*s0.z + h0.z);
  oa.w = bf2f(wv[3]) + silu_(bf2f(ub[3])*s0.w + h0.w);
  ob.x = bf2f(wv[4]) + silu_(bf2f(ub[4])*s1v.x + h1.x);
  ob.y = bf2f(wv[5]) + silu_(bf2f(ub[5])*s1v.y + h1.y);
  ob.z = bf2f(wv[6]) + silu_(bf2f(ub[6])*s1v.z + h1.z);
  ob.w = bf2f(wv[7]) + silu_(bf2f(ub[7])*s1v.w + h1.w);
  float4* wp = (float4*)(wout + eid*64u + f0);
  wp[0] = oa; wp[1] = ob;
}

// ---------------- launch ----------------

extern "C" void kernel_launch(void* const* d_in, const int* in_sizes, int n_in,
                              void* d_out, int out_size, void* d_ws, size_t ws_size,
                              hipStream_t stream){
  const float* x      = (const float*)d_in[0];
  const int*   eidx   = (const int*)d_in[1];
  const float* eattr  = (const float*)d_in[2];
  const float* Wv     = (const float*)d_in[3];
  const float* bv     = (const float*)d_in[4];
  const float* We     = (const float*)d_in[5];
  const float* be     = (const float*)d_in[6];
  const float* g_node = (const float*)d_in[7];
  const float* b_node = (const float*)d_in[8];
  const float* g_edge = (const float*)d_in[9];
  const float* b_edge = (const float*)d_in[10];
  const int* src = eidx;
  const int* dst = eidx + NE;

  float* hout = (float*)d_out;                 // [N][64] live node state (f32)
  float* wout = hout + (size_t)NN*64;          // [E][64] final edge output (f32)

  float* W    = (float*)d_ws;
  float* x1   = W;                                           // 3.2M f32
  float* agg  = W + 3200000;                                 // 3.2M f32
  float* nsum = W + 6400000;
  float* nsq  = W + 6404096;
  float* esum = W + 6408192;
  float* esq  = W + 6412288;
  float* coef = W + 6416384;                                 // 3*256
  float* invd = W + 6417152;                                 // 50000
  int*   deg  = (int*)(W + 6467152);                         // 50000
  unsigned short* xb   = (unsigned short*)(W + 6517152);     // 3*3.2M bf16
  unsigned short* wvs  = (unsigned short*)(W + 11317152);    // 12*4096 bf16 swz
  unsigned short* wes  = (unsigned short*)(W + 11341728);    // 3*4096 bf16 swz
  unsigned short* u_bf = (unsigned short*)(W + 11347872);    // E*64 bf16 (sorted)
  unsigned short* wb16 = (unsigned short*)(W + 36947872);    // E*64 bf16 (sorted)
  int* perm   = (int*)(W + 62547872);                        // E
  int* ssrc   = (int*)(W + 63347872);                        // E
  int* sdst   = (int*)(W + 64147872);                        // E
  int* cursor = (int*)(W + 64947872);                        // N

  hipMemsetAsync(deg, 0, NN*sizeof(int), stream);
  k_deg<<<3125, 256, 0, stream>>>(src, deg);
  k_scan<<<1, 1024, 0, stream>>>(deg, cursor, invd);
  k_scatter<<<3125, 256, 0, stream>>>(src, dst, cursor, perm, ssrc, sdst);
  k_prepW<<<15, 256, 0, stream>>>(Wv, We, wvs, wes);

  const unsigned short* x2 = xb;
  const unsigned short* x3 = xb + (size_t)NN*64;
  const unsigned short* x4 = xb + (size_t)2*NN*64;

  for (int l=0; l<3; ++l){
    const float* cprev = coef + (l-1)*256;    // valid for l>=1
    if (l == 0)
      k_nodelin<0><<<782, 256, 0, stream>>>(x, hout, x1, agg, invd, coef,
          wvs + l*16384, bv + l*256, xb);
    else
      k_nodelin<1><<<782, 256, 0, stream>>>(x, hout, x1, agg, invd, cprev,
          wvs + l*16384, bv + l*256, xb);
    hipMemsetAsync(agg, 0, (3200000 + 4*4096)*sizeof(float), stream);
    if (l == 0)
      k_edgeA<1><<<12500, 256, 0, stream>>>(eattr, wb16, perm, ssrc, sdst,
          wes + l*4096, be + l*64, x2, x3, x4, coef, agg, esum, esq, u_bf);
    else
      k_edgeA<0><<<12500, 256, 0, stream>>>(eattr, wb16, perm, ssrc, sdst,
          wes + l*4096, be + l*64, x2, x3, x4, cprev, agg, esum, esq, u_bf);
    k_nodestats<<<128, 256, 0, stream>>>(x1, agg, invd, nsum, nsq);
    k_finalize<<<1, 128, 0, stream>>>(nsum, nsq, esum, esq,
        g_node + l*64, b_node + l*64, g_edge + l*64, b_edge + l*64, coef + l*256);
  }
  // final state updates (layer 2 coef)
  k_nodeupd<<<12500, 256, 0, stream>>>(x1, agg, invd, coef + 512, hout);
  k_edgeBfin<<<25000, 256, 0, stream>>>(wb16, u_bf, coef + 512, perm, wout);
}